// Round 13
// baseline (1626.011 us; speedup 1.0000x reference)
//
#include <hip/hip_runtime.h>
#include <hip/hip_bf16.h>
#include <cstdint>

#define NT   900
#define EMB  1152
#define NH   16
#define DHD  72
#define DHH  36
#define DHP  96      // padded head dim (3*32)
#define KVP  928     // padded kv length (29*32)
#define NL   6
#define FFD  4608
#define MHD  4608
#define OUTD 2048
#define NM   225

typedef __attribute__((ext_vector_type(8))) short short8;
typedef __attribute__((ext_vector_type(4))) float f32x4;

__device__ __forceinline__ ushort f2bf(float f) {
    uint32_t u = __float_as_uint(f);
    uint32_t r = u + 0x7FFF + ((u >> 16) & 1);
    return (ushort)(r >> 16);
}
__device__ __forceinline__ float gelu_f(float x) {
    return 0.5f * x * (1.0f + tanhf(0.7978845608f * (x + 0.044715f * x * x * x)));
}

// async global -> LDS, 16B per lane (lds dest wave-uniform base; HW adds lane*16)
__device__ __forceinline__ void g2lds16(const ushort* g, ushort* l) {
    __builtin_amdgcn_global_load_lds(
        (const __attribute__((address_space(1))) unsigned int*)g,
        (__attribute__((address_space(3))) unsigned int*)l, 16, 0, 0);
}

// ---------------- weight f32 -> bf16 pre-conversion ----------------
__global__ __launch_bounds__(256) void k_cvt(const float* __restrict__ src,
                                             ushort* __restrict__ dst, int n4) {
    int idx = blockIdx.x * 256 + threadIdx.x;
    if (idx >= n4) return;
    const float4 v = *(const float4*)(src + (size_t)idx * 4);
    ushort o[4] = { f2bf(v.x), f2bf(v.y), f2bf(v.z), f2bf(v.w) };
    *(uint2*)(dst + (size_t)idx * 4) = *(const uint2*)o;
}

// ---------------- patch extraction: pixels -> bf16 [900, 1536] ----------------
__global__ __launch_bounds__(256) void k_patch(const float* __restrict__ pix,
                                               ushort* __restrict__ xp) {
    int idx = blockIdx.x * 256 + threadIdx.x;
    if (idx >= NT * 1536) return;
    int t = idx / 1536, f = idx - t * 1536;
    int mw = t & 1, mh = (t >> 1) & 1;
    int tq = t >> 2;
    int jj = tq % 15, ii = tq / 15;
    int pw = f & 15, ph = (f >> 4) & 15, c = f >> 9;
    int Hi = (ii * 2 + mh) * 16 + ph;
    int Wi = (jj * 2 + mw) * 16 + pw;
    float p = pix[((size_t)c * 480 + Hi) * 480 + Wi];
    xp[idx] = f2bf((p - 127.5f) * (1.0f / 127.5f));
}

// ---------------- layernorm f32 in -> bf16 out, one block per row ----------------
__global__ __launch_bounds__(256) void k_ln(const float* __restrict__ x,
                                            const float* __restrict__ w,
                                            const float* __restrict__ b,
                                            ushort* __restrict__ y, int C) {
    int row = blockIdx.x;
    int tid = threadIdx.x;
    const float* xr = x + (size_t)row * C;
    float s = 0.f, ss = 0.f;
    for (int c = tid; c < C; c += 256) { float v = xr[c]; s += v; ss += v * v; }
    for (int off = 32; off; off >>= 1) {
        s  += __shfl_down(s,  off, 64);
        ss += __shfl_down(ss, off, 64);
    }
    __shared__ float rs[4], rss[4];
    int wid = tid >> 6, lane = tid & 63;
    if (lane == 0) { rs[wid] = s; rss[wid] = ss; }
    __syncthreads();
    float S  = rs[0] + rs[1] + rs[2] + rs[3];
    float SS = rss[0] + rss[1] + rss[2] + rss[3];
    float mu  = S / C;
    float var = SS / C - mu * mu;
    float inv = rsqrtf(var + 1e-6f);
    ushort* yr = y + (size_t)row * C;
    for (int c = tid; c < C; c += 256) yr[c] = f2bf((xr[c] - mu) * inv * w[c] + b[c]);
}

// ---------------- fused split-K reduce + bias + residual + LayerNorm ----------------
__global__ __launch_bounds__(256) void k_fixln(const float* __restrict__ part,
                                               const float* __restrict__ bias,
                                               const float* __restrict__ res,
                                               float* __restrict__ hout,
                                               const float* __restrict__ lw,
                                               const float* __restrict__ lb,
                                               ushort* __restrict__ y,
                                               int C, int S, long MN) {
    int row = blockIdx.x, tid = threadIdx.x;
    int C4 = C >> 2;
    const float* prow = part + (size_t)row * C;
    const float* rrow = res + (size_t)row * C;
    float* hrow = hout + (size_t)row * C;
    ushort* yrow = y + (size_t)row * C;

    float4 vals[2];
    float s = 0.f, ss = 0.f;
    int idx[2] = { tid, tid + 256 };
#pragma unroll
    for (int it = 0; it < 2; ++it) {
        int c4 = idx[it];
        if (c4 < C4) {
            float4 v = *(const float4*)(prow + c4 * 4);
            for (int sI = 1; sI < S; ++sI) {
                const float4 p = *(const float4*)(prow + (size_t)sI * MN + c4 * 4);
                v.x += p.x; v.y += p.y; v.z += p.z; v.w += p.w;
            }
            const float4 bi = *(const float4*)(bias + c4 * 4);
            v.x += bi.x; v.y += bi.y; v.z += bi.z; v.w += bi.w;
            const float4 rr = *(const float4*)(rrow + c4 * 4);
            v.x += rr.x; v.y += rr.y; v.z += rr.z; v.w += rr.w;
            *(float4*)(hrow + c4 * 4) = v;
            vals[it] = v;
            s  += v.x + v.y + v.z + v.w;
            ss += v.x * v.x + v.y * v.y + v.z * v.z + v.w * v.w;
        }
    }
    for (int off = 32; off; off >>= 1) {
        s  += __shfl_down(s,  off, 64);
        ss += __shfl_down(ss, off, 64);
    }
    __shared__ float rs[4], rss[4];
    int wid = tid >> 6, lane = tid & 63;
    if (lane == 0) { rs[wid] = s; rss[wid] = ss; }
    __syncthreads();
    float St  = rs[0] + rs[1] + rs[2] + rs[3];
    float SSt = rss[0] + rss[1] + rss[2] + rss[3];
    float mu  = St / C;
    float var = SSt / C - mu * mu;
    float inv = rsqrtf(var + 1e-6f);
#pragma unroll
    for (int it = 0; it < 2; ++it) {
        int c4 = idx[it];
        if (c4 < C4) {
            float4 v = vals[it];
            const float4 w4 = *(const float4*)(lw + c4 * 4);
            const float4 b4 = *(const float4*)(lb + c4 * 4);
            ushort o[4] = { f2bf((v.x - mu) * inv * w4.x + b4.x),
                            f2bf((v.y - mu) * inv * w4.y + b4.y),
                            f2bf((v.z - mu) * inv * w4.z + b4.z),
                            f2bf((v.w - mu) * inv * w4.w + b4.w) };
            *(uint2*)(yrow + c4 * 4) = *(const uint2*)o;
        }
    }
}

// ---------------- dense MFMA GEMM, 128x128 tile, BK=64, gload_lds + XOR swizzle ----
// All registers NAMED (no arrays/lambdas) to avoid rule-#20 scratch allocation.
// C[M,N] = act(A @ W^T + bias) + res   (N % 128 == 0)
// grid (ceil(M/128), N/128, S). SPLIT=1: raw partials to part[z][M][N].
#define RD_A(i) (*(const short8*)&As[(wro + 16*(i) + fr) * 64 + kx])
#define RD_B(i) (*(const short8*)&Bs[(wco + 16*(i) + fr) * 64 + kx])
#define EPI(CV, I, JJ)                                                          \
    do {                                                                        \
        _Pragma("unroll")                                                       \
        for (int r = 0; r < 4; ++r) {                                           \
            int row = row0 + wro + (I) * 16 + (lane >> 4) * 4 + r;              \
            int col = col0 + wco + (JJ) * 16 + fr;                              \
            if (row < M) {                                                      \
                if (SPLIT) {                                                    \
                    part[((size_t)z * M + row) * N + col] = CV[r];              \
                } else {                                                        \
                    float v = CV[r] + bias[col];                                \
                    if (res) v += res[(size_t)row * N + col];                   \
                    if (ACT == 1) v = gelu_f(v);                                \
                    if (OBF16) ((ushort*)Cp)[(size_t)row * N + col] = f2bf(v);  \
                    else       ((float*)Cp)[(size_t)row * N + col] = v;         \
                }                                                               \
            }                                                                   \
        }                                                                       \
    } while (0)

template <int ACT, int OBF16, int SPLIT>
__global__ __launch_bounds__(256) void k_b2(const ushort* __restrict__ A,
                                            const ushort* __restrict__ W,
                                            const float* __restrict__ bias,
                                            const float* __restrict__ res,
                                            void* __restrict__ Cp,
                                            float* __restrict__ part,
                                            int M, int N, int K, int S) {
    __shared__ __align__(16) ushort As[128 * 64];
    __shared__ __align__(16) ushort Bs[128 * 64];
    int tid = threadIdx.x;
    int row0 = blockIdx.x * 128, col0 = blockIdx.y * 128;
    int z = blockIdx.z;
    int Kc = K / S;              // multiple of 64
    int kbeg = z * Kc;
    int steps = Kc >> 6;

    int w = tid >> 6, lane = tid & 63;
    int lrow = lane >> 3;                    // 0..7
    int cg   = ((lane & 7) ^ lrow) << 3;     // pre-swizzled source granule (elems)

    // wave w stages A rows [w*32, w*32+32) and B rows likewise, 4 issues each
    int ra0 = row0 + w * 32 + lrow;
    int a0r = ra0;      if (a0r > M - 1) a0r = M - 1;
    int a1r = ra0 + 8;  if (a1r > M - 1) a1r = M - 1;
    int a2r = ra0 + 16; if (a2r > M - 1) a2r = M - 1;
    int a3r = ra0 + 24; if (a3r > M - 1) a3r = M - 1;
    int wb = col0 + w * 32 + lrow;           // N % 128 == 0 -> in range
    const ushort* ap0 = A + (size_t)a0r * K + kbeg + cg;
    const ushort* ap1 = A + (size_t)a1r * K + kbeg + cg;
    const ushort* ap2 = A + (size_t)a2r * K + kbeg + cg;
    const ushort* ap3 = A + (size_t)a3r * K + kbeg + cg;
    const ushort* wp0 = W + (size_t)wb * K + kbeg + cg;
    const ushort* wp1 = W + (size_t)(wb + 8) * K + kbeg + cg;
    const ushort* wp2 = W + (size_t)(wb + 16) * K + kbeg + cg;
    const ushort* wp3 = W + (size_t)(wb + 24) * K + kbeg + cg;
    ushort* la0 = &As[(w * 32) * 64];
    ushort* la1 = &As[(w * 32 + 8) * 64];
    ushort* la2 = &As[(w * 32 + 16) * 64];
    ushort* la3 = &As[(w * 32 + 24) * 64];
    ushort* lb0 = &Bs[(w * 32) * 64];
    ushort* lb1 = &Bs[(w * 32 + 8) * 64];
    ushort* lb2 = &Bs[(w * 32 + 16) * 64];
    ushort* lb3 = &Bs[(w * 32 + 24) * 64];

    int fr = lane & 15, kg8 = (lane >> 4) << 3;
    int wro = (w >> 1) * 64, wco = (w & 1) * 64;
    int sw = (fr & 7) << 3;                  // ds_read granule XOR (elems)

    f32x4 c00 = {}, c01 = {}, c02 = {}, c03 = {};
    f32x4 c10 = {}, c11 = {}, c12 = {}, c13 = {};
    f32x4 c20 = {}, c21 = {}, c22 = {}, c23 = {};
    f32x4 c30 = {}, c31 = {}, c32 = {}, c33 = {};

    for (int s = 0; s < steps; ++s) {
        int kk = s << 6;
        __syncthreads();                     // prior tile fully consumed
        g2lds16(ap0 + kk, la0); g2lds16(ap1 + kk, la1);
        g2lds16(ap2 + kk, la2); g2lds16(ap3 + kk, la3);
        g2lds16(wp0 + kk, lb0); g2lds16(wp1 + kk, lb1);
        g2lds16(wp2 + kk, lb2); g2lds16(wp3 + kk, lb3);
        __syncthreads();                     // drains vmcnt: tile resident
#pragma unroll
        for (int j = 0; j < 2; ++j) {
            int kx = (j * 32 + kg8) ^ sw;
            short8 a0 = RD_A(0), a1 = RD_A(1), a2 = RD_A(2), a3 = RD_A(3);
            short8 b0 = RD_B(0), b1 = RD_B(1), b2 = RD_B(2), b3 = RD_B(3);
            c00 = __builtin_amdgcn_mfma_f32_16x16x32_bf16(a0, b0, c00, 0, 0, 0);
            c01 = __builtin_amdgcn_mfma_f32_16x16x32_bf16(a0, b1, c01, 0, 0, 0);
            c02 = __builtin_amdgcn_mfma_f32_16x16x32_bf16(a0, b2, c02, 0, 0, 0);
            c03 = __builtin_amdgcn_mfma_f32_16x16x32_bf16(a0, b3, c03, 0, 0, 0);
            c10 = __builtin_amdgcn_mfma_f32_16x16x32_bf16(a1, b0, c10, 0, 0, 0);
            c11 = __builtin_amdgcn_mfma_f32_16x16x32_bf16(a1, b1, c11, 0, 0, 0);
            c12 = __builtin_amdgcn_mfma_f32_16x16x32_bf16(a1, b2, c12, 0, 0, 0);
            c13 = __builtin_amdgcn_mfma_f32_16x16x32_bf16(a1, b3, c13, 0, 0, 0);
            c20 = __builtin_amdgcn_mfma_f32_16x16x32_bf16(a2, b0, c20, 0, 0, 0);
            c21 = __builtin_amdgcn_mfma_f32_16x16x32_bf16(a2, b1, c21, 0, 0, 0);
            c22 = __builtin_amdgcn_mfma_f32_16x16x32_bf16(a2, b2, c22, 0, 0, 0);
            c23 = __builtin_amdgcn_mfma_f32_16x16x32_bf16(a2, b3, c23, 0, 0, 0);
            c30 = __builtin_amdgcn_mfma_f32_16x16x32_bf16(a3, b0, c30, 0, 0, 0);
            c31 = __builtin_amdgcn_mfma_f32_16x16x32_bf16(a3, b1, c31, 0, 0, 0);
            c32 = __builtin_amdgcn_mfma_f32_16x16x32_bf16(a3, b2, c32, 0, 0, 0);
            c33 = __builtin_amdgcn_mfma_f32_16x16x32_bf16(a3, b3, c33, 0, 0, 0);
        }
    }

    EPI(c00, 0, 0); EPI(c01, 0, 1); EPI(c02, 0, 2); EPI(c03, 0, 3);
    EPI(c10, 1, 0); EPI(c11, 1, 1); EPI(c12, 1, 2); EPI(c13, 1, 3);
    EPI(c20, 2, 0); EPI(c21, 2, 1); EPI(c22, 2, 2); EPI(c23, 2, 3);
    EPI(c30, 3, 0); EPI(c31, 3, 1); EPI(c32, 3, 2); EPI(c33, 3, 3);
}

// ---------------- split-K fixup (no LN) ----------------
template <int ACT, int OBF16>
__global__ __launch_bounds__(256) void k_fix(const float* __restrict__ part,
                                             const float* __restrict__ bias,
                                             const float* __restrict__ res,
                                             void* __restrict__ Cp,
                                             int M, int N, int S) {
    size_t idx = (size_t)blockIdx.x * 256 + threadIdx.x;
    size_t total = (size_t)M * N / 4;
    if (idx >= total) return;
    size_t e = idx * 4;
    int row = (int)(e / N), col = (int)(e - (size_t)row * N);
    float4 v = *(const float4*)(part + e);
    for (int s = 1; s < S; ++s) {
        const float4 p = *(const float4*)(part + (size_t)s * M * N + e);
        v.x += p.x; v.y += p.y; v.z += p.z; v.w += p.w;
    }
    const float4 bi = *(const float4*)(bias + col);
    v.x += bi.x; v.y += bi.y; v.z += bi.z; v.w += bi.w;
    if (res) {
        const float4 rr = *(const float4*)(res + e);
        v.x += rr.x; v.y += rr.y; v.z += rr.z; v.w += rr.w;
    }
    if (ACT == 1) { v.x = gelu_f(v.x); v.y = gelu_f(v.y); v.z = gelu_f(v.z); v.w = gelu_f(v.w); }
    if (OBF16) {
        ushort o[4] = { f2bf(v.x), f2bf(v.y), f2bf(v.z), f2bf(v.w) };
        *(uint2*)((ushort*)Cp + e) = *(const uint2*)o;
    } else {
        *(float4*)((float*)Cp + e) = v;
    }
}

// ---------------- attention GEMM (bf16 A & W, batched over heads), BK=32 ----
template <int OBF16>
__global__ __launch_bounds__(256) void k_mm(const ushort* __restrict__ A,
                                            const ushort* __restrict__ Wb,
                                            void* __restrict__ Cp,
                                            int M, int N, int K, int ldc, int Nw,
                                            long as_, long ws_, long cs_) {
    __shared__ __align__(16) ushort As[64 * 40];
    __shared__ __align__(16) ushort Bs[64 * 40];
    int z = blockIdx.z;
    A  += (size_t)z * as_;
    Wb += (size_t)z * ws_;
    float*  Cf = (float*)Cp + (size_t)z * cs_;
    ushort* Cb = (ushort*)Cp + (size_t)z * cs_;

    int tid = threadIdx.x;
    int row0 = blockIdx.y * 64, col0 = blockIdx.x * 64;

    int sm = tid >> 2, sp = tid & 3;
    int ar = row0 + sm; if (ar > M - 1) ar = M - 1;
    int wr = col0 + sm; if (wr > N - 1) wr = N - 1;
    const ushort* aptr = A + (size_t)ar * K;

    int lane = tid & 63, wid = tid >> 6;
    int wrr = (wid >> 1) * 32, wcc = (wid & 1) * 32;
    int fr = lane & 15, kg = lane >> 4;

    f32x4 acc[2][2] = {};

    for (int k0 = 0; k0 < K; k0 += 32) {
        *(uint4*)&As[sm * 40 + sp * 8] = *(const uint4*)(aptr + k0 + sp * 8);
        *(uint4*)&Bs[sm * 40 + sp * 8] = *(const uint4*)(Wb + (size_t)wr * K + k0 + sp * 8);
        __syncthreads();
        short8 a0 = *(const short8*)&As[(wrr + fr) * 40 + kg * 8];
        short8 a1 = *(const short8*)&As[(wrr + 16 + fr) * 40 + kg * 8];
        short8 b0 = *(const short8*)&Bs[(wcc + fr) * 40 + kg * 8];
        short8 b1 = *(const short8*)&Bs[(wcc + 16 + fr) * 40 + kg * 8];
        acc[0][0] = __builtin_amdgcn_mfma_f32_16x16x32_bf16(a0, b0, acc[0][0], 0, 0, 0);
        acc[0][1] = __builtin_amdgcn_mfma_f32_16x16x32_bf16(a0, b1, acc[0][1], 0, 0, 0);
        acc[1][0] = __builtin_amdgcn_mfma_f32_16x16x32_bf16(a1, b0, acc[1][0], 0, 0, 0);
        acc[1][1] = __builtin_amdgcn_mfma_f32_16x16x32_bf16(a1, b1, acc[1][1], 0, 0, 0);
        __syncthreads();
    }

#pragma unroll
    for (int fi = 0; fi < 2; fi++)
#pragma unroll
        for (int fj = 0; fj < 2; fj++)
#pragma unroll
            for (int r = 0; r < 4; r++) {
                int row = row0 + wrr + fi * 16 + (lane >> 4) * 4 + r;
                int col = col0 + wcc + fj * 16 + (lane & 15);
                if (row < M && col < Nw) {
                    float v = acc[fi][fj][r];
                    if (OBF16) Cb[(size_t)row * ldc + col] = f2bf(v);
                    else       Cf[(size_t)row * ldc + col] = v;
                }
            }
}

// ---------------- qkv f32 [900,3456] -> rope(q),rope(k) bf16 [16,900,96], v^T bf16 [16,96,928]
__global__ __launch_bounds__(256) void k_rope(const float* __restrict__ qkv,
                                              const float* __restrict__ cs,
                                              const float* __restrict__ sn,
                                              ushort* __restrict__ q,
                                              ushort* __restrict__ k,
                                              ushort* __restrict__ vt) {
    int idx = blockIdx.x * 256 + threadIdx.x;
    if (idx >= NT * NH * DHP) return;
    int t = idx / (NH * DHP);
    int rem = idx - t * (NH * DHP);
    int h = rem / DHP, d = rem - h * DHP;
    size_t oi = ((size_t)h * NT + t) * DHP + d;
    if (d < DHD) {
        const float* base = qkv + (size_t)t * 3 * EMB;
        float c = cs[t * DHD + d], s = sn[t * DHD + d];
        int   d2 = (d < DHH) ? d + DHH : d - DHH;
        float sg = (d < DHH) ? -1.f : 1.f;
        int e = h * DHD + d;
        float qv = base[e] * c + sg * base[h * DHD + d2] * s;
        float kv = base[EMB + e] * c + sg * base[EMB + h * DHD + d2] * s;
        q[oi] = f2bf(qv);
        k[oi] = f2bf(kv);
        vt[((size_t)h * DHP + d) * KVP + t] = f2bf(base[2 * EMB + e]);
    } else {
        q[oi] = 0;
        k[oi] = 0;
    }
}

// zero v^T pad columns t in [900,928)  (run once; later layers never write pads)
__global__ __launch_bounds__(256) void k_vpad(ushort* __restrict__ vt) {
    int idx = blockIdx.x * 256 + threadIdx.x;
    int tot = NH * DHP * (KVP - NT);
    if (idx >= tot) return;
    int pw = KVP - NT;
    int hd = idx / pw, j = idx - hd * pw;
    vt[(size_t)hd * KVP + NT + j] = 0;
}

// ---------------- softmax: S f32 [16*900][928] -> P bf16 (pad cols zeroed) ----------------
__global__ __launch_bounds__(256) void k_sm(const float* __restrict__ S,
                                            ushort* __restrict__ P) {
    int row = blockIdx.x * 4 + (threadIdx.x >> 6);
    int lane = threadIdx.x & 63;
    const float* sp = S + (size_t)row * KVP;
    ushort* pp = P + (size_t)row * KVP;
    float v[15];
#pragma unroll
    for (int i = 0; i < 15; i++) {
        int kt = lane + i * 64;
        v[i] = (kt < NT) ? sp[kt] : -1e30f;
    }
    float mx = -1e30f;
#pragma unroll
    for (int i = 0; i < 15; i++) mx = fmaxf(mx, v[i]);
    for (int off = 32; off; off >>= 1) mx = fmaxf(mx, __shfl_xor(mx, off, 64));
    float sum = 0.f;
#pragma unroll
    for (int i = 0; i < 15; i++) {
        int kt = lane + i * 64;
        v[i] = (kt < NT) ? __expf(v[i] - mx) : 0.f;
        sum += v[i];
    }
    for (int off = 32; off; off >>= 1) sum += __shfl_xor(sum, off, 64);
    float inv = 1.f / sum;
#pragma unroll
    for (int i = 0; i < 15; i++) {
        int kt = lane + i * 64;
        if (kt < KVP) pp[kt] = f2bf(v[i] * inv);
    }
}

extern "C" void kernel_launch(void* const* d_in, const int* in_sizes, int n_in,
                              void* d_out, int out_size, void* d_ws, size_t ws_size,
                              hipStream_t stream) {
    const float* pix     = (const float*)d_in[0];
    const float* patch_w = (const float*)d_in[1];
    const float* patch_b = (const float*)d_in[2];
    const float* pos_emb = (const float*)d_in[3];
    const float* cosb    = (const float*)d_in[4];
    const float* sinb    = (const float*)d_in[5];
    const float* ln1_w   = (const float*)d_in[6];
    const float* ln1_b   = (const float*)d_in[7];
    const float* qkv_w   = (const float*)d_in[8];
    const float* qkv_b   = (const float*)d_in[9];
    const float* proj_w  = (const float*)d_in[10];
    const float* proj_b  = (const float*)d_in[11];
    const float* ln2_w   = (const float*)d_in[12];
    const float* ln2_b   = (const float*)d_in[13];
    const float* fc1_w   = (const float*)d_in[14];
    const float* fc1_b   = (const float*)d_in[15];
    const float* fc2_w   = (const float*)d_in[16];
    const float* fc2_b   = (const float*)d_in[17];
    const float* dsn_w   = (const float*)d_in[18];
    const float* dsn_b   = (const float*)d_in[19];
    const float* ds1_w   = (const float*)d_in[20];
    const float* ds1_b   = (const float*)d_in[21];
    const float* ds2_w   = (const float*)d_in[22];
    const float* ds2_b   = (const float*)d_in[23];
    const float* mn_w    = (const float*)d_in[24];
    const float* mn_b    = (const float*)d_in[25];
    const float* mf1_w   = (const float*)d_in[26];
    const float* mf1_b   = (const float*)d_in[27];
    const float* mf2_w   = (const float*)d_in[28];
    const float* mf2_b   = (const float*)d_in[29];
    float* out = (float*)d_out;

    // ---- workspace carve ----
    float* wsf = (float*)d_ws;
    size_t off = 0;
    auto af = [&](size_t n) { float* p = wsf + off; off += (n + 3) & ~(size_t)3; return p; };
    float* h    = af((size_t)NT * EMB);
    float* qkv  = af((size_t)NT * 3 * EMB);
    float* part = af((size_t)8 * NT * EMB);       // max split-K partials (33.2 MB)
    float* S    = af((size_t)NH * NT * KVP);      // attention scores f32
    ushort* wsh = (ushort*)(wsf + off);
    size_t hoff = 0;
    auto ah = [&](size_t n) { ushort* p = wsh + hoff; hoff += (n + 7) & ~(size_t)7; return p; };
    ushort* hn  = ah((size_t)NT * EMB);           // ln1/ln2/merger-ln output
    ushort* hn2 = ah((size_t)NM * MHD);           // deepstack-ln output
    ushort* qb  = ah((size_t)NH * NT * DHP);
    ushort* kb  = ah((size_t)NH * NT * DHP);
    ushort* vt  = ah((size_t)NH * DHP * KVP);
    ushort* P   = ah((size_t)NH * NT * KVP);
    ushort* ob  = ah((size_t)NT * EMB);
    ushort* t1  = ah((size_t)NT * FFD);
    ushort* xp  = t1;
    // bf16 weight mirrors
    ushort* w_patch = ah((size_t)EMB * 1536);
    ushort* w_qkv   = ah((size_t)NL * 3 * EMB * EMB);
    ushort* w_proj  = ah((size_t)NL * EMB * EMB);
    ushort* w_fc1   = ah((size_t)NL * FFD * EMB);
    ushort* w_fc2   = ah((size_t)NL * EMB * FFD);
    ushort* w_ds1   = ah((size_t)2 * MHD * MHD);
    ushort* w_ds2   = ah((size_t)2 * OUTD * MHD);
    ushort* w_mf1   = ah((size_t)MHD * MHD);
    ushort* w_mf2   = ah((size_t)OUTD * MHD);

    const long QS = (long)NT * DHP;
    const long VS = (long)DHP * KVP;
    const long SS = (long)NT * KVP;
    const long MN = (long)NT * EMB;

    const int MB2  = (NT + 127) / 128;  // 8  (dense 128-tiles)
    const int MBm2 = (NM + 127) / 128;  // 2
    const int MBa  = (NT + 63) / 64;    // 15 (attention 64-tiles)
    auto fixg = [](int M, int N) { return dim3(((size_t)M * N / 4 + 255) / 256); };
    auto cvt = [&](const float* s, ushort* d, size_t n) {
        k_cvt<<<dim3((unsigned)((n / 4 + 255) / 256)), 256, 0, stream>>>(s, d, (int)(n / 4));
    };

    // ---- weight pre-conversion (once per forward) ----
    cvt(patch_w, w_patch, (size_t)EMB * 1536);
    cvt(qkv_w,   w_qkv,   (size_t)NL * 3 * EMB * EMB);
    cvt(proj_w,  w_proj,  (size_t)NL * EMB * EMB);
    cvt(fc1_w,   w_fc1,   (size_t)NL * FFD * EMB);
    cvt(fc2_w,   w_fc2,   (size_t)NL * EMB * FFD);
    cvt(ds1_w,   w_ds1,   (size_t)2 * MHD * MHD);
    cvt(ds2_w,   w_ds2,   (size_t)2 * OUTD * MHD);
    cvt(mf1_w,   w_mf1,   (size_t)MHD * MHD);
    cvt(mf2_w,   w_mf2,   (size_t)OUTD * MHD);

    k_patch<<<dim3((NT * 1536 + 255) / 256), 256, 0, stream>>>(pix, xp);
    k_vpad<<<dim3((NH * DHP * (KVP - NT) + 255) / 256), 256, 0, stream>>>(vt);
    // patch: M=900 N=1152 K=1536, S=6 (Kc=256) -> 432 blocks
    k_b2<0, 0, 1><<<dim3(MB2, EMB / 128, 6), 256, 0, stream>>>(
        xp, w_patch, nullptr, nullptr, nullptr, part, NT, EMB, 1536, 6);
    k_fixln<<<NT, 256, 0, stream>>>(part, patch_b, pos_emb, h,
                                    ln1_w, ln1_b, hn, EMB, 6, MN);

    for (int l = 0; l < NL; ++l) {
        // qkv: M=900 N=3456 K=1152, S=2 (Kc=576) -> 432 blocks
        k_b2<0, 0, 1><<<dim3(MB2, 3 * EMB / 128, 2), 256, 0, stream>>>(
            hn, w_qkv + (size_t)l * 3 * EMB * EMB, nullptr, nullptr, nullptr, part,
            NT, 3 * EMB, EMB, 2);
        k_fix<0, 0><<<fixg(NT, 3 * EMB), 256, 0, stream>>>(
            part, qkv_b + l * 3 * EMB, nullptr, qkv, NT, 3 * EMB, 2);
        k_rope<<<dim3((NT * NH * DHP + 255) / 256), 256, 0, stream>>>(
            qkv, cosb, sinb, qb, kb, vt);
        // S = Q @ K^T (per head)
        k_mm<0><<<dim3(MBa, MBa, NH), 256, 0, stream>>>(
            qb, kb, S, NT, NT, DHP, KVP, NT, QS, QS, SS);
        k_sm<<<dim3(NH * NT / 4), 256, 0, stream>>>(S, P);
        // O = P @ V (per head) -> ob bf16 [900][1152]
        k_mm<1><<<dim3(2, MBa, NH), 256, 0, stream>>>(
            P, vt, ob, NT, DHD, KVP, EMB, DHD, SS, VS, DHD);
        // proj: M=900 N=1152 K=1152, S=6 (Kc=192) -> 432 blocks
        k_b2<0, 0, 1><<<dim3(MB2, EMB / 128, 6), 256, 0, stream>>>(
            ob, w_proj + (size_t)l * EMB * EMB, nullptr, nullptr, nullptr, part,
            NT, EMB, EMB, 6);
        k_fixln<<<NT, 256, 0, stream>>>(part, proj_b + l * EMB, h, h,
                                        ln2_w + l * EMB, ln2_b + l * EMB, hn,
                                        EMB, 6, MN);
        // fc1: M=900 N=4608 K=1152, S=1 -> 288 blocks, direct gelu bf16
        k_b2<1, 1, 0><<<dim3(MB2, FFD / 128, 1), 256, 0, stream>>>(
            hn, w_fc1 + (size_t)l * FFD * EMB, fc1_b + l * FFD, nullptr, t1,
            nullptr, NT, FFD, EMB, 1);
        // fc2: M=900 N=1152 K=4608, S=4 (Kc=1152) -> 288 blocks
        const float* nlw = (l == NL - 1) ? mn_w : ln1_w + (l + 1) * EMB;
        const float* nlb = (l == NL - 1) ? mn_b : ln1_b + (l + 1) * EMB;
        k_b2<0, 0, 1><<<dim3(MB2, EMB / 128, 4), 256, 0, stream>>>(
            t1, w_fc2 + (size_t)l * EMB * FFD, nullptr, nullptr, nullptr, part,
            NT, EMB, FFD, 4);
        k_fixln<<<NT, 256, 0, stream>>>(part, fc2_b + l * EMB, h, h,
                                        nlw, nlb, hn, EMB, 4, MN);
        if (l == 2 || l == 5) {
            int d = (l == 2) ? 0 : 1;
            k_ln<<<NM, 256, 0, stream>>>(h, dsn_w + d * MHD, dsn_b + d * MHD, hn2, MHD);
            // ds1: M=225 N=4608 K=4608, S=8 (Kc=576) -> 576 blocks
            k_b2<0, 0, 1><<<dim3(MBm2, MHD / 128, 8), 256, 0, stream>>>(
                hn2, w_ds1 + (size_t)d * MHD * MHD, nullptr, nullptr, nullptr, part,
                NM, MHD, MHD, 8);
            k_fix<1, 1><<<fixg(NM, MHD), 256, 0, stream>>>(part, ds1_b + d * MHD,
                                                           nullptr, t1, NM, MHD, 8);
            // ds2: M=225 N=2048 K=4608, S=12 (Kc=384) -> 384 blocks
            k_b2<0, 0, 1><<<dim3(MBm2, OUTD / 128, 12), 256, 0, stream>>>(
                t1, w_ds2 + (size_t)d * OUTD * MHD, nullptr, nullptr, nullptr, part,
                NM, OUTD, MHD, 12);
            k_fix<0, 0><<<fixg(NM, OUTD), 256, 0, stream>>>(
                part, ds2_b + d * OUTD, nullptr, out + (size_t)d * NM * OUTD,
                NM, OUTD, 12);
        }
    }
    // merger: hn already holds merger-LN output ([900][1152] == [225][4608])
    k_b2<0, 0, 1><<<dim3(MBm2, MHD / 128, 8), 256, 0, stream>>>(
        hn, w_mf1, nullptr, nullptr, nullptr, part, NM, MHD, MHD, 8);
    k_fix<1, 1><<<fixg(NM, MHD), 256, 0, stream>>>(part, mf1_b, nullptr, t1, NM, MHD, 8);
    k_b2<0, 0, 1><<<dim3(MBm2, OUTD / 128, 12), 256, 0, stream>>>(
        t1, w_mf2, nullptr, nullptr, nullptr, part, NM, OUTD, MHD, 12);
    k_fix<0, 0><<<fixg(NM, OUTD), 256, 0, stream>>>(
        part, mf2_b, nullptr, out + (size_t)2 * NM * OUTD, NM, OUTD, 12);
}

// Round 14
// 1463.141 us; speedup vs baseline: 1.1113x; 1.1113x over previous
//
#include <hip/hip_runtime.h>
#include <hip/hip_bf16.h>
#include <cstdint>

#define NT   900
#define EMB  1152
#define NH   16
#define DHD  72
#define DHH  36
#define DHP  96      // padded head dim (3*32)
#define KVP  928     // padded kv length (29*32)
#define NL   6
#define FFD  4608
#define MHD  4608
#define OUTD 2048
#define NM   225

typedef __attribute__((ext_vector_type(8))) short short8;
typedef __attribute__((ext_vector_type(4))) float f32x4;

__device__ __forceinline__ ushort f2bf(float f) {
    uint32_t u = __float_as_uint(f);
    uint32_t r = u + 0x7FFF + ((u >> 16) & 1);
    return (ushort)(r >> 16);
}
__device__ __forceinline__ float gelu_f(float x) {
    return 0.5f * x * (1.0f + tanhf(0.7978845608f * (x + 0.044715f * x * x * x)));
}

// async global -> LDS, 16B per lane (lds dest wave-uniform base; HW adds lane*16)
__device__ __forceinline__ void g2lds16(const ushort* g, ushort* l) {
    __builtin_amdgcn_global_load_lds(
        (const __attribute__((address_space(1))) unsigned int*)g,
        (__attribute__((address_space(3))) unsigned int*)l, 16, 0, 0);
}

// ---------------- weight f32 -> bf16 pre-conversion ----------------
__global__ __launch_bounds__(256) void k_cvt(const float* __restrict__ src,
                                             ushort* __restrict__ dst, int n4) {
    int idx = blockIdx.x * 256 + threadIdx.x;
    if (idx >= n4) return;
    const float4 v = *(const float4*)(src + (size_t)idx * 4);
    ushort o[4] = { f2bf(v.x), f2bf(v.y), f2bf(v.z), f2bf(v.w) };
    *(uint2*)(dst + (size_t)idx * 4) = *(const uint2*)o;
}

// ---------------- patch extraction: pixels -> bf16 [900, 1536] ----------------
__global__ __launch_bounds__(256) void k_patch(const float* __restrict__ pix,
                                               ushort* __restrict__ xp) {
    int idx = blockIdx.x * 256 + threadIdx.x;
    if (idx >= NT * 1536) return;
    int t = idx / 1536, f = idx - t * 1536;
    int mw = t & 1, mh = (t >> 1) & 1;
    int tq = t >> 2;
    int jj = tq % 15, ii = tq / 15;
    int pw = f & 15, ph = (f >> 4) & 15, c = f >> 9;
    int Hi = (ii * 2 + mh) * 16 + ph;
    int Wi = (jj * 2 + mw) * 16 + pw;
    float p = pix[((size_t)c * 480 + Hi) * 480 + Wi];
    xp[idx] = f2bf((p - 127.5f) * (1.0f / 127.5f));
}

// ---------------- layernorm f32 in -> bf16 out, one block per row ----------------
__global__ __launch_bounds__(256) void k_ln(const float* __restrict__ x,
                                            const float* __restrict__ w,
                                            const float* __restrict__ b,
                                            ushort* __restrict__ y, int C) {
    int row = blockIdx.x;
    int tid = threadIdx.x;
    const float* xr = x + (size_t)row * C;
    float s = 0.f, ss = 0.f;
    for (int c = tid; c < C; c += 256) { float v = xr[c]; s += v; ss += v * v; }
    for (int off = 32; off; off >>= 1) {
        s  += __shfl_down(s,  off, 64);
        ss += __shfl_down(ss, off, 64);
    }
    __shared__ float rs[4], rss[4];
    int wid = tid >> 6, lane = tid & 63;
    if (lane == 0) { rs[wid] = s; rss[wid] = ss; }
    __syncthreads();
    float S  = rs[0] + rs[1] + rs[2] + rs[3];
    float SS = rss[0] + rss[1] + rss[2] + rss[3];
    float mu  = S / C;
    float var = SS / C - mu * mu;
    float inv = rsqrtf(var + 1e-6f);
    ushort* yr = y + (size_t)row * C;
    for (int c = tid; c < C; c += 256) yr[c] = f2bf((xr[c] - mu) * inv * w[c] + b[c]);
}

// ---------------- fused split-K reduce + bias + residual + LayerNorm ----------------
__global__ __launch_bounds__(256) void k_fixln(const float* __restrict__ part,
                                               const float* __restrict__ bias,
                                               const float* __restrict__ res,
                                               float* __restrict__ hout,
                                               const float* __restrict__ lw,
                                               const float* __restrict__ lb,
                                               ushort* __restrict__ y,
                                               int C, int S, long MN) {
    int row = blockIdx.x, tid = threadIdx.x;
    int C4 = C >> 2;
    const float* prow = part + (size_t)row * C;
    const float* rrow = res + (size_t)row * C;
    float* hrow = hout + (size_t)row * C;
    ushort* yrow = y + (size_t)row * C;

    float4 vals[2];
    float s = 0.f, ss = 0.f;
    int idx[2] = { tid, tid + 256 };
#pragma unroll
    for (int it = 0; it < 2; ++it) {
        int c4 = idx[it];
        if (c4 < C4) {
            float4 v = *(const float4*)(prow + c4 * 4);
            for (int sI = 1; sI < S; ++sI) {
                const float4 p = *(const float4*)(prow + (size_t)sI * MN + c4 * 4);
                v.x += p.x; v.y += p.y; v.z += p.z; v.w += p.w;
            }
            const float4 bi = *(const float4*)(bias + c4 * 4);
            v.x += bi.x; v.y += bi.y; v.z += bi.z; v.w += bi.w;
            const float4 rr = *(const float4*)(rrow + c4 * 4);
            v.x += rr.x; v.y += rr.y; v.z += rr.z; v.w += rr.w;
            *(float4*)(hrow + c4 * 4) = v;
            vals[it] = v;
            s  += v.x + v.y + v.z + v.w;
            ss += v.x * v.x + v.y * v.y + v.z * v.z + v.w * v.w;
        }
    }
    for (int off = 32; off; off >>= 1) {
        s  += __shfl_down(s,  off, 64);
        ss += __shfl_down(ss, off, 64);
    }
    __shared__ float rs[4], rss[4];
    int wid = tid >> 6, lane = tid & 63;
    if (lane == 0) { rs[wid] = s; rss[wid] = ss; }
    __syncthreads();
    float St  = rs[0] + rs[1] + rs[2] + rs[3];
    float SSt = rss[0] + rss[1] + rss[2] + rss[3];
    float mu  = St / C;
    float var = SSt / C - mu * mu;
    float inv = rsqrtf(var + 1e-6f);
#pragma unroll
    for (int it = 0; it < 2; ++it) {
        int c4 = idx[it];
        if (c4 < C4) {
            float4 v = vals[it];
            const float4 w4 = *(const float4*)(lw + c4 * 4);
            const float4 b4 = *(const float4*)(lb + c4 * 4);
            ushort o[4] = { f2bf((v.x - mu) * inv * w4.x + b4.x),
                            f2bf((v.y - mu) * inv * w4.y + b4.y),
                            f2bf((v.z - mu) * inv * w4.z + b4.z),
                            f2bf((v.w - mu) * inv * w4.w + b4.w) };
            *(uint2*)(yrow + c4 * 4) = *(const uint2*)o;
        }
    }
}

// ---------------- dense MFMA GEMM, 64x64 tile, BK=64, gload_lds + XOR swizzle ----
// C[M,N] = act(A[M,K](bf16) @ W[N,K]^T(bf16) + bias) + res   (N % 64 == 0)
// grid (ceil(M/64), N/64, S). SPLIT=1: raw partials to part[z][M][N].
template <int ACT, int OBF16, int SPLIT>
__global__ __launch_bounds__(256) void k_bgs(const ushort* __restrict__ A,
                                             const ushort* __restrict__ W,
                                             const float* __restrict__ bias,
                                             const float* __restrict__ res,
                                             void* __restrict__ Cp,
                                             float* __restrict__ part,
                                             int M, int N, int K, int S) {
    __shared__ __align__(16) ushort As[64 * 64];
    __shared__ __align__(16) ushort Bs[64 * 64];
    int tid = threadIdx.x;
    int row0 = blockIdx.x * 64, col0 = blockIdx.y * 64;
    int z = blockIdx.z;
    int Kc = K / S;              // multiple of 64
    int kbeg = z * Kc;
    int steps = Kc >> 6;

    int w = tid >> 6, lane = tid & 63;
    int lrow = lane >> 3;                    // 0..7
    int cg   = ((lane & 7) ^ lrow) << 3;     // pre-swizzled source granule (elems)

    int ar0 = row0 + w * 16 + lrow; if (ar0 > M - 1) ar0 = M - 1;
    int ar1 = row0 + w * 16 + 8 + lrow; if (ar1 > M - 1) ar1 = M - 1;
    int wr0 = col0 + w * 16 + lrow;
    int wr1 = wr0 + 8;
    const ushort* ap0 = A + (size_t)ar0 * K + kbeg + cg;
    const ushort* ap1 = A + (size_t)ar1 * K + kbeg + cg;
    const ushort* wp0 = W + (size_t)wr0 * K + kbeg + cg;
    const ushort* wp1 = W + (size_t)wr1 * K + kbeg + cg;
    ushort* asd0 = &As[(w * 16) * 64];
    ushort* asd1 = &As[(w * 16 + 8) * 64];
    ushort* bsd0 = &Bs[(w * 16) * 64];
    ushort* bsd1 = &Bs[(w * 16 + 8) * 64];

    int fr = lane & 15, kg8 = (lane >> 4) << 3;
    int wrr = (w >> 1) * 32, wcc = (w & 1) * 32;
    int sw = (fr & 7) << 3;

    f32x4 acc[2][2] = {};
    for (int s = 0; s < steps; ++s) {
        int kk = s << 6;
        __syncthreads();
        g2lds16(ap0 + kk, asd0);
        g2lds16(ap1 + kk, asd1);
        g2lds16(wp0 + kk, bsd0);
        g2lds16(wp1 + kk, bsd1);
        __syncthreads();
#pragma unroll
        for (int j = 0; j < 2; ++j) {
            int ko = j * 32 + kg8;
            int kx = ko ^ sw;
            short8 a0 = *(const short8*)&As[(wrr + fr) * 64 + kx];
            short8 a1 = *(const short8*)&As[(wrr + 16 + fr) * 64 + kx];
            short8 b0 = *(const short8*)&Bs[(wcc + fr) * 64 + kx];
            short8 b1 = *(const short8*)&Bs[(wcc + 16 + fr) * 64 + kx];
            acc[0][0] = __builtin_amdgcn_mfma_f32_16x16x32_bf16(a0, b0, acc[0][0], 0, 0, 0);
            acc[0][1] = __builtin_amdgcn_mfma_f32_16x16x32_bf16(a0, b1, acc[0][1], 0, 0, 0);
            acc[1][0] = __builtin_amdgcn_mfma_f32_16x16x32_bf16(a1, b0, acc[1][0], 0, 0, 0);
            acc[1][1] = __builtin_amdgcn_mfma_f32_16x16x32_bf16(a1, b1, acc[1][1], 0, 0, 0);
        }
    }

#pragma unroll
    for (int fi = 0; fi < 2; fi++)
#pragma unroll
        for (int fj = 0; fj < 2; fj++)
#pragma unroll
            for (int r = 0; r < 4; r++) {
                int row = row0 + wrr + fi * 16 + (lane >> 4) * 4 + r;
                int col = col0 + wcc + fj * 16 + fr;
                if (row < M) {
                    if (SPLIT) {
                        part[((size_t)z * M + row) * N + col] = acc[fi][fj][r];
                    } else {
                        float v = acc[fi][fj][r] + bias[col];
                        if (res) v += res[(size_t)row * N + col];
                        if (ACT == 1) v = gelu_f(v);
                        if (OBF16) ((ushort*)Cp)[(size_t)row * N + col] = f2bf(v);
                        else       ((float*)Cp)[(size_t)row * N + col] = v;
                    }
                }
            }
}

// ---------------- split-K fixup (no LN) ----------------
template <int ACT, int OBF16>
__global__ __launch_bounds__(256) void k_fix(const float* __restrict__ part,
                                             const float* __restrict__ bias,
                                             const float* __restrict__ res,
                                             void* __restrict__ Cp,
                                             int M, int N, int S) {
    size_t idx = (size_t)blockIdx.x * 256 + threadIdx.x;
    size_t total = (size_t)M * N / 4;
    if (idx >= total) return;
    size_t e = idx * 4;
    int row = (int)(e / N), col = (int)(e - (size_t)row * N);
    float4 v = *(const float4*)(part + e);
    for (int s = 1; s < S; ++s) {
        const float4 p = *(const float4*)(part + (size_t)s * M * N + e);
        v.x += p.x; v.y += p.y; v.z += p.z; v.w += p.w;
    }
    const float4 bi = *(const float4*)(bias + col);
    v.x += bi.x; v.y += bi.y; v.z += bi.z; v.w += bi.w;
    if (res) {
        const float4 rr = *(const float4*)(res + e);
        v.x += rr.x; v.y += rr.y; v.z += rr.z; v.w += rr.w;
    }
    if (ACT == 1) { v.x = gelu_f(v.x); v.y = gelu_f(v.y); v.z = gelu_f(v.z); v.w = gelu_f(v.w); }
    if (OBF16) {
        ushort o[4] = { f2bf(v.x), f2bf(v.y), f2bf(v.z), f2bf(v.w) };
        *(uint2*)((ushort*)Cp + e) = *(const uint2*)o;
    } else {
        *(float4*)((float*)Cp + e) = v;
    }
}

// ---------------- qkv f32 [900,3456] -> rope(q),rope(k) bf16 [16,900,96], v^T bf16 [16,96,928]
__global__ __launch_bounds__(256) void k_rope(const float* __restrict__ qkv,
                                              const float* __restrict__ cs,
                                              const float* __restrict__ sn,
                                              ushort* __restrict__ q,
                                              ushort* __restrict__ k,
                                              ushort* __restrict__ vt) {
    int idx = blockIdx.x * 256 + threadIdx.x;
    if (idx >= NT * NH * DHP) return;
    int t = idx / (NH * DHP);
    int rem = idx - t * (NH * DHP);
    int h = rem / DHP, d = rem - h * DHP;
    size_t oi = ((size_t)h * NT + t) * DHP + d;
    if (d < DHD) {
        const float* base = qkv + (size_t)t * 3 * EMB;
        float c = cs[t * DHD + d], s = sn[t * DHD + d];
        int   d2 = (d < DHH) ? d + DHH : d - DHH;
        float sg = (d < DHH) ? -1.f : 1.f;
        int e = h * DHD + d;
        float qv = base[e] * c + sg * base[h * DHD + d2] * s;
        float kv = base[EMB + e] * c + sg * base[EMB + h * DHD + d2] * s;
        q[oi] = f2bf(qv);
        k[oi] = f2bf(kv);
        vt[((size_t)h * DHP + d) * KVP + t] = f2bf(base[2 * EMB + e]);
    } else {
        q[oi] = 0;
        k[oi] = 0;
    }
}

// zero v^T pad columns t in [900,928)
__global__ __launch_bounds__(256) void k_vpad(ushort* __restrict__ vt) {
    int idx = blockIdx.x * 256 + threadIdx.x;
    int tot = NH * DHP * (KVP - NT);
    if (idx >= tot) return;
    int pw = KVP - NT;
    int hd = idx / pw, j = idx - hd * pw;
    vt[(size_t)hd * KVP + NT + j] = 0;
}

// ---------------- flash attention with KV-split (4 splits of 15 kv-tiles) ----
// grid (15 q-tiles, 16 heads, 4 splits), 256 thr (4 waves x 16 q rows).
// Writes UNNORMALIZED partials: Op[z][h][q][80] f32, ml[z][h][q][2] = (m, l).
__global__ __launch_bounds__(256) void k_fa2(const ushort* __restrict__ qg,
                                             const ushort* __restrict__ kg,
                                             const ushort* __restrict__ vg,
                                             float* __restrict__ Op,
                                             float* __restrict__ ml) {
    __shared__ __align__(16) ushort Qs[64 * 104];
    __shared__ __align__(16) ushort Ks[64 * 104];
    __shared__ __align__(16) ushort Vs[80 * 76];
    __shared__ __align__(16) ushort Ps[4][16 * 76];

    const int h  = blockIdx.y;
    const int q0 = blockIdx.x * 64;
    const int z  = blockIdx.z;
    const int s0 = z * 4;
    const int s1 = (z == 3) ? 15 : s0 + 4;
    const int tid = threadIdx.x;
    const int lane = tid & 63, w = tid >> 6;
    const int fr = lane & 15, g = lane >> 4;

    const ushort* qh = qg + (size_t)h * (NT * DHP);
    const ushort* kh = kg + (size_t)h * (NT * DHP);
    const ushort* vh = vg + (size_t)h * (DHP * KVP);

    for (int i = tid; i < 768; i += 256) {
        int row = i / 12, cj = i % 12;
        int gr = q0 + row; if (gr > NT - 1) gr = NT - 1;
        *(uint4*)&Qs[row * 104 + cj * 8] = *(const uint4*)(qh + (size_t)gr * DHP + cj * 8);
    }
    __syncthreads();
    short8 aq[3];
#pragma unroll
    for (int ks = 0; ks < 3; ++ks)
        aq[ks] = *(const short8*)&Qs[(w * 16 + fr) * 104 + ks * 32 + g * 8];

    uint4 rk[3], rv[3];
    auto loadKV = [&](int s) {
        int k0 = s * 64;
#pragma unroll
        for (int j = 0; j < 3; ++j) {
            int i = tid + j * 256;
            int row = i / 12, cj = i % 12;
            int gr = k0 + row; if (gr > NT - 1) gr = NT - 1;
            rk[j] = *(const uint4*)(kh + (size_t)gr * DHP + cj * 8);
        }
#pragma unroll
        for (int j = 0; j < 3; ++j) {
            int i = tid + j * 256;
            if (i < 640) {
                int row = i >> 3, cj = i & 7;
                int gc = k0 + cj * 8; if (gc > KVP - 8) gc = KVP - 8;
                rv[j] = *(const uint4*)(vh + (size_t)row * KVP + gc);
            }
        }
    };
    auto writeKV = [&]() {
#pragma unroll
        for (int j = 0; j < 3; ++j) {
            int i = tid + j * 256;
            int row = i / 12, cj = i % 12;
            *(uint4*)&Ks[row * 104 + cj * 8] = rk[j];
        }
#pragma unroll
        for (int j = 0; j < 3; ++j) {
            int i = tid + j * 256;
            if (i < 640) {
                int row = i >> 3, cj = i & 7;
                *(uint4*)&Vs[row * 76 + cj * 8] = rv[j];
            }
        }
    };

    float m[4] = { -1e30f, -1e30f, -1e30f, -1e30f };
    float lsum[4] = {};
    f32x4 o[5] = {};
    ushort* pw = &Ps[w][0];

    loadKV(s0);
    for (int s = s0; s < s1; ++s) {
        __syncthreads();
        writeKV();
        if (s + 1 < s1) loadKV(s + 1);
        __syncthreads();
        f32x4 sc[4] = {};
#pragma unroll
        for (int nt = 0; nt < 4; ++nt)
#pragma unroll
            for (int ks = 0; ks < 3; ++ks) {
                short8 b = *(const short8*)&Ks[(nt * 16 + fr) * 104 + ks * 32 + g * 8];
                sc[nt] = __builtin_amdgcn_mfma_f32_16x16x32_bf16(aq[ks], b, sc[nt], 0, 0, 0);
            }
        int kbase = s * 64;
        if (kbase + 64 > NT) {
#pragma unroll
            for (int nt = 0; nt < 4; ++nt)
                if (kbase + nt * 16 + fr >= NT) {
                    sc[nt][0] = -1e30f; sc[nt][1] = -1e30f;
                    sc[nt][2] = -1e30f; sc[nt][3] = -1e30f;
                }
        }
#pragma unroll
        for (int r = 0; r < 4; ++r) {
            float tm = fmaxf(fmaxf(sc[0][r], sc[1][r]), fmaxf(sc[2][r], sc[3][r]));
#pragma unroll
            for (int off = 1; off < 16; off <<= 1) tm = fmaxf(tm, __shfl_xor(tm, off, 64));
            float mn = fmaxf(m[r], tm);
            float scale = __expf(m[r] - mn);
            m[r] = mn;
            float ps = 0.f;
#pragma unroll
            for (int nt = 0; nt < 4; ++nt) {
                float p = __expf(sc[nt][r] - mn);
                ps += p;
                pw[(g * 4 + r) * 76 + nt * 16 + fr] = f2bf(p);
            }
#pragma unroll
            for (int off = 1; off < 16; off <<= 1) ps += __shfl_xor(ps, off, 64);
            lsum[r] = lsum[r] * scale + ps;
#pragma unroll
            for (int dt = 0; dt < 5; ++dt) o[dt][r] *= scale;
        }
#pragma unroll
        for (int kt = 0; kt < 2; ++kt) {
            short8 a = *(const short8*)&pw[fr * 76 + kt * 32 + g * 8];
#pragma unroll
            for (int dt = 0; dt < 5; ++dt) {
                short8 b = *(const short8*)&Vs[(dt * 16 + fr) * 76 + kt * 32 + g * 8];
                o[dt] = __builtin_amdgcn_mfma_f32_16x16x32_bf16(a, b, o[dt], 0, 0, 0);
            }
        }
    }
    // unnormalized partial write
#pragma unroll
    for (int r = 0; r < 4; ++r) {
        int q = q0 + w * 16 + g * 4 + r;
        if (fr == 0 && q < NT) {
            size_t mi = (((size_t)z * NH + h) * NT + q) * 2;
            ml[mi]     = m[r];
            ml[mi + 1] = lsum[r];
        }
    }
#pragma unroll
    for (int dt = 0; dt < 5; ++dt)
#pragma unroll
        for (int r = 0; r < 4; ++r) {
            int q = q0 + w * 16 + g * 4 + r;
            int d = dt * 16 + fr;
            if (q < NT)
                Op[(((size_t)z * NH + h) * NT + q) * 80 + d] = o[dt][r];
        }
}

// ---------------- combine 4 attention splits -> ob bf16 [900][1152] ----------------
__global__ __launch_bounds__(256) void k_cmb(const float* __restrict__ Op,
                                             const float* __restrict__ ml,
                                             ushort* __restrict__ ob) {
    int idx = blockIdx.x * 256 + threadIdx.x;
    if (idx >= NH * NT * DHD) return;
    int h = idx / (NT * DHD);
    int rem = idx - h * NT * DHD;
    int q = rem / DHD, d = rem - q * DHD;
    float mz[4], lz[4];
    float M = -1e30f;
#pragma unroll
    for (int z = 0; z < 4; ++z) {
        size_t mi = (((size_t)z * NH + h) * NT + q) * 2;
        mz[z] = ml[mi];
        lz[z] = ml[mi + 1];
        M = fmaxf(M, mz[z]);
    }
    float L = 0.f, O = 0.f;
#pragma unroll
    for (int z = 0; z < 4; ++z) {
        float wz = __expf(mz[z] - M);
        L += lz[z] * wz;
        O += Op[(((size_t)z * NH + h) * NT + q) * 80 + d] * wz;
    }
    ob[(size_t)q * EMB + h * DHD + d] = f2bf(O / L);
}

extern "C" void kernel_launch(void* const* d_in, const int* in_sizes, int n_in,
                              void* d_out, int out_size, void* d_ws, size_t ws_size,
                              hipStream_t stream) {
    const float* pix     = (const float*)d_in[0];
    const float* patch_w = (const float*)d_in[1];
    const float* patch_b = (const float*)d_in[2];
    const float* pos_emb = (const float*)d_in[3];
    const float* cosb    = (const float*)d_in[4];
    const float* sinb    = (const float*)d_in[5];
    const float* ln1_w   = (const float*)d_in[6];
    const float* ln1_b   = (const float*)d_in[7];
    const float* qkv_w   = (const float*)d_in[8];
    const float* qkv_b   = (const float*)d_in[9];
    const float* proj_w  = (const float*)d_in[10];
    const float* proj_b  = (const float*)d_in[11];
    const float* ln2_w   = (const float*)d_in[12];
    const float* ln2_b   = (const float*)d_in[13];
    const float* fc1_w   = (const float*)d_in[14];
    const float* fc1_b   = (const float*)d_in[15];
    const float* fc2_w   = (const float*)d_in[16];
    const float* fc2_b   = (const float*)d_in[17];
    const float* dsn_w   = (const float*)d_in[18];
    const float* dsn_b   = (const float*)d_in[19];
    const float* ds1_w   = (const float*)d_in[20];
    const float* ds1_b   = (const float*)d_in[21];
    const float* ds2_w   = (const float*)d_in[22];
    const float* ds2_b   = (const float*)d_in[23];
    const float* mn_w    = (const float*)d_in[24];
    const float* mn_b    = (const float*)d_in[25];
    const float* mf1_w   = (const float*)d_in[26];
    const float* mf1_b   = (const float*)d_in[27];
    const float* mf2_w   = (const float*)d_in[28];
    const float* mf2_b   = (const float*)d_in[29];
    float* out = (float*)d_out;

    // ---- workspace carve ----
    float* wsf = (float*)d_ws;
    size_t off = 0;
    auto af = [&](size_t n) { float* p = wsf + off; off += (n + 3) & ~(size_t)3; return p; };
    float* h    = af((size_t)NT * EMB);
    float* qkv  = af((size_t)NT * 3 * EMB);
    float* part = af((size_t)4 * NT * EMB);
    float* S    = af((size_t)NH * NT * KVP);      // attention partials region
    float* Op   = S;                              // [4][16][900][80] f32 = 18.4 MB
    float* ml   = S + (size_t)4 * NH * NT * 80;   // [4][16][900][2]
    ushort* wsh = (ushort*)(wsf + off);
    size_t hoff = 0;
    auto ah = [&](size_t n) { ushort* p = wsh + hoff; hoff += (n + 7) & ~(size_t)7; return p; };
    ushort* hn  = ah((size_t)NT * EMB);
    ushort* hn2 = ah((size_t)NM * MHD);
    ushort* qb  = ah((size_t)NH * NT * DHP);
    ushort* kb  = ah((size_t)NH * NT * DHP);
    ushort* vt  = ah((size_t)NH * DHP * KVP);
    ushort* ob  = ah((size_t)NT * EMB);
    ushort* t1  = ah((size_t)NT * FFD);
    ushort* xp  = t1;
    // bf16 weight mirrors
    ushort* w_patch = ah((size_t)EMB * 1536);
    ushort* w_qkv   = ah((size_t)NL * 3 * EMB * EMB);
    ushort* w_proj  = ah((size_t)NL * EMB * EMB);
    ushort* w_fc1   = ah((size_t)NL * FFD * EMB);
    ushort* w_fc2   = ah((size_t)NL * EMB * FFD);
    ushort* w_ds1   = ah((size_t)2 * MHD * MHD);
    ushort* w_ds2   = ah((size_t)2 * OUTD * MHD);
    ushort* w_mf1   = ah((size_t)MHD * MHD);
    ushort* w_mf2   = ah((size_t)OUTD * MHD);

    const long MN = (long)NT * EMB;

    const int MB  = (NT + 63) / 64;   // 15
    const int MBm = (NM + 63) / 64;   // 4
    auto fixg = [](int M, int N) { return dim3(((size_t)M * N / 4 + 255) / 256); };
    auto cvt = [&](const float* s, ushort* d, size_t n) {
        k_cvt<<<dim3((unsigned)((n / 4 + 255) / 256)), 256, 0, stream>>>(s, d, (int)(n / 4));
    };

    // ---- weight pre-conversion (once per forward) ----
    cvt(patch_w, w_patch, (size_t)EMB * 1536);
    cvt(qkv_w,   w_qkv,   (size_t)NL * 3 * EMB * EMB);
    cvt(proj_w,  w_proj,  (size_t)NL * EMB * EMB);
    cvt(fc1_w,   w_fc1,   (size_t)NL * FFD * EMB);
    cvt(fc2_w,   w_fc2,   (size_t)NL * EMB * FFD);
    cvt(ds1_w,   w_ds1,   (size_t)2 * MHD * MHD);
    cvt(ds2_w,   w_ds2,   (size_t)2 * OUTD * MHD);
    cvt(mf1_w,   w_mf1,   (size_t)MHD * MHD);
    cvt(mf2_w,   w_mf2,   (size_t)OUTD * MHD);

    k_patch<<<dim3((NT * 1536 + 255) / 256), 256, 0, stream>>>(pix, xp);
    k_vpad<<<dim3((NH * DHP * (KVP - NT) + 255) / 256), 256, 0, stream>>>(vt);
    // patch: M=900 N=1152 K=1536, S=2; fused: +pos_emb -> h, then ln1[0] -> hn
    k_bgs<0, 0, 1><<<dim3(MB, EMB / 64, 2), 256, 0, stream>>>(
        xp, w_patch, nullptr, nullptr, nullptr, part, NT, EMB, 1536, 2);
    k_fixln<<<NT, 256, 0, stream>>>(part, patch_b, pos_emb, h,
                                    ln1_w, ln1_b, hn, EMB, 2, MN);

    for (int l = 0; l < NL; ++l) {
        // qkv: M=900 N=3456 K=1152, S=1 -> 810 blocks, direct f32 + bias
        k_bgs<0, 0, 0><<<dim3(MB, 3 * EMB / 64, 1), 256, 0, stream>>>(
            hn, w_qkv + (size_t)l * 3 * EMB * EMB, qkv_b + l * 3 * EMB, nullptr, qkv,
            nullptr, NT, 3 * EMB, EMB, 1);
        k_rope<<<dim3((NT * NH * DHP + 255) / 256), 256, 0, stream>>>(
            qkv, cosb, sinb, qb, kb, vt);
        // flash attention: 15 q-tiles x 16 heads x 4 kv-splits
        k_fa2<<<dim3(MB, NH, 4), 256, 0, stream>>>(qb, kb, vt, Op, ml);
        k_cmb<<<dim3((NH * NT * DHD + 255) / 256), 256, 0, stream>>>(Op, ml, ob);
        // proj: M=900 N=1152 K=1152, S=3; fused: +h residual -> h, then ln2 -> hn
        k_bgs<0, 0, 1><<<dim3(MB, EMB / 64, 3), 256, 0, stream>>>(
            ob, w_proj + (size_t)l * EMB * EMB, nullptr, nullptr, nullptr, part,
            NT, EMB, EMB, 3);
        k_fixln<<<NT, 256, 0, stream>>>(part, proj_b + l * EMB, h, h,
                                        ln2_w + l * EMB, ln2_b + l * EMB, hn,
                                        EMB, 3, MN);
        // fc1: M=900 N=4608 K=1152, S=1 -> 1080 blocks, direct gelu bf16
        k_bgs<1, 1, 0><<<dim3(MB, FFD / 64, 1), 256, 0, stream>>>(
            hn, w_fc1 + (size_t)l * FFD * EMB, fc1_b + l * FFD, nullptr, t1,
            nullptr, NT, FFD, EMB, 1);
        // fc2: M=900 N=1152 K=4608, S=4; fused: +h residual -> h, then next-LN -> hn
        const float* nlw = (l == NL - 1) ? mn_w : ln1_w + (l + 1) * EMB;
        const float* nlb = (l == NL - 1) ? mn_b : ln1_b + (l + 1) * EMB;
        k_bgs<0, 0, 1><<<dim3(MB, EMB / 64, 4), 256, 0, stream>>>(
            t1, w_fc2 + (size_t)l * EMB * FFD, nullptr, nullptr, nullptr, part,
            NT, EMB, FFD, 4);
        k_fixln<<<NT, 256, 0, stream>>>(part, fc2_b + l * EMB, h, h,
                                        nlw, nlb, hn, EMB, 4, MN);
        if (l == 2 || l == 5) {
            int d = (l == 2) ? 0 : 1;
            k_ln<<<NM, 256, 0, stream>>>(h, dsn_w + d * MHD, dsn_b + d * MHD, hn2, MHD);
            // ds1: M=225 N=4608 K=4608, S=4
            k_bgs<0, 0, 1><<<dim3(MBm, MHD / 64, 4), 256, 0, stream>>>(
                hn2, w_ds1 + (size_t)d * MHD * MHD, nullptr, nullptr, nullptr, part,
                NM, MHD, MHD, 4);
            k_fix<1, 1><<<fixg(NM, MHD), 256, 0, stream>>>(part, ds1_b + d * MHD,
                                                           nullptr, t1, NM, MHD, 4);
            // ds2: M=225 N=2048 K=4608, S=4
            k_bgs<0, 0, 1><<<dim3(MBm, OUTD / 64, 4), 256, 0, stream>>>(
                t1, w_ds2 + (size_t)d * OUTD * MHD, nullptr, nullptr, nullptr, part,
                NM, OUTD, MHD, 4);
            k_fix<0, 0><<<fixg(NM, OUTD), 256, 0, stream>>>(
                part, ds2_b + d * OUTD, nullptr, out + (size_t)d * NM * OUTD,
                NM, OUTD, 4);
        }
    }
    // merger: hn already holds merger-LN output ([900][1152] == [225][4608])
    k_bgs<0, 0, 1><<<dim3(MBm, MHD / 64, 4), 256, 0, stream>>>(
        hn, w_mf1, nullptr, nullptr, nullptr, part, NM, MHD, MHD, 4);
    k_fix<1, 1><<<fixg(NM, MHD), 256, 0, stream>>>(part, mf1_b, nullptr, t1, NM, MHD, 4);
    k_bgs<0, 0, 1><<<dim3(MBm, OUTD / 64, 4), 256, 0, stream>>>(
        t1, w_mf2, nullptr, nullptr, nullptr, part, NM, OUTD, MHD, 4);
    k_fix<0, 0><<<fixg(NM, OUTD), 256, 0, stream>>>(
        part, mf2_b, nullptr, out + (size_t)2 * NM * OUTD, NM, OUTD, 4);
}

// Round 15
// 1379.561 us; speedup vs baseline: 1.1786x; 1.0606x over previous
//
#include <hip/hip_runtime.h>
#include <hip/hip_bf16.h>
#include <cstdint>

#define NT   900
#define EMB  1152
#define NH   16
#define DHD  72
#define DHH  36
#define DHP  96      // padded head dim (3*32)
#define KVP  928     // padded kv length (29*32)
#define NL   6
#define FFD  4608
#define MHD  4608
#define OUTD 2048
#define NM   225

typedef __attribute__((ext_vector_type(8))) short short8;
typedef __attribute__((ext_vector_type(4))) float f32x4;

__device__ __forceinline__ ushort f2bf(float f) {
    uint32_t u = __float_as_uint(f);
    uint32_t r = u + 0x7FFF + ((u >> 16) & 1);
    return (ushort)(r >> 16);
}
__device__ __forceinline__ float gelu_f(float x) {
    return 0.5f * x * (1.0f + tanhf(0.7978845608f * (x + 0.044715f * x * x * x)));
}

// async global -> LDS, 16B per lane (lds dest wave-uniform base; HW adds lane*16)
__device__ __forceinline__ void g2lds16(const ushort* g, ushort* l) {
    __builtin_amdgcn_global_load_lds(
        (const __attribute__((address_space(1))) unsigned int*)g,
        (__attribute__((address_space(3))) unsigned int*)l, 16, 0, 0);
}

// ---------------- weight f32 -> bf16 pre-conversion ----------------
__global__ __launch_bounds__(256) void k_cvt(const float* __restrict__ src,
                                             ushort* __restrict__ dst, int n4) {
    int idx = blockIdx.x * 256 + threadIdx.x;
    if (idx >= n4) return;
    const float4 v = *(const float4*)(src + (size_t)idx * 4);
    ushort o[4] = { f2bf(v.x), f2bf(v.y), f2bf(v.z), f2bf(v.w) };
    *(uint2*)(dst + (size_t)idx * 4) = *(const uint2*)o;
}

// ---------------- patch extraction: pixels -> bf16 [900, 1536] ----------------
__global__ __launch_bounds__(256) void k_patch(const float* __restrict__ pix,
                                               ushort* __restrict__ xp) {
    int idx = blockIdx.x * 256 + threadIdx.x;
    if (idx >= NT * 1536) return;
    int t = idx / 1536, f = idx - t * 1536;
    int mw = t & 1, mh = (t >> 1) & 1;
    int tq = t >> 2;
    int jj = tq % 15, ii = tq / 15;
    int pw = f & 15, ph = (f >> 4) & 15, c = f >> 9;
    int Hi = (ii * 2 + mh) * 16 + ph;
    int Wi = (jj * 2 + mw) * 16 + pw;
    float p = pix[((size_t)c * 480 + Hi) * 480 + Wi];
    xp[idx] = f2bf((p - 127.5f) * (1.0f / 127.5f));
}

// ---------------- layernorm f32 in -> bf16 out, one block per row ----------------
__global__ __launch_bounds__(256) void k_ln(const float* __restrict__ x,
                                            const float* __restrict__ w,
                                            const float* __restrict__ b,
                                            ushort* __restrict__ y, int C) {
    int row = blockIdx.x;
    int tid = threadIdx.x;
    const float* xr = x + (size_t)row * C;
    float s = 0.f, ss = 0.f;
    for (int c = tid; c < C; c += 256) { float v = xr[c]; s += v; ss += v * v; }
    for (int off = 32; off; off >>= 1) {
        s  += __shfl_down(s,  off, 64);
        ss += __shfl_down(ss, off, 64);
    }
    __shared__ float rs[4], rss[4];
    int wid = tid >> 6, lane = tid & 63;
    if (lane == 0) { rs[wid] = s; rss[wid] = ss; }
    __syncthreads();
    float S  = rs[0] + rs[1] + rs[2] + rs[3];
    float SS = rss[0] + rss[1] + rss[2] + rss[3];
    float mu  = S / C;
    float var = SS / C - mu * mu;
    float inv = rsqrtf(var + 1e-6f);
    ushort* yr = y + (size_t)row * C;
    for (int c = tid; c < C; c += 256) yr[c] = f2bf((xr[c] - mu) * inv * w[c] + b[c]);
}

// ---------------- fused split-K reduce + bias + residual + LayerNorm ----------------
__global__ __launch_bounds__(256) void k_fixln(const float* __restrict__ part,
                                               const float* __restrict__ bias,
                                               const float* __restrict__ res,
                                               float* __restrict__ hout,
                                               const float* __restrict__ lw,
                                               const float* __restrict__ lb,
                                               ushort* __restrict__ y,
                                               int C, int S, long MN) {
    int row = blockIdx.x, tid = threadIdx.x;
    int C4 = C >> 2;
    const float* prow = part + (size_t)row * C;
    const float* rrow = res + (size_t)row * C;
    float* hrow = hout + (size_t)row * C;
    ushort* yrow = y + (size_t)row * C;

    float4 vals[2];
    float s = 0.f, ss = 0.f;
    int idx[2] = { tid, tid + 256 };
#pragma unroll
    for (int it = 0; it < 2; ++it) {
        int c4 = idx[it];
        if (c4 < C4) {
            float4 v = *(const float4*)(prow + c4 * 4);
            for (int sI = 1; sI < S; ++sI) {
                const float4 p = *(const float4*)(prow + (size_t)sI * MN + c4 * 4);
                v.x += p.x; v.y += p.y; v.z += p.z; v.w += p.w;
            }
            const float4 bi = *(const float4*)(bias + c4 * 4);
            v.x += bi.x; v.y += bi.y; v.z += bi.z; v.w += bi.w;
            const float4 rr = *(const float4*)(rrow + c4 * 4);
            v.x += rr.x; v.y += rr.y; v.z += rr.z; v.w += rr.w;
            *(float4*)(hrow + c4 * 4) = v;
            vals[it] = v;
            s  += v.x + v.y + v.z + v.w;
            ss += v.x * v.x + v.y * v.y + v.z * v.z + v.w * v.w;
        }
    }
    for (int off = 32; off; off >>= 1) {
        s  += __shfl_down(s,  off, 64);
        ss += __shfl_down(ss, off, 64);
    }
    __shared__ float rs[4], rss[4];
    int wid = tid >> 6, lane = tid & 63;
    if (lane == 0) { rs[wid] = s; rss[wid] = ss; }
    __syncthreads();
    float St  = rs[0] + rs[1] + rs[2] + rs[3];
    float SSt = rss[0] + rss[1] + rss[2] + rss[3];
    float mu  = St / C;
    float var = SSt / C - mu * mu;
    float inv = rsqrtf(var + 1e-6f);
#pragma unroll
    for (int it = 0; it < 2; ++it) {
        int c4 = idx[it];
        if (c4 < C4) {
            float4 v = vals[it];
            const float4 w4 = *(const float4*)(lw + c4 * 4);
            const float4 b4 = *(const float4*)(lb + c4 * 4);
            ushort o[4] = { f2bf((v.x - mu) * inv * w4.x + b4.x),
                            f2bf((v.y - mu) * inv * w4.y + b4.y),
                            f2bf((v.z - mu) * inv * w4.z + b4.z),
                            f2bf((v.w - mu) * inv * w4.w + b4.w) };
            *(uint2*)(yrow + c4 * 4) = *(const uint2*)o;
        }
    }
}

// ---------------- dense MFMA GEMM, 64x64 tile, BK=64, gload_lds + XOR swizzle ----
// + XCD-chunked bijective block remap (T1, m204) for weight-panel L2 locality.
// C[M,N] = act(A[M,K](bf16) @ W[N,K]^T(bf16) + bias) + res   (N % 64 == 0)
// grid (ceil(M/64), N/64, S). SPLIT=1: raw partials to part[z][M][N].
template <int ACT, int OBF16, int SPLIT>
__global__ __launch_bounds__(256) void k_bgs(const ushort* __restrict__ A,
                                             const ushort* __restrict__ W,
                                             const float* __restrict__ bias,
                                             const float* __restrict__ res,
                                             void* __restrict__ Cp,
                                             float* __restrict__ part,
                                             int M, int N, int K, int S) {
    __shared__ __align__(16) ushort As[64 * 64];
    __shared__ __align__(16) ushort Bs[64 * 64];
    int tid = threadIdx.x;

    // ---- XCD-chunked bijective remap: hardware round-robins block id % 8 over
    // XCDs; give each XCD a CONTIGUOUS work chunk so the 15 same-weight-panel
    // M-tiles stay in one L2. (m204 formula, handles nwg % 8 != 0.)
    int nwg  = gridDim.x * gridDim.y * gridDim.z;
    int orig = blockIdx.x + gridDim.x * (blockIdx.y + gridDim.y * blockIdx.z);
    int xcd = orig & 7, loc = orig >> 3;
    int q8 = nwg >> 3, r8 = nwg & 7;
    int work = (xcd < r8 ? xcd * (q8 + 1) : r8 * (q8 + 1) + (xcd - r8) * q8) + loc;
    int bx = work % gridDim.x;
    int rest = work / gridDim.x;
    int by = rest % gridDim.y;
    int bz = rest / gridDim.y;

    int row0 = bx * 64, col0 = by * 64;
    int z = bz;
    int Kc = K / S;              // multiple of 64
    int kbeg = z * Kc;
    int steps = Kc >> 6;

    int w = tid >> 6, lane = tid & 63;
    int lrow = lane >> 3;                    // 0..7
    int cg   = ((lane & 7) ^ lrow) << 3;     // pre-swizzled source granule (elems)

    int ar0 = row0 + w * 16 + lrow; if (ar0 > M - 1) ar0 = M - 1;
    int ar1 = row0 + w * 16 + 8 + lrow; if (ar1 > M - 1) ar1 = M - 1;
    int wr0 = col0 + w * 16 + lrow;
    int wr1 = wr0 + 8;
    const ushort* ap0 = A + (size_t)ar0 * K + kbeg + cg;
    const ushort* ap1 = A + (size_t)ar1 * K + kbeg + cg;
    const ushort* wp0 = W + (size_t)wr0 * K + kbeg + cg;
    const ushort* wp1 = W + (size_t)wr1 * K + kbeg + cg;
    ushort* asd0 = &As[(w * 16) * 64];
    ushort* asd1 = &As[(w * 16 + 8) * 64];
    ushort* bsd0 = &Bs[(w * 16) * 64];
    ushort* bsd1 = &Bs[(w * 16 + 8) * 64];

    int fr = lane & 15, kg8 = (lane >> 4) << 3;
    int wrr = (w >> 1) * 32, wcc = (w & 1) * 32;
    int sw = (fr & 7) << 3;

    f32x4 acc[2][2] = {};
    for (int s = 0; s < steps; ++s) {
        int kk = s << 6;
        __syncthreads();
        g2lds16(ap0 + kk, asd0);
        g2lds16(ap1 + kk, asd1);
        g2lds16(wp0 + kk, bsd0);
        g2lds16(wp1 + kk, bsd1);
        __syncthreads();
#pragma unroll
        for (int j = 0; j < 2; ++j) {
            int ko = j * 32 + kg8;
            int kx = ko ^ sw;
            short8 a0 = *(const short8*)&As[(wrr + fr) * 64 + kx];
            short8 a1 = *(const short8*)&As[(wrr + 16 + fr) * 64 + kx];
            short8 b0 = *(const short8*)&Bs[(wcc + fr) * 64 + kx];
            short8 b1 = *(const short8*)&Bs[(wcc + 16 + fr) * 64 + kx];
            acc[0][0] = __builtin_amdgcn_mfma_f32_16x16x32_bf16(a0, b0, acc[0][0], 0, 0, 0);
            acc[0][1] = __builtin_amdgcn_mfma_f32_16x16x32_bf16(a0, b1, acc[0][1], 0, 0, 0);
            acc[1][0] = __builtin_amdgcn_mfma_f32_16x16x32_bf16(a1, b0, acc[1][0], 0, 0, 0);
            acc[1][1] = __builtin_amdgcn_mfma_f32_16x16x32_bf16(a1, b1, acc[1][1], 0, 0, 0);
        }
    }

#pragma unroll
    for (int fi = 0; fi < 2; fi++)
#pragma unroll
        for (int fj = 0; fj < 2; fj++)
#pragma unroll
            for (int r = 0; r < 4; r++) {
                int row = row0 + wrr + fi * 16 + (lane >> 4) * 4 + r;
                int col = col0 + wcc + fj * 16 + fr;
                if (row < M) {
                    if (SPLIT) {
                        part[((size_t)z * M + row) * N + col] = acc[fi][fj][r];
                    } else {
                        float v = acc[fi][fj][r] + bias[col];
                        if (res) v += res[(size_t)row * N + col];
                        if (ACT == 1) v = gelu_f(v);
                        if (OBF16) ((ushort*)Cp)[(size_t)row * N + col] = f2bf(v);
                        else       ((float*)Cp)[(size_t)row * N + col] = v;
                    }
                }
            }
}

// ---------------- split-K fixup (no LN) ----------------
template <int ACT, int OBF16>
__global__ __launch_bounds__(256) void k_fix(const float* __restrict__ part,
                                             const float* __restrict__ bias,
                                             const float* __restrict__ res,
                                             void* __restrict__ Cp,
                                             int M, int N, int S) {
    size_t idx = (size_t)blockIdx.x * 256 + threadIdx.x;
    size_t total = (size_t)M * N / 4;
    if (idx >= total) return;
    size_t e = idx * 4;
    int row = (int)(e / N), col = (int)(e - (size_t)row * N);
    float4 v = *(const float4*)(part + e);
    for (int s = 1; s < S; ++s) {
        const float4 p = *(const float4*)(part + (size_t)s * M * N + e);
        v.x += p.x; v.y += p.y; v.z += p.z; v.w += p.w;
    }
    const float4 bi = *(const float4*)(bias + col);
    v.x += bi.x; v.y += bi.y; v.z += bi.z; v.w += bi.w;
    if (res) {
        const float4 rr = *(const float4*)(res + e);
        v.x += rr.x; v.y += rr.y; v.z += rr.z; v.w += rr.w;
    }
    if (ACT == 1) { v.x = gelu_f(v.x); v.y = gelu_f(v.y); v.z = gelu_f(v.z); v.w = gelu_f(v.w); }
    if (OBF16) {
        ushort o[4] = { f2bf(v.x), f2bf(v.y), f2bf(v.z), f2bf(v.w) };
        *(uint2*)((ushort*)Cp + e) = *(const uint2*)o;
    } else {
        *(float4*)((float*)Cp + e) = v;
    }
}

// ---------------- attention GEMM (bf16 A & W, batched over heads), BK=32 ----
template <int OBF16>
__global__ __launch_bounds__(256) void k_mm(const ushort* __restrict__ A,
                                            const ushort* __restrict__ Wb,
                                            void* __restrict__ Cp,
                                            int M, int N, int K, int ldc, int Nw,
                                            long as_, long ws_, long cs_) {
    __shared__ __align__(16) ushort As[64 * 40];
    __shared__ __align__(16) ushort Bs[64 * 40];
    int z = blockIdx.z;
    A  += (size_t)z * as_;
    Wb += (size_t)z * ws_;
    float*  Cf = (float*)Cp + (size_t)z * cs_;
    ushort* Cb = (ushort*)Cp + (size_t)z * cs_;

    int tid = threadIdx.x;
    int row0 = blockIdx.y * 64, col0 = blockIdx.x * 64;

    int sm = tid >> 2, sp = tid & 3;
    int ar = row0 + sm; if (ar > M - 1) ar = M - 1;
    int wr = col0 + sm; if (wr > N - 1) wr = N - 1;
    const ushort* aptr = A + (size_t)ar * K;

    int lane = tid & 63, wid = tid >> 6;
    int wrr = (wid >> 1) * 32, wcc = (wid & 1) * 32;
    int fr = lane & 15, kg = lane >> 4;

    f32x4 acc[2][2] = {};

    for (int k0 = 0; k0 < K; k0 += 32) {
        *(uint4*)&As[sm * 40 + sp * 8] = *(const uint4*)(aptr + k0 + sp * 8);
        *(uint4*)&Bs[sm * 40 + sp * 8] = *(const uint4*)(Wb + (size_t)wr * K + k0 + sp * 8);
        __syncthreads();
        short8 a0 = *(const short8*)&As[(wrr + fr) * 40 + kg * 8];
        short8 a1 = *(const short8*)&As[(wrr + 16 + fr) * 40 + kg * 8];
        short8 b0 = *(const short8*)&Bs[(wcc + fr) * 40 + kg * 8];
        short8 b1 = *(const short8*)&Bs[(wcc + 16 + fr) * 40 + kg * 8];
        acc[0][0] = __builtin_amdgcn_mfma_f32_16x16x32_bf16(a0, b0, acc[0][0], 0, 0, 0);
        acc[0][1] = __builtin_amdgcn_mfma_f32_16x16x32_bf16(a0, b1, acc[0][1], 0, 0, 0);
        acc[1][0] = __builtin_amdgcn_mfma_f32_16x16x32_bf16(a1, b0, acc[1][0], 0, 0, 0);
        acc[1][1] = __builtin_amdgcn_mfma_f32_16x16x32_bf16(a1, b1, acc[1][1], 0, 0, 0);
        __syncthreads();
    }

#pragma unroll
    for (int fi = 0; fi < 2; fi++)
#pragma unroll
        for (int fj = 0; fj < 2; fj++)
#pragma unroll
            for (int r = 0; r < 4; r++) {
                int row = row0 + wrr + fi * 16 + (lane >> 4) * 4 + r;
                int col = col0 + wcc + fj * 16 + (lane & 15);
                if (row < M && col < Nw) {
                    float v = acc[fi][fj][r];
                    if (OBF16) Cb[(size_t)row * ldc + col] = f2bf(v);
                    else       Cf[(size_t)row * ldc + col] = v;
                }
            }
}

// ---------------- qkv f32 [900,3456] -> rope(q),rope(k) bf16 [16,900,96], v^T bf16 [16,96,928]
__global__ __launch_bounds__(256) void k_rope(const float* __restrict__ qkv,
                                              const float* __restrict__ cs,
                                              const float* __restrict__ sn,
                                              ushort* __restrict__ q,
                                              ushort* __restrict__ k,
                                              ushort* __restrict__ vt) {
    int idx = blockIdx.x * 256 + threadIdx.x;
    if (idx >= NT * NH * DHP) return;
    int t = idx / (NH * DHP);
    int rem = idx - t * (NH * DHP);
    int h = rem / DHP, d = rem - h * DHP;
    size_t oi = ((size_t)h * NT + t) * DHP + d;
    if (d < DHD) {
        const float* base = qkv + (size_t)t * 3 * EMB;
        float c = cs[t * DHD + d], s = sn[t * DHD + d];
        int   d2 = (d < DHH) ? d + DHH : d - DHH;
        float sg = (d < DHH) ? -1.f : 1.f;
        int e = h * DHD + d;
        float qv = base[e] * c + sg * base[h * DHD + d2] * s;
        float kv = base[EMB + e] * c + sg * base[EMB + h * DHD + d2] * s;
        q[oi] = f2bf(qv);
        k[oi] = f2bf(kv);
        vt[((size_t)h * DHP + d) * KVP + t] = f2bf(base[2 * EMB + e]);
    } else {
        q[oi] = 0;
        k[oi] = 0;
    }
}

// zero v^T pad columns t in [900,928)
__global__ __launch_bounds__(256) void k_vpad(ushort* __restrict__ vt) {
    int idx = blockIdx.x * 256 + threadIdx.x;
    int tot = NH * DHP * (KVP - NT);
    if (idx >= tot) return;
    int pw = KVP - NT;
    int hd = idx / pw, j = idx - hd * pw;
    vt[(size_t)hd * KVP + NT + j] = 0;
}

// ---------------- softmax: S f32 [16*900][928] -> P bf16 (pad cols zeroed) ----------------
__global__ __launch_bounds__(256) void k_sm(const float* __restrict__ S,
                                            ushort* __restrict__ P) {
    int row = blockIdx.x * 4 + (threadIdx.x >> 6);
    int lane = threadIdx.x & 63;
    const float* sp = S + (size_t)row * KVP;
    ushort* pp = P + (size_t)row * KVP;
    float v[15];
#pragma unroll
    for (int i = 0; i < 15; i++) {
        int kt = lane + i * 64;
        v[i] = (kt < NT) ? sp[kt] : -1e30f;
    }
    float mx = -1e30f;
#pragma unroll
    for (int i = 0; i < 15; i++) mx = fmaxf(mx, v[i]);
    for (int off = 32; off; off >>= 1) mx = fmaxf(mx, __shfl_xor(mx, off, 64));
    float sum = 0.f;
#pragma unroll
    for (int i = 0; i < 15; i++) {
        int kt = lane + i * 64;
        v[i] = (kt < NT) ? __expf(v[i] - mx) : 0.f;
        sum += v[i];
    }
    for (int off = 32; off; off >>= 1) sum += __shfl_xor(sum, off, 64);
    float inv = 1.f / sum;
#pragma unroll
    for (int i = 0; i < 15; i++) {
        int kt = lane + i * 64;
        if (kt < KVP) pp[kt] = f2bf(v[i] * inv);
    }
}

extern "C" void kernel_launch(void* const* d_in, const int* in_sizes, int n_in,
                              void* d_out, int out_size, void* d_ws, size_t ws_size,
                              hipStream_t stream) {
    const float* pix     = (const float*)d_in[0];
    const float* patch_w = (const float*)d_in[1];
    const float* patch_b = (const float*)d_in[2];
    const float* pos_emb = (const float*)d_in[3];
    const float* cosb    = (const float*)d_in[4];
    const float* sinb    = (const float*)d_in[5];
    const float* ln1_w   = (const float*)d_in[6];
    const float* ln1_b   = (const float*)d_in[7];
    const float* qkv_w   = (const float*)d_in[8];
    const float* qkv_b   = (const float*)d_in[9];
    const float* proj_w  = (const float*)d_in[10];
    const float* proj_b  = (const float*)d_in[11];
    const float* ln2_w   = (const float*)d_in[12];
    const float* ln2_b   = (const float*)d_in[13];
    const float* fc1_w   = (const float*)d_in[14];
    const float* fc1_b   = (const float*)d_in[15];
    const float* fc2_w   = (const float*)d_in[16];
    const float* fc2_b   = (const float*)d_in[17];
    const float* dsn_w   = (const float*)d_in[18];
    const float* dsn_b   = (const float*)d_in[19];
    const float* ds1_w   = (const float*)d_in[20];
    const float* ds1_b   = (const float*)d_in[21];
    const float* ds2_w   = (const float*)d_in[22];
    const float* ds2_b   = (const float*)d_in[23];
    const float* mn_w    = (const float*)d_in[24];
    const float* mn_b    = (const float*)d_in[25];
    const float* mf1_w   = (const float*)d_in[26];
    const float* mf1_b   = (const float*)d_in[27];
    const float* mf2_w   = (const float*)d_in[28];
    const float* mf2_b   = (const float*)d_in[29];
    float* out = (float*)d_out;

    // ---- workspace carve ----
    float* wsf = (float*)d_ws;
    size_t off = 0;
    auto af = [&](size_t n) { float* p = wsf + off; off += (n + 3) & ~(size_t)3; return p; };
    float* h    = af((size_t)NT * EMB);
    float* qkv  = af((size_t)NT * 3 * EMB);
    float* part = af((size_t)4 * NT * EMB);
    float* S    = af((size_t)NH * NT * KVP);      // attention scores f32
    ushort* wsh = (ushort*)(wsf + off);
    size_t hoff = 0;
    auto ah = [&](size_t n) { ushort* p = wsh + hoff; hoff += (n + 7) & ~(size_t)7; return p; };
    ushort* hn  = ah((size_t)NT * EMB);
    ushort* hn2 = ah((size_t)NM * MHD);
    ushort* qb  = ah((size_t)NH * NT * DHP);
    ushort* kb  = ah((size_t)NH * NT * DHP);
    ushort* vt  = ah((size_t)NH * DHP * KVP);
    ushort* P   = ah((size_t)NH * NT * KVP);
    ushort* ob  = ah((size_t)NT * EMB);
    ushort* t1  = ah((size_t)NT * FFD);
    ushort* xp  = t1;
    // bf16 weight mirrors
    ushort* w_patch = ah((size_t)EMB * 1536);
    ushort* w_qkv   = ah((size_t)NL * 3 * EMB * EMB);
    ushort* w_proj  = ah((size_t)NL * EMB * EMB);
    ushort* w_fc1   = ah((size_t)NL * FFD * EMB);
    ushort* w_fc2   = ah((size_t)NL * EMB * FFD);
    ushort* w_ds1   = ah((size_t)2 * MHD * MHD);
    ushort* w_ds2   = ah((size_t)2 * OUTD * MHD);
    ushort* w_mf1   = ah((size_t)MHD * MHD);
    ushort* w_mf2   = ah((size_t)OUTD * MHD);

    const long QS = (long)NT * DHP;
    const long VS = (long)DHP * KVP;
    const long SS = (long)NT * KVP;
    const long MN = (long)NT * EMB;

    const int MB  = (NT + 63) / 64;   // 15
    const int MBm = (NM + 63) / 64;   // 4
    auto fixg = [](int M, int N) { return dim3(((size_t)M * N / 4 + 255) / 256); };
    auto cvt = [&](const float* s, ushort* d, size_t n) {
        k_cvt<<<dim3((unsigned)((n / 4 + 255) / 256)), 256, 0, stream>>>(s, d, (int)(n / 4));
    };

    // ---- weight pre-conversion (once per forward) ----
    cvt(patch_w, w_patch, (size_t)EMB * 1536);
    cvt(qkv_w,   w_qkv,   (size_t)NL * 3 * EMB * EMB);
    cvt(proj_w,  w_proj,  (size_t)NL * EMB * EMB);
    cvt(fc1_w,   w_fc1,   (size_t)NL * FFD * EMB);
    cvt(fc2_w,   w_fc2,   (size_t)NL * EMB * FFD);
    cvt(ds1_w,   w_ds1,   (size_t)2 * MHD * MHD);
    cvt(ds2_w,   w_ds2,   (size_t)2 * OUTD * MHD);
    cvt(mf1_w,   w_mf1,   (size_t)MHD * MHD);
    cvt(mf2_w,   w_mf2,   (size_t)OUTD * MHD);

    k_patch<<<dim3((NT * 1536 + 255) / 256), 256, 0, stream>>>(pix, xp);
    k_vpad<<<dim3((NH * DHP * (KVP - NT) + 255) / 256), 256, 0, stream>>>(vt);
    // patch: M=900 N=1152 K=1536, S=2; fused: +pos_emb -> h, then ln1[0] -> hn
    k_bgs<0, 0, 1><<<dim3(MB, EMB / 64, 2), 256, 0, stream>>>(
        xp, w_patch, nullptr, nullptr, nullptr, part, NT, EMB, 1536, 2);
    k_fixln<<<NT, 256, 0, stream>>>(part, patch_b, pos_emb, h,
                                    ln1_w, ln1_b, hn, EMB, 2, MN);

    for (int l = 0; l < NL; ++l) {
        // qkv: M=900 N=3456 K=1152, S=1 -> 810 blocks, direct f32 + bias
        k_bgs<0, 0, 0><<<dim3(MB, 3 * EMB / 64, 1), 256, 0, stream>>>(
            hn, w_qkv + (size_t)l * 3 * EMB * EMB, qkv_b + l * 3 * EMB, nullptr, qkv,
            nullptr, NT, 3 * EMB, EMB, 1);
        k_rope<<<dim3((NT * NH * DHP + 255) / 256), 256, 0, stream>>>(
            qkv, cosb, sinb, qb, kb, vt);
        // S = Q @ K^T (per head)
        k_mm<0><<<dim3(MB, MB, NH), 256, 0, stream>>>(
            qb, kb, S, NT, NT, DHP, KVP, NT, QS, QS, SS);
        k_sm<<<dim3(NH * NT / 4), 256, 0, stream>>>(S, P);
        // O = P @ V (per head) -> ob bf16 [900][1152]
        k_mm<1><<<dim3(2, MB, NH), 256, 0, stream>>>(
            P, vt, ob, NT, DHD, KVP, EMB, DHD, SS, VS, DHD);
        // proj: M=900 N=1152 K=1152, S=3; fused: +h residual -> h, then ln2 -> hn
        k_bgs<0, 0, 1><<<dim3(MB, EMB / 64, 3), 256, 0, stream>>>(
            ob, w_proj + (size_t)l * EMB * EMB, nullptr, nullptr, nullptr, part,
            NT, EMB, EMB, 3);
        k_fixln<<<NT, 256, 0, stream>>>(part, proj_b + l * EMB, h, h,
                                        ln2_w + l * EMB, ln2_b + l * EMB, hn,
                                        EMB, 3, MN);
        // fc1: M=900 N=4608 K=1152, S=1 -> 1080 blocks, direct gelu bf16
        k_bgs<1, 1, 0><<<dim3(MB, FFD / 64, 1), 256, 0, stream>>>(
            hn, w_fc1 + (size_t)l * FFD * EMB, fc1_b + l * FFD, nullptr, t1,
            nullptr, NT, FFD, EMB, 1);
        // fc2: M=900 N=1152 K=4608, S=4; fused: +h residual -> h, then next-LN -> hn
        const float* nlw = (l == NL - 1) ? mn_w : ln1_w + (l + 1) * EMB;
        const float* nlb = (l == NL - 1) ? mn_b : ln1_b + (l + 1) * EMB;
        k_bgs<0, 0, 1><<<dim3(MB, EMB / 64, 4), 256, 0, stream>>>(
            t1, w_fc2 + (size_t)l * EMB * FFD, nullptr, nullptr, nullptr, part,
            NT, EMB, FFD, 4);
        k_fixln<<<NT, 256, 0, stream>>>(part, fc2_b + l * EMB, h, h,
                                        nlw, nlb, hn, EMB, 4, MN);
        if (l == 2 || l == 5) {
            int d = (l == 2) ? 0 : 1;
            k_ln<<<NM, 256, 0, stream>>>(h, dsn_w + d * MHD, dsn_b + d * MHD, hn2, MHD);
            // ds1: M=225 N=4608 K=4608, S=4
            k_bgs<0, 0, 1><<<dim3(MBm, MHD / 64, 4), 256, 0, stream>>>(
                hn2, w_ds1 + (size_t)d * MHD * MHD, nullptr, nullptr, nullptr, part,
                NM, MHD, MHD, 4);
            k_fix<1, 1><<<fixg(NM, MHD), 256, 0, stream>>>(part, ds1_b + d * MHD,
                                                           nullptr, t1, NM, MHD, 4);
            // ds2: M=225 N=2048 K=4608, S=4
            k_bgs<0, 0, 1><<<dim3(MBm, OUTD / 64, 4), 256, 0, stream>>>(
                t1, w_ds2 + (size_t)d * OUTD * MHD, nullptr, nullptr, nullptr, part,
                NM, OUTD, MHD, 4);
            k_fix<0, 0><<<fixg(NM, OUTD), 256, 0, stream>>>(
                part, ds2_b + d * OUTD, nullptr, out + (size_t)d * NM * OUTD,
                NM, OUTD, 4);
        }
    }
    // merger: hn already holds merger-LN output ([900][1152] == [225][4608])
    k_bgs<0, 0, 1><<<dim3(MBm, MHD / 64, 4), 256, 0, stream>>>(
        hn, w_mf1, nullptr, nullptr, nullptr, part, NM, MHD, MHD, 4);
    k_fix<1, 1><<<fixg(NM, MHD), 256, 0, stream>>>(part, mf1_b, nullptr, t1, NM, MHD, 4);
    k_bgs<0, 0, 1><<<dim3(MBm, OUTD / 64, 4), 256, 0, stream>>>(
        t1, w_mf2, nullptr, nullptr, nullptr, part, NM, OUTD, MHD, 4);
    k_fix<0, 0><<<fixg(NM, OUTD), 256, 0, stream>>>(
        part, mf2_b, nullptr, out + (size_t)2 * NM * OUTD, NM, OUTD, 4);
}

// Round 16
// 1296.746 us; speedup vs baseline: 1.2539x; 1.0639x over previous
//
#include <hip/hip_runtime.h>
#include <hip/hip_bf16.h>
#include <cstdint>

#define NT   900
#define EMB  1152
#define NH   16
#define DHD  72
#define DHH  36
#define DHP  96      // padded head dim for QK (3*32)
#define KVP  928     // S width (29*32)
#define PW   960     // P / V^T K-width for PV (15*64)
#define VR   128     // V^T padded rows per head
#define NL   6
#define FFD  4608
#define MHD  4608
#define OUTD 2048
#define NM   225

typedef __attribute__((ext_vector_type(8))) short short8;
typedef __attribute__((ext_vector_type(4))) float f32x4;

__device__ __forceinline__ ushort f2bf(float f) {
    uint32_t u = __float_as_uint(f);
    uint32_t r = u + 0x7FFF + ((u >> 16) & 1);
    return (ushort)(r >> 16);
}
__device__ __forceinline__ float gelu_f(float x) {
    return 0.5f * x * (1.0f + tanhf(0.7978845608f * (x + 0.044715f * x * x * x)));
}

// async global -> LDS, 16B per lane (lds dest wave-uniform base; HW adds lane*16)
__device__ __forceinline__ void g2lds16(const ushort* g, ushort* l) {
    __builtin_amdgcn_global_load_lds(
        (const __attribute__((address_space(1))) unsigned int*)g,
        (__attribute__((address_space(3))) unsigned int*)l, 16, 0, 0);
}

// XCD-chunked bijective block remap (T1, m204): contiguous work chunk per XCD.
__device__ __forceinline__ int xcd_remap(int orig, int nwg) {
    int xcd = orig & 7, loc = orig >> 3;
    int q8 = nwg >> 3, r8 = nwg & 7;
    return (xcd < r8 ? xcd * (q8 + 1) : r8 * (q8 + 1) + (xcd - r8) * q8) + loc;
}

// ---------------- merged weight f32 -> bf16 pre-conversion (9 segments) ------
struct CvtArgs {
    const float* src[9];
    ushort* dst[9];
    long off[10];          // prefix sums in float4 units
};
__global__ __launch_bounds__(256) void k_cvt9(CvtArgs a) {
    long idx = (long)blockIdx.x * 256 + threadIdx.x;
    if (idx >= a.off[9]) return;
    int g = 0;
#pragma unroll
    for (int i = 1; i < 9; ++i) if (idx >= a.off[i]) g = i;
    long li = idx - a.off[g];
    const float4 v = *(const float4*)(a.src[g] + li * 4);
    ushort o[4] = { f2bf(v.x), f2bf(v.y), f2bf(v.z), f2bf(v.w) };
    *(uint2*)(a.dst[g] + li * 4) = *(const uint2*)o;
}

// ---------------- patch extraction: pixels -> bf16 [900, 1536] ----------------
__global__ __launch_bounds__(256) void k_patch(const float* __restrict__ pix,
                                               ushort* __restrict__ xp) {
    int idx = blockIdx.x * 256 + threadIdx.x;
    if (idx >= NT * 1536) return;
    int t = idx / 1536, f = idx - t * 1536;
    int mw = t & 1, mh = (t >> 1) & 1;
    int tq = t >> 2;
    int jj = tq % 15, ii = tq / 15;
    int pw = f & 15, ph = (f >> 4) & 15, c = f >> 9;
    int Hi = (ii * 2 + mh) * 16 + ph;
    int Wi = (jj * 2 + mw) * 16 + pw;
    float p = pix[((size_t)c * 480 + Hi) * 480 + Wi];
    xp[idx] = f2bf((p - 127.5f) * (1.0f / 127.5f));
}

// ---------------- layernorm f32 in -> bf16 out, one block per row ----------------
__global__ __launch_bounds__(256) void k_ln(const float* __restrict__ x,
                                            const float* __restrict__ w,
                                            const float* __restrict__ b,
                                            ushort* __restrict__ y, int C) {
    int row = blockIdx.x;
    int tid = threadIdx.x;
    const float* xr = x + (size_t)row * C;
    float s = 0.f, ss = 0.f;
    for (int c = tid; c < C; c += 256) { float v = xr[c]; s += v; ss += v * v; }
    for (int off = 32; off; off >>= 1) {
        s  += __shfl_down(s,  off, 64);
        ss += __shfl_down(ss, off, 64);
    }
    __shared__ float rs[4], rss[4];
    int wid = tid >> 6, lane = tid & 63;
    if (lane == 0) { rs[wid] = s; rss[wid] = ss; }
    __syncthreads();
    float S  = rs[0] + rs[1] + rs[2] + rs[3];
    float SS = rss[0] + rss[1] + rss[2] + rss[3];
    float mu  = S / C;
    float var = SS / C - mu * mu;
    float inv = rsqrtf(var + 1e-6f);
    ushort* yr = y + (size_t)row * C;
    for (int c = tid; c < C; c += 256) yr[c] = f2bf((xr[c] - mu) * inv * w[c] + b[c]);
}

// ---------------- fused split-K reduce + bias + residual + LayerNorm ----------------
__global__ __launch_bounds__(256) void k_fixln(const float* __restrict__ part,
                                               const float* __restrict__ bias,
                                               const float* __restrict__ res,
                                               float* __restrict__ hout,
                                               const float* __restrict__ lw,
                                               const float* __restrict__ lb,
                                               ushort* __restrict__ y,
                                               int C, int S, long MN) {
    int row = blockIdx.x, tid = threadIdx.x;
    int C4 = C >> 2;
    const float* prow = part + (size_t)row * C;
    const float* rrow = res + (size_t)row * C;
    float* hrow = hout + (size_t)row * C;
    ushort* yrow = y + (size_t)row * C;

    float4 vals[2];
    float s = 0.f, ss = 0.f;
    int idx[2] = { tid, tid + 256 };
#pragma unroll
    for (int it = 0; it < 2; ++it) {
        int c4 = idx[it];
        if (c4 < C4) {
            float4 v = *(const float4*)(prow + c4 * 4);
            for (int sI = 1; sI < S; ++sI) {
                const float4 p = *(const float4*)(prow + (size_t)sI * MN + c4 * 4);
                v.x += p.x; v.y += p.y; v.z += p.z; v.w += p.w;
            }
            const float4 bi = *(const float4*)(bias + c4 * 4);
            v.x += bi.x; v.y += bi.y; v.z += bi.z; v.w += bi.w;
            const float4 rr = *(const float4*)(rrow + c4 * 4);
            v.x += rr.x; v.y += rr.y; v.z += rr.z; v.w += rr.w;
            *(float4*)(hrow + c4 * 4) = v;
            vals[it] = v;
            s  += v.x + v.y + v.z + v.w;
            ss += v.x * v.x + v.y * v.y + v.z * v.z + v.w * v.w;
        }
    }
    for (int off = 32; off; off >>= 1) {
        s  += __shfl_down(s,  off, 64);
        ss += __shfl_down(ss, off, 64);
    }
    __shared__ float rs[4], rss[4];
    int wid = tid >> 6, lane = tid & 63;
    if (lane == 0) { rs[wid] = s; rss[wid] = ss; }
    __syncthreads();
    float St  = rs[0] + rs[1] + rs[2] + rs[3];
    float SSt = rss[0] + rss[1] + rss[2] + rss[3];
    float mu  = St / C;
    float var = SSt / C - mu * mu;
    float inv = rsqrtf(var + 1e-6f);
#pragma unroll
    for (int it = 0; it < 2; ++it) {
        int c4 = idx[it];
        if (c4 < C4) {
            float4 v = vals[it];
            const float4 w4 = *(const float4*)(lw + c4 * 4);
            const float4 b4 = *(const float4*)(lb + c4 * 4);
            ushort o[4] = { f2bf((v.x - mu) * inv * w4.x + b4.x),
                            f2bf((v.y - mu) * inv * w4.y + b4.y),
                            f2bf((v.z - mu) * inv * w4.z + b4.z),
                            f2bf((v.w - mu) * inv * w4.w + b4.w) };
            *(uint2*)(yrow + c4 * 4) = *(const uint2*)o;
        }
    }
}

// ---------------- dense MFMA GEMM, 64x64 tile, BK=64, gload_lds + XOR swizzle
// + XCD remap.  C[M,N] = act(A @ W^T + bias) + res   (N % 64 == 0)
template <int ACT, int OBF16, int SPLIT>
__global__ __launch_bounds__(256) void k_bgs(const ushort* __restrict__ A,
                                             const ushort* __restrict__ W,
                                             const float* __restrict__ bias,
                                             const float* __restrict__ res,
                                             void* __restrict__ Cp,
                                             float* __restrict__ part,
                                             int M, int N, int K, int S) {
    __shared__ __align__(16) ushort As[64 * 64];
    __shared__ __align__(16) ushort Bs[64 * 64];
    int tid = threadIdx.x;

    int nwg  = gridDim.x * gridDim.y * gridDim.z;
    int orig = blockIdx.x + gridDim.x * (blockIdx.y + gridDim.y * blockIdx.z);
    int work = xcd_remap(orig, nwg);
    int bx = work % gridDim.x;
    int rest = work / gridDim.x;
    int by = rest % gridDim.y;
    int bz = rest / gridDim.y;

    int row0 = bx * 64, col0 = by * 64;
    int z = bz;
    int Kc = K / S;              // multiple of 64
    int kbeg = z * Kc;
    int steps = Kc >> 6;

    int w = tid >> 6, lane = tid & 63;
    int lrow = lane >> 3;
    int cg   = ((lane & 7) ^ lrow) << 3;

    int ar0 = row0 + w * 16 + lrow; if (ar0 > M - 1) ar0 = M - 1;
    int ar1 = row0 + w * 16 + 8 + lrow; if (ar1 > M - 1) ar1 = M - 1;
    int wr0 = col0 + w * 16 + lrow;
    int wr1 = wr0 + 8;
    const ushort* ap0 = A + (size_t)ar0 * K + kbeg + cg;
    const ushort* ap1 = A + (size_t)ar1 * K + kbeg + cg;
    const ushort* wp0 = W + (size_t)wr0 * K + kbeg + cg;
    const ushort* wp1 = W + (size_t)wr1 * K + kbeg + cg;
    ushort* asd0 = &As[(w * 16) * 64];
    ushort* asd1 = &As[(w * 16 + 8) * 64];
    ushort* bsd0 = &Bs[(w * 16) * 64];
    ushort* bsd1 = &Bs[(w * 16 + 8) * 64];

    int fr = lane & 15, kg8 = (lane >> 4) << 3;
    int wrr = (w >> 1) * 32, wcc = (w & 1) * 32;
    int sw = (fr & 7) << 3;

    f32x4 acc[2][2] = {};
    for (int s = 0; s < steps; ++s) {
        int kk = s << 6;
        __syncthreads();
        g2lds16(ap0 + kk, asd0);
        g2lds16(ap1 + kk, asd1);
        g2lds16(wp0 + kk, bsd0);
        g2lds16(wp1 + kk, bsd1);
        __syncthreads();
#pragma unroll
        for (int j = 0; j < 2; ++j) {
            int ko = j * 32 + kg8;
            int kx = ko ^ sw;
            short8 a0 = *(const short8*)&As[(wrr + fr) * 64 + kx];
            short8 a1 = *(const short8*)&As[(wrr + 16 + fr) * 64 + kx];
            short8 b0 = *(const short8*)&Bs[(wcc + fr) * 64 + kx];
            short8 b1 = *(const short8*)&Bs[(wcc + 16 + fr) * 64 + kx];
            acc[0][0] = __builtin_amdgcn_mfma_f32_16x16x32_bf16(a0, b0, acc[0][0], 0, 0, 0);
            acc[0][1] = __builtin_amdgcn_mfma_f32_16x16x32_bf16(a0, b1, acc[0][1], 0, 0, 0);
            acc[1][0] = __builtin_amdgcn_mfma_f32_16x16x32_bf16(a1, b0, acc[1][0], 0, 0, 0);
            acc[1][1] = __builtin_amdgcn_mfma_f32_16x16x32_bf16(a1, b1, acc[1][1], 0, 0, 0);
        }
    }

#pragma unroll
    for (int fi = 0; fi < 2; fi++)
#pragma unroll
        for (int fj = 0; fj < 2; fj++)
#pragma unroll
            for (int r = 0; r < 4; r++) {
                int row = row0 + wrr + fi * 16 + (lane >> 4) * 4 + r;
                int col = col0 + wcc + fj * 16 + fr;
                if (row < M) {
                    if (SPLIT) {
                        part[((size_t)z * M + row) * N + col] = acc[fi][fj][r];
                    } else {
                        float v = acc[fi][fj][r] + bias[col];
                        if (res) v += res[(size_t)row * N + col];
                        if (ACT == 1) v = gelu_f(v);
                        if (OBF16) ((ushort*)Cp)[(size_t)row * N + col] = f2bf(v);
                        else       ((float*)Cp)[(size_t)row * N + col] = v;
                    }
                }
            }
}

// ---------------- PV attention GEMM: k_bgs structure, head-batched ------------
// O[h] = P[h][900][960] @ Vt[h][128][960]^T  -> ob[900][1152] (col guard 72)
// grid (15 M-tiles, 2 N-tiles, 16 heads).
__global__ __launch_bounds__(256) void k_att(const ushort* __restrict__ P,
                                             const ushort* __restrict__ Vt,
                                             ushort* __restrict__ ob) {
    __shared__ __align__(16) ushort As[64 * 64];
    __shared__ __align__(16) ushort Bs[64 * 64];
    int tid = threadIdx.x;

    int nwg  = gridDim.x * gridDim.y * gridDim.z;
    int orig = blockIdx.x + gridDim.x * (blockIdx.y + gridDim.y * blockIdx.z);
    int work = xcd_remap(orig, nwg);
    int bx = work % gridDim.x;
    int rest = work / gridDim.x;
    int by = rest % gridDim.y;
    int h  = rest / gridDim.y;

    int row0 = bx * 64, col0 = by * 64;
    const ushort* Ah = P  + (size_t)h * NT * PW;
    const ushort* Wh = Vt + (size_t)h * VR * PW;

    int w = tid >> 6, lane = tid & 63;
    int lrow = lane >> 3;
    int cg   = ((lane & 7) ^ lrow) << 3;

    int ar0 = row0 + w * 16 + lrow; if (ar0 > NT - 1) ar0 = NT - 1;
    int ar1 = row0 + w * 16 + 8 + lrow; if (ar1 > NT - 1) ar1 = NT - 1;
    int wr0 = col0 + w * 16 + lrow;          // < 128 = VR
    int wr1 = wr0 + 8;
    const ushort* ap0 = Ah + (size_t)ar0 * PW + cg;
    const ushort* ap1 = Ah + (size_t)ar1 * PW + cg;
    const ushort* wp0 = Wh + (size_t)wr0 * PW + cg;
    const ushort* wp1 = Wh + (size_t)wr1 * PW + cg;
    ushort* asd0 = &As[(w * 16) * 64];
    ushort* asd1 = &As[(w * 16 + 8) * 64];
    ushort* bsd0 = &Bs[(w * 16) * 64];
    ushort* bsd1 = &Bs[(w * 16 + 8) * 64];

    int fr = lane & 15, kg8 = (lane >> 4) << 3;
    int wrr = (w >> 1) * 32, wcc = (w & 1) * 32;
    int sw = (fr & 7) << 3;

    f32x4 acc[2][2] = {};
    for (int s = 0; s < 15; ++s) {
        int kk = s << 6;
        __syncthreads();
        g2lds16(ap0 + kk, asd0);
        g2lds16(ap1 + kk, asd1);
        g2lds16(wp0 + kk, bsd0);
        g2lds16(wp1 + kk, bsd1);
        __syncthreads();
#pragma unroll
        for (int j = 0; j < 2; ++j) {
            int ko = j * 32 + kg8;
            int kx = ko ^ sw;
            short8 a0 = *(const short8*)&As[(wrr + fr) * 64 + kx];
            short8 a1 = *(const short8*)&As[(wrr + 16 + fr) * 64 + kx];
            short8 b0 = *(const short8*)&Bs[(wcc + fr) * 64 + kx];
            short8 b1 = *(const short8*)&Bs[(wcc + 16 + fr) * 64 + kx];
            acc[0][0] = __builtin_amdgcn_mfma_f32_16x16x32_bf16(a0, b0, acc[0][0], 0, 0, 0);
            acc[0][1] = __builtin_amdgcn_mfma_f32_16x16x32_bf16(a0, b1, acc[0][1], 0, 0, 0);
            acc[1][0] = __builtin_amdgcn_mfma_f32_16x16x32_bf16(a1, b0, acc[1][0], 0, 0, 0);
            acc[1][1] = __builtin_amdgcn_mfma_f32_16x16x32_bf16(a1, b1, acc[1][1], 0, 0, 0);
        }
    }

#pragma unroll
    for (int fi = 0; fi < 2; fi++)
#pragma unroll
        for (int fj = 0; fj < 2; fj++)
#pragma unroll
            for (int r = 0; r < 4; r++) {
                int row = row0 + wrr + fi * 16 + (lane >> 4) * 4 + r;
                int col = col0 + wcc + fj * 16 + fr;
                if (row < NT && col < DHD)
                    ob[(size_t)row * EMB + h * DHD + col] = f2bf(acc[fi][fj][r]);
            }
}

// ---------------- split-K fixup (no LN) ----------------
template <int ACT, int OBF16>
__global__ __launch_bounds__(256) void k_fix(const float* __restrict__ part,
                                             const float* __restrict__ bias,
                                             const float* __restrict__ res,
                                             void* __restrict__ Cp,
                                             int M, int N, int S) {
    size_t idx = (size_t)blockIdx.x * 256 + threadIdx.x;
    size_t total = (size_t)M * N / 4;
    if (idx >= total) return;
    size_t e = idx * 4;
    int row = (int)(e / N), col = (int)(e - (size_t)row * N);
    float4 v = *(const float4*)(part + e);
    for (int s = 1; s < S; ++s) {
        const float4 p = *(const float4*)(part + (size_t)s * M * N + e);
        v.x += p.x; v.y += p.y; v.z += p.z; v.w += p.w;
    }
    const float4 bi = *(const float4*)(bias + col);
    v.x += bi.x; v.y += bi.y; v.z += bi.z; v.w += bi.w;
    if (res) {
        const float4 rr = *(const float4*)(res + e);
        v.x += rr.x; v.y += rr.y; v.z += rr.z; v.w += rr.w;
    }
    if (ACT == 1) { v.x = gelu_f(v.x); v.y = gelu_f(v.y); v.z = gelu_f(v.z); v.w = gelu_f(v.w); }
    if (OBF16) {
        ushort o[4] = { f2bf(v.x), f2bf(v.y), f2bf(v.z), f2bf(v.w) };
        *(uint2*)((ushort*)Cp + e) = *(const uint2*)o;
    } else {
        *(float4*)((float*)Cp + e) = v;
    }
}

// ---------------- QK^T GEMM (bf16, batched over heads), BK=32, XCD remap ----
__global__ __launch_bounds__(256) void k_mm(const ushort* __restrict__ A,
                                            const ushort* __restrict__ Wb,
                                            float* __restrict__ Cf,
                                            int M, int N, int K, int ldc, int Nw,
                                            long as_, long ws_, long cs_) {
    __shared__ __align__(16) ushort As[64 * 40];
    __shared__ __align__(16) ushort Bs[64 * 40];
    int nwg  = gridDim.x * gridDim.y * gridDim.z;
    int orig = blockIdx.x + gridDim.x * (blockIdx.y + gridDim.y * blockIdx.z);
    int work = xcd_remap(orig, nwg);
    int bx = work % gridDim.x;
    int rest = work / gridDim.x;
    int by = rest % gridDim.y;
    int z  = rest / gridDim.y;

    A  += (size_t)z * as_;
    Wb += (size_t)z * ws_;
    Cf += (size_t)z * cs_;

    int tid = threadIdx.x;
    int row0 = by * 64, col0 = bx * 64;

    int sm = tid >> 2, sp = tid & 3;
    int ar = row0 + sm; if (ar > M - 1) ar = M - 1;
    int wr = col0 + sm; if (wr > N - 1) wr = N - 1;
    const ushort* aptr = A + (size_t)ar * K;

    int lane = tid & 63, wid = tid >> 6;
    int wrr = (wid >> 1) * 32, wcc = (wid & 1) * 32;
    int fr = lane & 15, kg = lane >> 4;

    f32x4 acc[2][2] = {};

    for (int k0 = 0; k0 < K; k0 += 32) {
        *(uint4*)&As[sm * 40 + sp * 8] = *(const uint4*)(aptr + k0 + sp * 8);
        *(uint4*)&Bs[sm * 40 + sp * 8] = *(const uint4*)(Wb + (size_t)wr * K + k0 + sp * 8);
        __syncthreads();
        short8 a0 = *(const short8*)&As[(wrr + fr) * 40 + kg * 8];
        short8 a1 = *(const short8*)&As[(wrr + 16 + fr) * 40 + kg * 8];
        short8 b0 = *(const short8*)&Bs[(wcc + fr) * 40 + kg * 8];
        short8 b1 = *(const short8*)&Bs[(wcc + 16 + fr) * 40 + kg * 8];
        acc[0][0] = __builtin_amdgcn_mfma_f32_16x16x32_bf16(a0, b0, acc[0][0], 0, 0, 0);
        acc[0][1] = __builtin_amdgcn_mfma_f32_16x16x32_bf16(a0, b1, acc[0][1], 0, 0, 0);
        acc[1][0] = __builtin_amdgcn_mfma_f32_16x16x32_bf16(a1, b0, acc[1][0], 0, 0, 0);
        acc[1][1] = __builtin_amdgcn_mfma_f32_16x16x32_bf16(a1, b1, acc[1][1], 0, 0, 0);
        __syncthreads();
    }

#pragma unroll
    for (int fi = 0; fi < 2; fi++)
#pragma unroll
        for (int fj = 0; fj < 2; fj++)
#pragma unroll
            for (int r = 0; r < 4; r++) {
                int row = row0 + wrr + fi * 16 + (lane >> 4) * 4 + r;
                int col = col0 + wcc + fj * 16 + (lane & 15);
                if (row < M && col < Nw)
                    Cf[(size_t)row * ldc + col] = acc[fi][fj][r];
            }
}

// ---------------- qkv f32 -> rope(q),rope(k) bf16 [16,900,96], v^T bf16 [16,128,960]
__global__ __launch_bounds__(256) void k_rope(const float* __restrict__ qkv,
                                              const float* __restrict__ cs,
                                              const float* __restrict__ sn,
                                              ushort* __restrict__ q,
                                              ushort* __restrict__ k,
                                              ushort* __restrict__ vt) {
    int idx = blockIdx.x * 256 + threadIdx.x;
    if (idx >= NT * NH * DHP) return;
    int t = idx / (NH * DHP);
    int rem = idx - t * (NH * DHP);
    int h = rem / DHP, d = rem - h * DHP;
    size_t oi = ((size_t)h * NT + t) * DHP + d;
    if (d < DHD) {
        const float* base = qkv + (size_t)t * 3 * EMB;
        float c = cs[t * DHD + d], s = sn[t * DHD + d];
        int   d2 = (d < DHH) ? d + DHH : d - DHH;
        float sg = (d < DHH) ? -1.f : 1.f;
        int e = h * DHD + d;
        float qv = base[e] * c + sg * base[h * DHD + d2] * s;
        float kv = base[EMB + e] * c + sg * base[EMB + h * DHD + d2] * s;
        q[oi] = f2bf(qv);
        k[oi] = f2bf(kv);
        vt[((size_t)h * VR + d) * PW + t] = f2bf(base[2 * EMB + e]);
    } else {
        q[oi] = 0;
        k[oi] = 0;
    }
}

// zero whole v^T buffer once per launch (rope fills the valid region after)
__global__ __launch_bounds__(256) void k_vzero(ushort* __restrict__ vt) {
    int idx = blockIdx.x * 256 + threadIdx.x;
    int tot = NH * VR * PW / 8;
    if (idx >= tot) return;
    uint4 z = { 0, 0, 0, 0 };
    *(uint4*)(vt + (size_t)idx * 8) = z;
}

// ---------------- softmax: S f32 [16*900][928] -> P bf16 [16*900][960] -------
__global__ __launch_bounds__(256) void k_sm(const float* __restrict__ S,
                                            ushort* __restrict__ P) {
    int row = blockIdx.x * 4 + (threadIdx.x >> 6);
    int lane = threadIdx.x & 63;
    const float* sp = S + (size_t)row * KVP;
    ushort* pp = P + (size_t)row * PW;
    float v[15];
#pragma unroll
    for (int i = 0; i < 15; i++) {
        int kt = lane + i * 64;
        v[i] = (kt < NT) ? sp[kt] : -1e30f;
    }
    float mx = -1e30f;
#pragma unroll
    for (int i = 0; i < 15; i++) mx = fmaxf(mx, v[i]);
    for (int off = 32; off; off >>= 1) mx = fmaxf(mx, __shfl_xor(mx, off, 64));
    float sum = 0.f;
#pragma unroll
    for (int i = 0; i < 15; i++) {
        int kt = lane + i * 64;
        v[i] = (kt < NT) ? __expf(v[i] - mx) : 0.f;
        sum += v[i];
    }
    for (int off = 32; off; off >>= 1) sum += __shfl_xor(sum, off, 64);
    float inv = 1.f / sum;
#pragma unroll
    for (int i = 0; i < 15; i++) {
        int kt = lane + i * 64;
        pp[kt] = f2bf(v[i] * inv);      // kt < 960 always (max 959)
    }
}

extern "C" void kernel_launch(void* const* d_in, const int* in_sizes, int n_in,
                              void* d_out, int out_size, void* d_ws, size_t ws_size,
                              hipStream_t stream) {
    const float* pix     = (const float*)d_in[0];
    const float* patch_w = (const float*)d_in[1];
    const float* patch_b = (const float*)d_in[2];
    const float* pos_emb = (const float*)d_in[3];
    const float* cosb    = (const float*)d_in[4];
    const float* sinb    = (const float*)d_in[5];
    const float* ln1_w   = (const float*)d_in[6];
    const float* ln1_b   = (const float*)d_in[7];
    const float* qkv_w   = (const float*)d_in[8];
    const float* qkv_b   = (const float*)d_in[9];
    const float* proj_w  = (const float*)d_in[10];
    const float* proj_b  = (const float*)d_in[11];
    const float* ln2_w   = (const float*)d_in[12];
    const float* ln2_b   = (const float*)d_in[13];
    const float* fc1_w   = (const float*)d_in[14];
    const float* fc1_b   = (const float*)d_in[15];
    const float* fc2_w   = (const float*)d_in[16];
    const float* fc2_b   = (const float*)d_in[17];
    const float* dsn_w   = (const float*)d_in[18];
    const float* dsn_b   = (const float*)d_in[19];
    const float* ds1_w   = (const float*)d_in[20];
    const float* ds1_b   = (const float*)d_in[21];
    const float* ds2_w   = (const float*)d_in[22];
    const float* ds2_b   = (const float*)d_in[23];
    const float* mn_w    = (const float*)d_in[24];
    const float* mn_b    = (const float*)d_in[25];
    const float* mf1_w   = (const float*)d_in[26];
    const float* mf1_b   = (const float*)d_in[27];
    const float* mf2_w   = (const float*)d_in[28];
    const float* mf2_b   = (const float*)d_in[29];
    float* out = (float*)d_out;

    // ---- workspace carve ----
    float* wsf = (float*)d_ws;
    size_t off = 0;
    auto af = [&](size_t n) { float* p = wsf + off; off += (n + 3) & ~(size_t)3; return p; };
    float* h    = af((size_t)NT * EMB);
    float* qkv  = af((size_t)NT * 3 * EMB);
    float* part = af((size_t)4 * NT * EMB);
    float* S    = af((size_t)NH * NT * KVP);
    ushort* wsh = (ushort*)(wsf + off);
    size_t hoff = 0;
    auto ah = [&](size_t n) { ushort* p = wsh + hoff; hoff += (n + 7) & ~(size_t)7; return p; };
    ushort* hn  = ah((size_t)NT * EMB);
    ushort* hn2 = ah((size_t)NM * MHD);
    ushort* qb  = ah((size_t)NH * NT * DHP);
    ushort* kb  = ah((size_t)NH * NT * DHP);
    ushort* vt  = ah((size_t)NH * VR * PW);
    ushort* P   = ah((size_t)NH * NT * PW);
    ushort* ob  = ah((size_t)NT * EMB);
    ushort* t1  = ah((size_t)NT * FFD);
    ushort* xp  = t1;
    // bf16 weight mirrors
    ushort* w_patch = ah((size_t)EMB * 1536);
    ushort* w_qkv   = ah((size_t)NL * 3 * EMB * EMB);
    ushort* w_proj  = ah((size_t)NL * EMB * EMB);
    ushort* w_fc1   = ah((size_t)NL * FFD * EMB);
    ushort* w_fc2   = ah((size_t)NL * EMB * FFD);
    ushort* w_ds1   = ah((size_t)2 * MHD * MHD);
    ushort* w_ds2   = ah((size_t)2 * OUTD * MHD);
    ushort* w_mf1   = ah((size_t)MHD * MHD);
    ushort* w_mf2   = ah((size_t)OUTD * MHD);

    const long QS = (long)NT * DHP;
    const long SS = (long)NT * KVP;
    const long MN = (long)NT * EMB;

    const int MB  = (NT + 63) / 64;   // 15
    const int MBm = (NM + 63) / 64;   // 4
    auto fixg = [](int M, int N) { return dim3(((size_t)M * N / 4 + 255) / 256); };

    // ---- merged weight pre-conversion (one launch) ----
    CvtArgs ca;
    const float* srcs[9] = { patch_w, qkv_w, proj_w, fc1_w, fc2_w, ds1_w, ds2_w, mf1_w, mf2_w };
    ushort* dsts[9] = { w_patch, w_qkv, w_proj, w_fc1, w_fc2, w_ds1, w_ds2, w_mf1, w_mf2 };
    long lens[9] = { (long)EMB * 1536, (long)NL * 3 * EMB * EMB, (long)NL * EMB * EMB,
                     (long)NL * FFD * EMB, (long)NL * EMB * FFD, (long)2 * MHD * MHD,
                     (long)2 * OUTD * MHD, (long)MHD * MHD, (long)OUTD * MHD };
    ca.off[0] = 0;
    for (int i = 0; i < 9; ++i) {
        ca.src[i] = srcs[i];
        ca.dst[i] = dsts[i];
        ca.off[i + 1] = ca.off[i] + lens[i] / 4;
    }
    k_cvt9<<<dim3((unsigned)((ca.off[9] + 255) / 256)), 256, 0, stream>>>(ca);

    k_patch<<<dim3((NT * 1536 + 255) / 256), 256, 0, stream>>>(pix, xp);
    k_vzero<<<dim3((NH * VR * PW / 8 + 255) / 256), 256, 0, stream>>>(vt);
    // patch: M=900 N=1152 K=1536, S=2; fused: +pos_emb -> h, then ln1[0] -> hn
    k_bgs<0, 0, 1><<<dim3(MB, EMB / 64, 2), 256, 0, stream>>>(
        xp, w_patch, nullptr, nullptr, nullptr, part, NT, EMB, 1536, 2);
    k_fixln<<<NT, 256, 0, stream>>>(part, patch_b, pos_emb, h,
                                    ln1_w, ln1_b, hn, EMB, 2, MN);

    for (int l = 0; l < NL; ++l) {
        // qkv: M=900 N=3456 K=1152, S=1 -> 810 blocks, direct f32 + bias
        k_bgs<0, 0, 0><<<dim3(MB, 3 * EMB / 64, 1), 256, 0, stream>>>(
            hn, w_qkv + (size_t)l * 3 * EMB * EMB, qkv_b + l * 3 * EMB, nullptr, qkv,
            nullptr, NT, 3 * EMB, EMB, 1);
        k_rope<<<dim3((NT * NH * DHP + 255) / 256), 256, 0, stream>>>(
            qkv, cosb, sinb, qb, kb, vt);
        // S = Q @ K^T (per head), f32
        k_mm<<<dim3(MB, MB, NH), 256, 0, stream>>>(
            qb, kb, S, NT, NT, DHP, KVP, NT, QS, QS, SS);
        k_sm<<<dim3(NH * NT / 4), 256, 0, stream>>>(S, P);
        // O = P @ V (per head) via k_bgs-structure PV kernel
        k_att<<<dim3(MB, 2, NH), 256, 0, stream>>>(P, vt, ob);
        // proj: M=900 N=1152 K=1152, S=3; fused: +h residual -> h, then ln2 -> hn
        k_bgs<0, 0, 1><<<dim3(MB, EMB / 64, 3), 256, 0, stream>>>(
            ob, w_proj + (size_t)l * EMB * EMB, nullptr, nullptr, nullptr, part,
            NT, EMB, EMB, 3);
        k_fixln<<<NT, 256, 0, stream>>>(part, proj_b + l * EMB, h, h,
                                        ln2_w + l * EMB, ln2_b + l * EMB, hn,
                                        EMB, 3, MN);
        // fc1: M=900 N=4608 K=1152, S=1 -> 1080 blocks, direct gelu bf16
        k_bgs<1, 1, 0><<<dim3(MB, FFD / 64, 1), 256, 0, stream>>>(
            hn, w_fc1 + (size_t)l * FFD * EMB, fc1_b + l * FFD, nullptr, t1,
            nullptr, NT, FFD, EMB, 1);
        // fc2: M=900 N=1152 K=4608, S=4; fused: +h residual -> h, then next-LN -> hn
        const float* nlw = (l == NL - 1) ? mn_w : ln1_w + (l + 1) * EMB;
        const float* nlb = (l == NL - 1) ? mn_b : ln1_b + (l + 1) * EMB;
        k_bgs<0, 0, 1><<<dim3(MB, EMB / 64, 4), 256, 0, stream>>>(
            t1, w_fc2 + (size_t)l * EMB * FFD, nullptr, nullptr, nullptr, part,
            NT, EMB, FFD, 4);
        k_fixln<<<NT, 256, 0, stream>>>(part, fc2_b + l * EMB, h, h,
                                        nlw, nlb, hn, EMB, 4, MN);
        if (l == 2 || l == 5) {
            int d = (l == 2) ? 0 : 1;
            k_ln<<<NM, 256, 0, stream>>>(h, dsn_w + d * MHD, dsn_b + d * MHD, hn2, MHD);
            // ds1: M=225 N=4608 K=4608, S=4
            k_bgs<0, 0, 1><<<dim3(MBm, MHD / 64, 4), 256, 0, stream>>>(
                hn2, w_ds1 + (size_t)d * MHD * MHD, nullptr, nullptr, nullptr, part,
                NM, MHD, MHD, 4);
            k_fix<1, 1><<<fixg(NM, MHD), 256, 0, stream>>>(part, ds1_b + d * MHD,
                                                           nullptr, t1, NM, MHD, 4);
            // ds2: M=225 N=2048 K=4608, S=4
            k_bgs<0, 0, 1><<<dim3(MBm, OUTD / 64, 4), 256, 0, stream>>>(
                t1, w_ds2 + (size_t)d * OUTD * MHD, nullptr, nullptr, nullptr, part,
                NM, OUTD, MHD, 4);
            k_fix<0, 0><<<fixg(NM, OUTD), 256, 0, stream>>>(
                part, ds2_b + d * OUTD, nullptr, out + (size_t)d * NM * OUTD,
                NM, OUTD, 4);
        }
    }
    // merger: hn already holds merger-LN output ([900][1152] == [225][4608])
    k_bgs<0, 0, 1><<<dim3(MBm, MHD / 64, 4), 256, 0, stream>>>(
        hn, w_mf1, nullptr, nullptr, nullptr, part, NM, MHD, MHD, 4);
    k_fix<1, 1><<<fixg(NM, MHD), 256, 0, stream>>>(part, mf1_b, nullptr, t1, NM, MHD, 4);
    k_bgs<0, 0, 1><<<dim3(MBm, OUTD / 64, 4), 256, 0, stream>>>(
        t1, w_mf2, nullptr, nullptr, nullptr, part, NM, OUTD, MHD, 4);
    k_fix<0, 0><<<fixg(NM, OUTD), 256, 0, stream>>>(
        part, mf2_b, nullptr, out + (size_t)2 * NM * OUTD, NM, OUTD, 4);
}

// Round 17
// 1294.946 us; speedup vs baseline: 1.2557x; 1.0014x over previous
//
#include <hip/hip_runtime.h>
#include <hip/hip_bf16.h>
#include <cstdint>

#define NT   900
#define EMB  1152
#define NH   16
#define DHD  72
#define DHH  36
#define DHP  96      // padded head dim for QK (3*32)
#define KVP  928     // S width (29*32)
#define PW   960     // P / V^T K-width for PV (15*64)
#define VR   128     // V^T padded rows per head
#define NL   6
#define FFD  4608
#define MHD  4608
#define OUTD 2048
#define NM   225

typedef __attribute__((ext_vector_type(8))) short short8;
typedef __attribute__((ext_vector_type(4))) float f32x4;

__device__ __forceinline__ ushort f2bf(float f) {
    uint32_t u = __float_as_uint(f);
    uint32_t r = u + 0x7FFF + ((u >> 16) & 1);
    return (ushort)(r >> 16);
}
__device__ __forceinline__ float gelu_f(float x) {
    return 0.5f * x * (1.0f + tanhf(0.7978845608f * (x + 0.044715f * x * x * x)));
}

// async global -> LDS, 16B per lane (lds dest wave-uniform base; HW adds lane*16)
__device__ __forceinline__ void g2lds16(const ushort* g, ushort* l) {
    __builtin_amdgcn_global_load_lds(
        (const __attribute__((address_space(1))) unsigned int*)g,
        (__attribute__((address_space(3))) unsigned int*)l, 16, 0, 0);
}

// XCD-chunked bijective block remap (T1, m204): contiguous work chunk per XCD.
__device__ __forceinline__ int xcd_remap(int orig, int nwg) {
    int xcd = orig & 7, loc = orig >> 3;
    int q8 = nwg >> 3, r8 = nwg & 7;
    return (xcd < r8 ? xcd * (q8 + 1) : r8 * (q8 + 1) + (xcd - r8) * q8) + loc;
}

// ---------------- merged weight f32 -> bf16 pre-conversion (9 segments) ------
// Block-chunked: each block converts 2048 consecutive float4s of ONE segment
// (8 float4 = 128B read / 64B write per thread). Segment decoded once per
// block from a block-prefix table (uniform branches).
#define CVT_CHUNK 2048L
struct CvtArgs {
    const float* src[9];
    ushort* dst[9];
    long len4[9];          // segment lengths in float4 units
    int blk[10];           // block prefix sums
};
__global__ __launch_bounds__(256) void k_cvt9(CvtArgs a) {
    int b = blockIdx.x;
    int g = 0;
#pragma unroll
    for (int i = 1; i < 9; ++i) if (b >= a.blk[i]) g = i;
    long n4 = a.len4[g];
    long base = (long)(b - a.blk[g]) * CVT_CHUNK;
    const float* s = a.src[g];
    ushort* d = a.dst[g];
#pragma unroll
    for (int j = 0; j < 8; ++j) {
        long i4 = base + threadIdx.x + j * 256;
        if (i4 < n4) {
            const float4 v = *(const float4*)(s + i4 * 4);
            ushort o[4] = { f2bf(v.x), f2bf(v.y), f2bf(v.z), f2bf(v.w) };
            *(uint2*)(d + i4 * 4) = *(const uint2*)o;
        }
    }
}

// ---------------- patch extraction + v^T zero (merged grids) ----------------
// blocks [0, PB): patch pixels -> bf16 [900,1536]; blocks [PB, PB+VB): zero vt.
__global__ __launch_bounds__(256) void k_patch(const float* __restrict__ pix,
                                               ushort* __restrict__ xp,
                                               ushort* __restrict__ vt, int PB) {
    if ((int)blockIdx.x >= PB) {
        int idx = ((int)blockIdx.x - PB) * 256 + threadIdx.x;
        if (idx < NH * VR * PW / 8) {
            uint4 z = { 0, 0, 0, 0 };
            *(uint4*)(vt + (size_t)idx * 8) = z;
        }
        return;
    }
    int idx = blockIdx.x * 256 + threadIdx.x;
    if (idx >= NT * 1536) return;
    int t = idx / 1536, f = idx - t * 1536;
    int mw = t & 1, mh = (t >> 1) & 1;
    int tq = t >> 2;
    int jj = tq % 15, ii = tq / 15;
    int pw = f & 15, ph = (f >> 4) & 15, c = f >> 9;
    int Hi = (ii * 2 + mh) * 16 + ph;
    int Wi = (jj * 2 + mw) * 16 + pw;
    float p = pix[((size_t)c * 480 + Hi) * 480 + Wi];
    xp[idx] = f2bf((p - 127.5f) * (1.0f / 127.5f));
}

// ---------------- layernorm f32 in -> bf16 out, one block per row ----------------
__global__ __launch_bounds__(256) void k_ln(const float* __restrict__ x,
                                            const float* __restrict__ w,
                                            const float* __restrict__ b,
                                            ushort* __restrict__ y, int C) {
    int row = blockIdx.x;
    int tid = threadIdx.x;
    const float* xr = x + (size_t)row * C;
    float s = 0.f, ss = 0.f;
    for (int c = tid; c < C; c += 256) { float v = xr[c]; s += v; ss += v * v; }
    for (int off = 32; off; off >>= 1) {
        s  += __shfl_down(s,  off, 64);
        ss += __shfl_down(ss, off, 64);
    }
    __shared__ float rs[4], rss[4];
    int wid = tid >> 6, lane = tid & 63;
    if (lane == 0) { rs[wid] = s; rss[wid] = ss; }
    __syncthreads();
    float S  = rs[0] + rs[1] + rs[2] + rs[3];
    float SS = rss[0] + rss[1] + rss[2] + rss[3];
    float mu  = S / C;
    float var = SS / C - mu * mu;
    float inv = rsqrtf(var + 1e-6f);
    ushort* yr = y + (size_t)row * C;
    for (int c = tid; c < C; c += 256) yr[c] = f2bf((xr[c] - mu) * inv * w[c] + b[c]);
}

// ---------------- fused split-K reduce + bias + residual + LayerNorm ----------------
__global__ __launch_bounds__(256) void k_fixln(const float* __restrict__ part,
                                               const float* __restrict__ bias,
                                               const float* __restrict__ res,
                                               float* __restrict__ hout,
                                               const float* __restrict__ lw,
                                               const float* __restrict__ lb,
                                               ushort* __restrict__ y,
                                               int C, int S, long MN) {
    int row = blockIdx.x, tid = threadIdx.x;
    int C4 = C >> 2;
    const float* prow = part + (size_t)row * C;
    const float* rrow = res + (size_t)row * C;
    float* hrow = hout + (size_t)row * C;
    ushort* yrow = y + (size_t)row * C;

    float4 vals[2];
    float s = 0.f, ss = 0.f;
    int idx[2] = { tid, tid + 256 };
#pragma unroll
    for (int it = 0; it < 2; ++it) {
        int c4 = idx[it];
        if (c4 < C4) {
            float4 v = *(const float4*)(prow + c4 * 4);
            for (int sI = 1; sI < S; ++sI) {
                const float4 p = *(const float4*)(prow + (size_t)sI * MN + c4 * 4);
                v.x += p.x; v.y += p.y; v.z += p.z; v.w += p.w;
            }
            const float4 bi = *(const float4*)(bias + c4 * 4);
            v.x += bi.x; v.y += bi.y; v.z += bi.z; v.w += bi.w;
            const float4 rr = *(const float4*)(rrow + c4 * 4);
            v.x += rr.x; v.y += rr.y; v.z += rr.z; v.w += rr.w;
            *(float4*)(hrow + c4 * 4) = v;
            vals[it] = v;
            s  += v.x + v.y + v.z + v.w;
            ss += v.x * v.x + v.y * v.y + v.z * v.z + v.w * v.w;
        }
    }
    for (int off = 32; off; off >>= 1) {
        s  += __shfl_down(s,  off, 64);
        ss += __shfl_down(ss, off, 64);
    }
    __shared__ float rs[4], rss[4];
    int wid = tid >> 6, lane = tid & 63;
    if (lane == 0) { rs[wid] = s; rss[wid] = ss; }
    __syncthreads();
    float St  = rs[0] + rs[1] + rs[2] + rs[3];
    float SSt = rss[0] + rss[1] + rss[2] + rss[3];
    float mu  = St / C;
    float var = SSt / C - mu * mu;
    float inv = rsqrtf(var + 1e-6f);
#pragma unroll
    for (int it = 0; it < 2; ++it) {
        int c4 = idx[it];
        if (c4 < C4) {
            float4 v = vals[it];
            const float4 w4 = *(const float4*)(lw + c4 * 4);
            const float4 b4 = *(const float4*)(lb + c4 * 4);
            ushort o[4] = { f2bf((v.x - mu) * inv * w4.x + b4.x),
                            f2bf((v.y - mu) * inv * w4.y + b4.y),
                            f2bf((v.z - mu) * inv * w4.z + b4.z),
                            f2bf((v.w - mu) * inv * w4.w + b4.w) };
            *(uint2*)(yrow + c4 * 4) = *(const uint2*)o;
        }
    }
}

// ---------------- dense MFMA GEMM, 64x64 tile, BK=64, gload_lds + XOR swizzle
// + XCD remap.  C[M,N] = act(A @ W^T + bias) + res   (N % 64 == 0)
template <int ACT, int OBF16, int SPLIT>
__global__ __launch_bounds__(256) void k_bgs(const ushort* __restrict__ A,
                                             const ushort* __restrict__ W,
                                             const float* __restrict__ bias,
                                             const float* __restrict__ res,
                                             void* __restrict__ Cp,
                                             float* __restrict__ part,
                                             int M, int N, int K, int S) {
    __shared__ __align__(16) ushort As[64 * 64];
    __shared__ __align__(16) ushort Bs[64 * 64];
    int tid = threadIdx.x;

    int nwg  = gridDim.x * gridDim.y * gridDim.z;
    int orig = blockIdx.x + gridDim.x * (blockIdx.y + gridDim.y * blockIdx.z);
    int work = xcd_remap(orig, nwg);
    int bx = work % gridDim.x;
    int rest = work / gridDim.x;
    int by = rest % gridDim.y;
    int bz = rest / gridDim.y;

    int row0 = bx * 64, col0 = by * 64;
    int z = bz;
    int Kc = K / S;              // multiple of 64
    int kbeg = z * Kc;
    int steps = Kc >> 6;

    int w = tid >> 6, lane = tid & 63;
    int lrow = lane >> 3;
    int cg   = ((lane & 7) ^ lrow) << 3;

    int ar0 = row0 + w * 16 + lrow; if (ar0 > M - 1) ar0 = M - 1;
    int ar1 = row0 + w * 16 + 8 + lrow; if (ar1 > M - 1) ar1 = M - 1;
    int wr0 = col0 + w * 16 + lrow;
    int wr1 = wr0 + 8;
    const ushort* ap0 = A + (size_t)ar0 * K + kbeg + cg;
    const ushort* ap1 = A + (size_t)ar1 * K + kbeg + cg;
    const ushort* wp0 = W + (size_t)wr0 * K + kbeg + cg;
    const ushort* wp1 = W + (size_t)wr1 * K + kbeg + cg;
    ushort* asd0 = &As[(w * 16) * 64];
    ushort* asd1 = &As[(w * 16 + 8) * 64];
    ushort* bsd0 = &Bs[(w * 16) * 64];
    ushort* bsd1 = &Bs[(w * 16 + 8) * 64];

    int fr = lane & 15, kg8 = (lane >> 4) << 3;
    int wrr = (w >> 1) * 32, wcc = (w & 1) * 32;
    int sw = (fr & 7) << 3;

    f32x4 acc[2][2] = {};
    for (int s = 0; s < steps; ++s) {
        int kk = s << 6;
        __syncthreads();
        g2lds16(ap0 + kk, asd0);
        g2lds16(ap1 + kk, asd1);
        g2lds16(wp0 + kk, bsd0);
        g2lds16(wp1 + kk, bsd1);
        __syncthreads();
#pragma unroll
        for (int j = 0; j < 2; ++j) {
            int ko = j * 32 + kg8;
            int kx = ko ^ sw;
            short8 a0 = *(const short8*)&As[(wrr + fr) * 64 + kx];
            short8 a1 = *(const short8*)&As[(wrr + 16 + fr) * 64 + kx];
            short8 b0 = *(const short8*)&Bs[(wcc + fr) * 64 + kx];
            short8 b1 = *(const short8*)&Bs[(wcc + 16 + fr) * 64 + kx];
            acc[0][0] = __builtin_amdgcn_mfma_f32_16x16x32_bf16(a0, b0, acc[0][0], 0, 0, 0);
            acc[0][1] = __builtin_amdgcn_mfma_f32_16x16x32_bf16(a0, b1, acc[0][1], 0, 0, 0);
            acc[1][0] = __builtin_amdgcn_mfma_f32_16x16x32_bf16(a1, b0, acc[1][0], 0, 0, 0);
            acc[1][1] = __builtin_amdgcn_mfma_f32_16x16x32_bf16(a1, b1, acc[1][1], 0, 0, 0);
        }
    }

#pragma unroll
    for (int fi = 0; fi < 2; fi++)
#pragma unroll
        for (int fj = 0; fj < 2; fj++)
#pragma unroll
            for (int r = 0; r < 4; r++) {
                int row = row0 + wrr + fi * 16 + (lane >> 4) * 4 + r;
                int col = col0 + wcc + fj * 16 + fr;
                if (row < M) {
                    if (SPLIT) {
                        part[((size_t)z * M + row) * N + col] = acc[fi][fj][r];
                    } else {
                        float v = acc[fi][fj][r] + bias[col];
                        if (res) v += res[(size_t)row * N + col];
                        if (ACT == 1) v = gelu_f(v);
                        if (OBF16) ((ushort*)Cp)[(size_t)row * N + col] = f2bf(v);
                        else       ((float*)Cp)[(size_t)row * N + col] = v;
                    }
                }
            }
}

// ---------------- PV attention GEMM: k_bgs structure, head-batched ------------
__global__ __launch_bounds__(256) void k_att(const ushort* __restrict__ P,
                                             const ushort* __restrict__ Vt,
                                             ushort* __restrict__ ob) {
    __shared__ __align__(16) ushort As[64 * 64];
    __shared__ __align__(16) ushort Bs[64 * 64];
    int tid = threadIdx.x;

    int nwg  = gridDim.x * gridDim.y * gridDim.z;
    int orig = blockIdx.x + gridDim.x * (blockIdx.y + gridDim.y * blockIdx.z);
    int work = xcd_remap(orig, nwg);
    int bx = work % gridDim.x;
    int rest = work / gridDim.x;
    int by = rest % gridDim.y;
    int h  = rest / gridDim.y;

    int row0 = bx * 64, col0 = by * 64;
    const ushort* Ah = P  + (size_t)h * NT * PW;
    const ushort* Wh = Vt + (size_t)h * VR * PW;

    int w = tid >> 6, lane = tid & 63;
    int lrow = lane >> 3;
    int cg   = ((lane & 7) ^ lrow) << 3;

    int ar0 = row0 + w * 16 + lrow; if (ar0 > NT - 1) ar0 = NT - 1;
    int ar1 = row0 + w * 16 + 8 + lrow; if (ar1 > NT - 1) ar1 = NT - 1;
    int wr0 = col0 + w * 16 + lrow;
    int wr1 = wr0 + 8;
    const ushort* ap0 = Ah + (size_t)ar0 * PW + cg;
    const ushort* ap1 = Ah + (size_t)ar1 * PW + cg;
    const ushort* wp0 = Wh + (size_t)wr0 * PW + cg;
    const ushort* wp1 = Wh + (size_t)wr1 * PW + cg;
    ushort* asd0 = &As[(w * 16) * 64];
    ushort* asd1 = &As[(w * 16 + 8) * 64];
    ushort* bsd0 = &Bs[(w * 16) * 64];
    ushort* bsd1 = &Bs[(w * 16 + 8) * 64];

    int fr = lane & 15, kg8 = (lane >> 4) << 3;
    int wrr = (w >> 1) * 32, wcc = (w & 1) * 32;
    int sw = (fr & 7) << 3;

    f32x4 acc[2][2] = {};
    for (int s = 0; s < 15; ++s) {
        int kk = s << 6;
        __syncthreads();
        g2lds16(ap0 + kk, asd0);
        g2lds16(ap1 + kk, asd1);
        g2lds16(wp0 + kk, bsd0);
        g2lds16(wp1 + kk, bsd1);
        __syncthreads();
#pragma unroll
        for (int j = 0; j < 2; ++j) {
            int ko = j * 32 + kg8;
            int kx = ko ^ sw;
            short8 a0 = *(const short8*)&As[(wrr + fr) * 64 + kx];
            short8 a1 = *(const short8*)&As[(wrr + 16 + fr) * 64 + kx];
            short8 b0 = *(const short8*)&Bs[(wcc + fr) * 64 + kx];
            short8 b1 = *(const short8*)&Bs[(wcc + 16 + fr) * 64 + kx];
            acc[0][0] = __builtin_amdgcn_mfma_f32_16x16x32_bf16(a0, b0, acc[0][0], 0, 0, 0);
            acc[0][1] = __builtin_amdgcn_mfma_f32_16x16x32_bf16(a0, b1, acc[0][1], 0, 0, 0);
            acc[1][0] = __builtin_amdgcn_mfma_f32_16x16x32_bf16(a1, b0, acc[1][0], 0, 0, 0);
            acc[1][1] = __builtin_amdgcn_mfma_f32_16x16x32_bf16(a1, b1, acc[1][1], 0, 0, 0);
        }
    }

#pragma unroll
    for (int fi = 0; fi < 2; fi++)
#pragma unroll
        for (int fj = 0; fj < 2; fj++)
#pragma unroll
            for (int r = 0; r < 4; r++) {
                int row = row0 + wrr + fi * 16 + (lane >> 4) * 4 + r;
                int col = col0 + wcc + fj * 16 + fr;
                if (row < NT && col < DHD)
                    ob[(size_t)row * EMB + h * DHD + col] = f2bf(acc[fi][fj][r]);
            }
}

// ---------------- split-K fixup (no LN) ----------------
template <int ACT, int OBF16>
__global__ __launch_bounds__(256) void k_fix(const float* __restrict__ part,
                                             const float* __restrict__ bias,
                                             const float* __restrict__ res,
                                             void* __restrict__ Cp,
                                             int M, int N, int S) {
    size_t idx = (size_t)blockIdx.x * 256 + threadIdx.x;
    size_t total = (size_t)M * N / 4;
    if (idx >= total) return;
    size_t e = idx * 4;
    int row = (int)(e / N), col = (int)(e - (size_t)row * N);
    float4 v = *(const float4*)(part + e);
    for (int s = 1; s < S; ++s) {
        const float4 p = *(const float4*)(part + (size_t)s * M * N + e);
        v.x += p.x; v.y += p.y; v.z += p.z; v.w += p.w;
    }
    const float4 bi = *(const float4*)(bias + col);
    v.x += bi.x; v.y += bi.y; v.z += bi.z; v.w += bi.w;
    if (res) {
        const float4 rr = *(const float4*)(res + e);
        v.x += rr.x; v.y += rr.y; v.z += rr.z; v.w += rr.w;
    }
    if (ACT == 1) { v.x = gelu_f(v.x); v.y = gelu_f(v.y); v.z = gelu_f(v.z); v.w = gelu_f(v.w); }
    if (OBF16) {
        ushort o[4] = { f2bf(v.x), f2bf(v.y), f2bf(v.z), f2bf(v.w) };
        *(uint2*)((ushort*)Cp + e) = *(const uint2*)o;
    } else {
        *(float4*)((float*)Cp + e) = v;
    }
}

// ---------------- QK^T GEMM (bf16, batched over heads), BK=32, XCD remap ----
__global__ __launch_bounds__(256) void k_mm(const ushort* __restrict__ A,
                                            const ushort* __restrict__ Wb,
                                            float* __restrict__ Cf,
                                            int M, int N, int K, int ldc, int Nw,
                                            long as_, long ws_, long cs_) {
    __shared__ __align__(16) ushort As[64 * 40];
    __shared__ __align__(16) ushort Bs[64 * 40];
    int nwg  = gridDim.x * gridDim.y * gridDim.z;
    int orig = blockIdx.x + gridDim.x * (blockIdx.y + gridDim.y * blockIdx.z);
    int work = xcd_remap(orig, nwg);
    int bx = work % gridDim.x;
    int rest = work / gridDim.x;
    int by = rest % gridDim.y;
    int z  = rest / gridDim.y;

    A  += (size_t)z * as_;
    Wb += (size_t)z * ws_;
    Cf += (size_t)z * cs_;

    int tid = threadIdx.x;
    int row0 = by * 64, col0 = bx * 64;

    int sm = tid >> 2, sp = tid & 3;
    int ar = row0 + sm; if (ar > M - 1) ar = M - 1;
    int wr = col0 + sm; if (wr > N - 1) wr = N - 1;
    const ushort* aptr = A + (size_t)ar * K;

    int lane = tid & 63, wid = tid >> 6;
    int wrr = (wid >> 1) * 32, wcc = (wid & 1) * 32;
    int fr = lane & 15, kg = lane >> 4;

    f32x4 acc[2][2] = {};

    for (int k0 = 0; k0 < K; k0 += 32) {
        *(uint4*)&As[sm * 40 + sp * 8] = *(const uint4*)(aptr + k0 + sp * 8);
        *(uint4*)&Bs[sm * 40 + sp * 8] = *(const uint4*)(Wb + (size_t)wr * K + k0 + sp * 8);
        __syncthreads();
        short8 a0 = *(const short8*)&As[(wrr + fr) * 40 + kg * 8];
        short8 a1 = *(const short8*)&As[(wrr + 16 + fr) * 40 + kg * 8];
        short8 b0 = *(const short8*)&Bs[(wcc + fr) * 40 + kg * 8];
        short8 b1 = *(const short8*)&Bs[(wcc + 16 + fr) * 40 + kg * 8];
        acc[0][0] = __builtin_amdgcn_mfma_f32_16x16x32_bf16(a0, b0, acc[0][0], 0, 0, 0);
        acc[0][1] = __builtin_amdgcn_mfma_f32_16x16x32_bf16(a0, b1, acc[0][1], 0, 0, 0);
        acc[1][0] = __builtin_amdgcn_mfma_f32_16x16x32_bf16(a1, b0, acc[1][0], 0, 0, 0);
        acc[1][1] = __builtin_amdgcn_mfma_f32_16x16x32_bf16(a1, b1, acc[1][1], 0, 0, 0);
        __syncthreads();
    }

#pragma unroll
    for (int fi = 0; fi < 2; fi++)
#pragma unroll
        for (int fj = 0; fj < 2; fj++)
#pragma unroll
            for (int r = 0; r < 4; r++) {
                int row = row0 + wrr + fi * 16 + (lane >> 4) * 4 + r;
                int col = col0 + wcc + fj * 16 + (lane & 15);
                if (row < M && col < Nw)
                    Cf[(size_t)row * ldc + col] = acc[fi][fj][r];
            }
}

// ---------------- qkv f32 -> rope(q),rope(k) bf16 [16,900,96], v^T bf16 [16,128,960]
__global__ __launch_bounds__(256) void k_rope(const float* __restrict__ qkv,
                                              const float* __restrict__ cs,
                                              const float* __restrict__ sn,
                                              ushort* __restrict__ q,
                                              ushort* __restrict__ k,
                                              ushort* __restrict__ vt) {
    int idx = blockIdx.x * 256 + threadIdx.x;
    if (idx >= NT * NH * DHP) return;
    int t = idx / (NH * DHP);
    int rem = idx - t * (NH * DHP);
    int h = rem / DHP, d = rem - h * DHP;
    size_t oi = ((size_t)h * NT + t) * DHP + d;
    if (d < DHD) {
        const float* base = qkv + (size_t)t * 3 * EMB;
        float c = cs[t * DHD + d], s = sn[t * DHD + d];
        int   d2 = (d < DHH) ? d + DHH : d - DHH;
        float sg = (d < DHH) ? -1.f : 1.f;
        int e = h * DHD + d;
        float qv = base[e] * c + sg * base[h * DHD + d2] * s;
        float kv = base[EMB + e] * c + sg * base[EMB + h * DHD + d2] * s;
        q[oi] = f2bf(qv);
        k[oi] = f2bf(kv);
        vt[((size_t)h * VR + d) * PW + t] = f2bf(base[2 * EMB + e]);
    } else {
        q[oi] = 0;
        k[oi] = 0;
    }
}

// ---------------- softmax: S f32 [16*900][928] -> P bf16 [16*900][960] -------
__global__ __launch_bounds__(256) void k_sm(const float* __restrict__ S,
                                            ushort* __restrict__ P) {
    int row = blockIdx.x * 4 + (threadIdx.x >> 6);
    int lane = threadIdx.x & 63;
    const float* sp = S + (size_t)row * KVP;
    ushort* pp = P + (size_t)row * PW;
    float v[15];
#pragma unroll
    for (int i = 0; i < 15; i++) {
        int kt = lane + i * 64;
        v[i] = (kt < NT) ? sp[kt] : -1e30f;
    }
    float mx = -1e30f;
#pragma unroll
    for (int i = 0; i < 15; i++) mx = fmaxf(mx, v[i]);
    for (int off = 32; off; off >>= 1) mx = fmaxf(mx, __shfl_xor(mx, off, 64));
    float sum = 0.f;
#pragma unroll
    for (int i = 0; i < 15; i++) {
        int kt = lane + i * 64;
        v[i] = (kt < NT) ? __expf(v[i] - mx) : 0.f;
        sum += v[i];
    }
    for (int off = 32; off; off >>= 1) sum += __shfl_xor(sum, off, 64);
    float inv = 1.f / sum;
#pragma unroll
    for (int i = 0; i < 15; i++) {
        int kt = lane + i * 64;
        pp[kt] = f2bf(v[i] * inv);      // kt < 960 always (max 959)
    }
}

extern "C" void kernel_launch(void* const* d_in, const int* in_sizes, int n_in,
                              void* d_out, int out_size, void* d_ws, size_t ws_size,
                              hipStream_t stream) {
    const float* pix     = (const float*)d_in[0];
    const float* patch_w = (const float*)d_in[1];
    const float* patch_b = (const float*)d_in[2];
    const float* pos_emb = (const float*)d_in[3];
    const float* cosb    = (const float*)d_in[4];
    const float* sinb    = (const float*)d_in[5];
    const float* ln1_w   = (const float*)d_in[6];
    const float* ln1_b   = (const float*)d_in[7];
    const float* qkv_w   = (const float*)d_in[8];
    const float* qkv_b   = (const float*)d_in[9];
    const float* proj_w  = (const float*)d_in[10];
    const float* proj_b  = (const float*)d_in[11];
    const float* ln2_w   = (const float*)d_in[12];
    const float* ln2_b   = (const float*)d_in[13];
    const float* fc1_w   = (const float*)d_in[14];
    const float* fc1_b   = (const float*)d_in[15];
    const float* fc2_w   = (const float*)d_in[16];
    const float* fc2_b   = (const float*)d_in[17];
    const float* dsn_w   = (const float*)d_in[18];
    const float* dsn_b   = (const float*)d_in[19];
    const float* ds1_w   = (const float*)d_in[20];
    const float* ds1_b   = (const float*)d_in[21];
    const float* ds2_w   = (const float*)d_in[22];
    const float* ds2_b   = (const float*)d_in[23];
    const float* mn_w    = (const float*)d_in[24];
    const float* mn_b    = (const float*)d_in[25];
    const float* mf1_w   = (const float*)d_in[26];
    const float* mf1_b   = (const float*)d_in[27];
    const float* mf2_w   = (const float*)d_in[28];
    const float* mf2_b   = (const float*)d_in[29];
    float* out = (float*)d_out;

    // ---- workspace carve ----
    float* wsf = (float*)d_ws;
    size_t off = 0;
    auto af = [&](size_t n) { float* p = wsf + off; off += (n + 3) & ~(size_t)3; return p; };
    float* h    = af((size_t)NT * EMB);
    float* qkv  = af((size_t)NT * 3 * EMB);
    float* part = af((size_t)4 * NT * EMB);
    float* S    = af((size_t)NH * NT * KVP);
    ushort* wsh = (ushort*)(wsf + off);
    size_t hoff = 0;
    auto ah = [&](size_t n) { ushort* p = wsh + hoff; hoff += (n + 7) & ~(size_t)7; return p; };
    ushort* hn  = ah((size_t)NT * EMB);
    ushort* hn2 = ah((size_t)NM * MHD);
    ushort* qb  = ah((size_t)NH * NT * DHP);
    ushort* kb  = ah((size_t)NH * NT * DHP);
    ushort* vt  = ah((size_t)NH * VR * PW);
    ushort* P   = ah((size_t)NH * NT * PW);
    ushort* ob  = ah((size_t)NT * EMB);
    ushort* t1  = ah((size_t)NT * FFD);
    ushort* xp  = t1;
    // bf16 weight mirrors
    ushort* w_patch = ah((size_t)EMB * 1536);
    ushort* w_qkv   = ah((size_t)NL * 3 * EMB * EMB);
    ushort* w_proj  = ah((size_t)NL * EMB * EMB);
    ushort* w_fc1   = ah((size_t)NL * FFD * EMB);
    ushort* w_fc2   = ah((size_t)NL * EMB * FFD);
    ushort* w_ds1   = ah((size_t)2 * MHD * MHD);
    ushort* w_ds2   = ah((size_t)2 * OUTD * MHD);
    ushort* w_mf1   = ah((size_t)MHD * MHD);
    ushort* w_mf2   = ah((size_t)OUTD * MHD);

    const long QS = (long)NT * DHP;
    const long SS = (long)NT * KVP;
    const long MN = (long)NT * EMB;

    const int MB  = (NT + 63) / 64;   // 15
    const int MBm = (NM + 63) / 64;   // 4
    auto fixg = [](int M, int N) { return dim3(((size_t)M * N / 4 + 255) / 256); };

    // ---- merged weight pre-conversion (one block-chunked launch) ----
    CvtArgs ca;
    const float* srcs[9] = { patch_w, qkv_w, proj_w, fc1_w, fc2_w, ds1_w, ds2_w, mf1_w, mf2_w };
    ushort* dsts[9] = { w_patch, w_qkv, w_proj, w_fc1, w_fc2, w_ds1, w_ds2, w_mf1, w_mf2 };
    long lens[9] = { (long)EMB * 1536, (long)NL * 3 * EMB * EMB, (long)NL * EMB * EMB,
                     (long)NL * FFD * EMB, (long)NL * EMB * FFD, (long)2 * MHD * MHD,
                     (long)2 * OUTD * MHD, (long)MHD * MHD, (long)OUTD * MHD };
    ca.blk[0] = 0;
    for (int i = 0; i < 9; ++i) {
        ca.src[i] = srcs[i];
        ca.dst[i] = dsts[i];
        ca.len4[i] = lens[i] / 4;
        ca.blk[i + 1] = ca.blk[i] + (int)((ca.len4[i] + CVT_CHUNK - 1) / CVT_CHUNK);
    }
    k_cvt9<<<dim3((unsigned)ca.blk[9]), 256, 0, stream>>>(ca);

    // patch extraction + vt zero in one launch
    const int PB = (NT * 1536 + 255) / 256;
    const int VB = (NH * VR * PW / 8 + 255) / 256;
    k_patch<<<dim3(PB + VB), 256, 0, stream>>>(pix, xp, vt, PB);
    // patch: M=900 N=1152 K=1536, S=2; fused: +pos_emb -> h, then ln1[0] -> hn
    k_bgs<0, 0, 1><<<dim3(MB, EMB / 64, 2), 256, 0, stream>>>(
        xp, w_patch, nullptr, nullptr, nullptr, part, NT, EMB, 1536, 2);
    k_fixln<<<NT, 256, 0, stream>>>(part, patch_b, pos_emb, h,
                                    ln1_w, ln1_b, hn, EMB, 2, MN);

    for (int l = 0; l < NL; ++l) {
        // qkv: M=900 N=3456 K=1152, S=1 -> 810 blocks, direct f32 + bias
        k_bgs<0, 0, 0><<<dim3(MB, 3 * EMB / 64, 1), 256, 0, stream>>>(
            hn, w_qkv + (size_t)l * 3 * EMB * EMB, qkv_b + l * 3 * EMB, nullptr, qkv,
            nullptr, NT, 3 * EMB, EMB, 1);
        k_rope<<<dim3((NT * NH * DHP + 255) / 256), 256, 0, stream>>>(
            qkv, cosb, sinb, qb, kb, vt);
        // S = Q @ K^T (per head), f32
        k_mm<<<dim3(MB, MB, NH), 256, 0, stream>>>(
            qb, kb, S, NT, NT, DHP, KVP, NT, QS, QS, SS);
        k_sm<<<dim3(NH * NT / 4), 256, 0, stream>>>(S, P);
        // O = P @ V (per head) via k_bgs-structure PV kernel
        k_att<<<dim3(MB, 2, NH), 256, 0, stream>>>(P, vt, ob);
        // proj: M=900 N=1152 K=1152, S=3; fused: +h residual -> h, then ln2 -> hn
        k_bgs<0, 0, 1><<<dim3(MB, EMB / 64, 3), 256, 0, stream>>>(
            ob, w_proj + (size_t)l * EMB * EMB, nullptr, nullptr, nullptr, part,
            NT, EMB, EMB, 3);
        k_fixln<<<NT, 256, 0, stream>>>(part, proj_b + l * EMB, h, h,
                                        ln2_w + l * EMB, ln2_b + l * EMB, hn,
                                        EMB, 3, MN);
        // fc1: M=900 N=4608 K=1152, S=1 -> 1080 blocks, direct gelu bf16
        k_bgs<1, 1, 0><<<dim3(MB, FFD / 64, 1), 256, 0, stream>>>(
            hn, w_fc1 + (size_t)l * FFD * EMB, fc1_b + l * FFD, nullptr, t1,
            nullptr, NT, FFD, EMB, 1);
        // fc2: M=900 N=1152 K=4608, S=4; fused: +h residual -> h, then next-LN -> hn
        const float* nlw = (l == NL - 1) ? mn_w : ln1_w + (l + 1) * EMB;
        const float* nlb = (l == NL - 1) ? mn_b : ln1_b + (l + 1) * EMB;
        k_bgs<0, 0, 1><<<dim3(MB, EMB / 64, 4), 256, 0, stream>>>(
            t1, w_fc2 + (size_t)l * EMB * FFD, nullptr, nullptr, nullptr, part,
            NT, EMB, FFD, 4);
        k_fixln<<<NT, 256, 0, stream>>>(part, fc2_b + l * EMB, h, h,
                                        nlw, nlb, hn, EMB, 4, MN);
        if (l == 2 || l == 5) {
            int d = (l == 2) ? 0 : 1;
            k_ln<<<NM, 256, 0, stream>>>(h, dsn_w + d * MHD, dsn_b + d * MHD, hn2, MHD);
            // ds1: M=225 N=4608 K=4608, S=4
            k_bgs<0, 0, 1><<<dim3(MBm, MHD / 64, 4), 256, 0, stream>>>(
                hn2, w_ds1 + (size_t)d * MHD * MHD, nullptr, nullptr, nullptr, part,
                NM, MHD, MHD, 4);
            k_fix<1, 1><<<fixg(NM, MHD), 256, 0, stream>>>(part, ds1_b + d * MHD,
                                                           nullptr, t1, NM, MHD, 4);
            // ds2: M=225 N=2048 K=4608, S=4
            k_bgs<0, 0, 1><<<dim3(MBm, OUTD / 64, 4), 256, 0, stream>>>(
                t1, w_ds2 + (size_t)d * OUTD * MHD, nullptr, nullptr, nullptr, part,
                NM, OUTD, MHD, 4);
            k_fix<0, 0><<<fixg(NM, OUTD), 256, 0, stream>>>(
                part, ds2_b + d * OUTD, nullptr, out + (size_t)d * NM * OUTD,
                NM, OUTD, 4);
        }
    }
    // merger: hn already holds merger-LN output ([900][1152] == [225][4608])
    k_bgs<0, 0, 1><<<dim3(MBm, MHD / 64, 4), 256, 0, stream>>>(
        hn, w_mf1, nullptr, nullptr, nullptr, part, NM, MHD, MHD, 4);
    k_fix<1, 1><<<fixg(NM, MHD), 256, 0, stream>>>(part, mf1_b, nullptr, t1, NM, MHD, 4);
    k_bgs<0, 0, 1><<<dim3(MBm, OUTD / 64, 4), 256, 0, stream>>>(
        t1, w_mf2, nullptr, nullptr, nullptr, part, NM, OUTD, MHD, 4);
    k_fix<0, 0><<<fixg(NM, OUTD), 256, 0, stream>>>(
        part, mf2_b, nullptr, out + (size_t)2 * NM * OUTD, NM, OUTD, 4);
}

// Round 18
// 1294.603 us; speedup vs baseline: 1.2560x; 1.0003x over previous
//
#include <hip/hip_runtime.h>
#include <hip/hip_bf16.h>
#include <cstdint>

#define NT   900
#define EMB  1152
#define NH   16
#define DHD  72
#define DHH  36
#define DHP  96      // padded head dim for QK (3*32)
#define KVP  928     // S width (29*32)
#define PW   960     // P / V^T K-width for PV (15*64)
#define VR   128     // V^T padded rows per head
#define NL   6
#define FFD  4608
#define MHD  4608
#define OUTD 2048
#define NM   225

typedef __attribute__((ext_vector_type(8))) short short8;
typedef __attribute__((ext_vector_type(4))) float f32x4;

__device__ __forceinline__ ushort f2bf(float f) {
    uint32_t u = __float_as_uint(f);
    uint32_t r = u + 0x7FFF + ((u >> 16) & 1);
    return (ushort)(r >> 16);
}
__device__ __forceinline__ float gelu_f(float x) {
    return 0.5f * x * (1.0f + tanhf(0.7978845608f * (x + 0.044715f * x * x * x)));
}

// async global -> LDS, 16B per lane (lds dest wave-uniform base; HW adds lane*16)
__device__ __forceinline__ void g2lds16(const ushort* g, ushort* l) {
    __builtin_amdgcn_global_load_lds(
        (const __attribute__((address_space(1))) unsigned int*)g,
        (__attribute__((address_space(3))) unsigned int*)l, 16, 0, 0);
}

// XCD-chunked bijective block remap (T1, m204): contiguous work chunk per XCD.
__device__ __forceinline__ int xcd_remap(int orig, int nwg) {
    int xcd = orig & 7, loc = orig >> 3;
    int q8 = nwg >> 3, r8 = nwg & 7;
    return (xcd < r8 ? xcd * (q8 + 1) : r8 * (q8 + 1) + (xcd - r8) * q8) + loc;
}

// ---------------- merged weight f32 -> bf16 pre-conversion (9 segments) ------
// Block-chunked, wide stores: each thread-step reads 2 float4 (32B) and writes
// one uint4 (16B). 2048 float4 per block; all segment lengths are exact
// multiples of the chunk.
#define CVT_CHUNK 2048L
struct CvtArgs {
    const float* src[9];
    ushort* dst[9];
    long len4[9];          // segment lengths in float4 units
    int blk[10];           // block prefix sums
};
__global__ __launch_bounds__(256) void k_cvt9(CvtArgs a) {
    int b = blockIdx.x;
    int g = 0;
#pragma unroll
    for (int i = 1; i < 9; ++i) if (b >= a.blk[i]) g = i;
    long n4 = a.len4[g];
    long base = (long)(b - a.blk[g]) * CVT_CHUNK;
    const float* s = a.src[g];
    ushort* d = a.dst[g];
#pragma unroll
    for (int j = 0; j < 4; ++j) {
        long i4 = base + ((long)threadIdx.x + j * 256) * 2;   // pair of float4s
        if (i4 + 1 < n4) {
            const float4 v0 = *(const float4*)(s + i4 * 4);
            const float4 v1 = *(const float4*)(s + i4 * 4 + 4);
            ushort o[8] = { f2bf(v0.x), f2bf(v0.y), f2bf(v0.z), f2bf(v0.w),
                            f2bf(v1.x), f2bf(v1.y), f2bf(v1.z), f2bf(v1.w) };
            *(uint4*)(d + i4 * 4) = *(const uint4*)o;
        }
    }
}

// ---------------- patch extraction + v^T zero (merged grids) ----------------
__global__ __launch_bounds__(256) void k_patch(const float* __restrict__ pix,
                                               ushort* __restrict__ xp,
                                               ushort* __restrict__ vt, int PB) {
    if ((int)blockIdx.x >= PB) {
        int idx = ((int)blockIdx.x - PB) * 256 + threadIdx.x;
        if (idx < NH * VR * PW / 8) {
            uint4 z = { 0, 0, 0, 0 };
            *(uint4*)(vt + (size_t)idx * 8) = z;
        }
        return;
    }
    int idx = blockIdx.x * 256 + threadIdx.x;
    if (idx >= NT * 1536) return;
    int t = idx / 1536, f = idx - t * 1536;
    int mw = t & 1, mh = (t >> 1) & 1;
    int tq = t >> 2;
    int jj = tq % 15, ii = tq / 15;
    int pw = f & 15, ph = (f >> 4) & 15, c = f >> 9;
    int Hi = (ii * 2 + mh) * 16 + ph;
    int Wi = (jj * 2 + mw) * 16 + pw;
    float p = pix[((size_t)c * 480 + Hi) * 480 + Wi];
    xp[idx] = f2bf((p - 127.5f) * (1.0f / 127.5f));
}

// ---------------- layernorm f32 in -> bf16 out, one block per row ----------------
__global__ __launch_bounds__(256) void k_ln(const float* __restrict__ x,
                                            const float* __restrict__ w,
                                            const float* __restrict__ b,
                                            ushort* __restrict__ y, int C) {
    int row = blockIdx.x;
    int tid = threadIdx.x;
    const float* xr = x + (size_t)row * C;
    float s = 0.f, ss = 0.f;
    for (int c = tid; c < C; c += 256) { float v = xr[c]; s += v; ss += v * v; }
    for (int off = 32; off; off >>= 1) {
        s  += __shfl_down(s,  off, 64);
        ss += __shfl_down(ss, off, 64);
    }
    __shared__ float rs[4], rss[4];
    int wid = tid >> 6, lane = tid & 63;
    if (lane == 0) { rs[wid] = s; rss[wid] = ss; }
    __syncthreads();
    float S  = rs[0] + rs[1] + rs[2] + rs[3];
    float SS = rss[0] + rss[1] + rss[2] + rss[3];
    float mu  = S / C;
    float var = SS / C - mu * mu;
    float inv = rsqrtf(var + 1e-6f);
    ushort* yr = y + (size_t)row * C;
    for (int c = tid; c < C; c += 256) yr[c] = f2bf((xr[c] - mu) * inv * w[c] + b[c]);
}

// ---------------- fused split-K reduce + bias + residual + LayerNorm ----------------
__global__ __launch_bounds__(256) void k_fixln(const float* __restrict__ part,
                                               const float* __restrict__ bias,
                                               const float* __restrict__ res,
                                               float* __restrict__ hout,
                                               const float* __restrict__ lw,
                                               const float* __restrict__ lb,
                                               ushort* __restrict__ y,
                                               int C, int S, long MN) {
    int row = blockIdx.x, tid = threadIdx.x;
    int C4 = C >> 2;
    const float* prow = part + (size_t)row * C;
    const float* rrow = res + (size_t)row * C;
    float* hrow = hout + (size_t)row * C;
    ushort* yrow = y + (size_t)row * C;

    float4 vals[2];
    float s = 0.f, ss = 0.f;
    int idx[2] = { tid, tid + 256 };
#pragma unroll
    for (int it = 0; it < 2; ++it) {
        int c4 = idx[it];
        if (c4 < C4) {
            float4 v = *(const float4*)(prow + c4 * 4);
            for (int sI = 1; sI < S; ++sI) {
                const float4 p = *(const float4*)(prow + (size_t)sI * MN + c4 * 4);
                v.x += p.x; v.y += p.y; v.z += p.z; v.w += p.w;
            }
            const float4 bi = *(const float4*)(bias + c4 * 4);
            v.x += bi.x; v.y += bi.y; v.z += bi.z; v.w += bi.w;
            const float4 rr = *(const float4*)(rrow + c4 * 4);
            v.x += rr.x; v.y += rr.y; v.z += rr.z; v.w += rr.w;
            *(float4*)(hrow + c4 * 4) = v;
            vals[it] = v;
            s  += v.x + v.y + v.z + v.w;
            ss += v.x * v.x + v.y * v.y + v.z * v.z + v.w * v.w;
        }
    }
    for (int off = 32; off; off >>= 1) {
        s  += __shfl_down(s,  off, 64);
        ss += __shfl_down(ss, off, 64);
    }
    __shared__ float rs[4], rss[4];
    int wid = tid >> 6, lane = tid & 63;
    if (lane == 0) { rs[wid] = s; rss[wid] = ss; }
    __syncthreads();
    float St  = rs[0] + rs[1] + rs[2] + rs[3];
    float SSt = rss[0] + rss[1] + rss[2] + rss[3];
    float mu  = St / C;
    float var = SSt / C - mu * mu;
    float inv = rsqrtf(var + 1e-6f);
#pragma unroll
    for (int it = 0; it < 2; ++it) {
        int c4 = idx[it];
        if (c4 < C4) {
            float4 v = vals[it];
            const float4 w4 = *(const float4*)(lw + c4 * 4);
            const float4 b4 = *(const float4*)(lb + c4 * 4);
            ushort o[4] = { f2bf((v.x - mu) * inv * w4.x + b4.x),
                            f2bf((v.y - mu) * inv * w4.y + b4.y),
                            f2bf((v.z - mu) * inv * w4.z + b4.z),
                            f2bf((v.w - mu) * inv * w4.w + b4.w) };
            *(uint2*)(yrow + c4 * 4) = *(const uint2*)o;
        }
    }
}

// ---------------- dense MFMA GEMM, 64x64 tile, BK=64, gload_lds + XOR swizzle
// + XCD remap.  C[M,N] = act(A @ W^T + bias) + res   (N % 64 == 0)
template <int ACT, int OBF16, int SPLIT>
__global__ __launch_bounds__(256) void k_bgs(const ushort* __restrict__ A,
                                             const ushort* __restrict__ W,
                                             const float* __restrict__ bias,
                                             const float* __restrict__ res,
                                             void* __restrict__ Cp,
                                             float* __restrict__ part,
                                             int M, int N, int K, int S) {
    __shared__ __align__(16) ushort As[64 * 64];
    __shared__ __align__(16) ushort Bs[64 * 64];
    int tid = threadIdx.x;

    int nwg  = gridDim.x * gridDim.y * gridDim.z;
    int orig = blockIdx.x + gridDim.x * (blockIdx.y + gridDim.y * blockIdx.z);
    int work = xcd_remap(orig, nwg);
    int bx = work % gridDim.x;
    int rest = work / gridDim.x;
    int by = rest % gridDim.y;
    int bz = rest / gridDim.y;

    int row0 = bx * 64, col0 = by * 64;
    int z = bz;
    int Kc = K / S;              // multiple of 64
    int kbeg = z * Kc;
    int steps = Kc >> 6;

    int w = tid >> 6, lane = tid & 63;
    int lrow = lane >> 3;
    int cg   = ((lane & 7) ^ lrow) << 3;

    int ar0 = row0 + w * 16 + lrow; if (ar0 > M - 1) ar0 = M - 1;
    int ar1 = row0 + w * 16 + 8 + lrow; if (ar1 > M - 1) ar1 = M - 1;
    int wr0 = col0 + w * 16 + lrow;
    int wr1 = wr0 + 8;
    const ushort* ap0 = A + (size_t)ar0 * K + kbeg + cg;
    const ushort* ap1 = A + (size_t)ar1 * K + kbeg + cg;
    const ushort* wp0 = W + (size_t)wr0 * K + kbeg + cg;
    const ushort* wp1 = W + (size_t)wr1 * K + kbeg + cg;
    ushort* asd0 = &As[(w * 16) * 64];
    ushort* asd1 = &As[(w * 16 + 8) * 64];
    ushort* bsd0 = &Bs[(w * 16) * 64];
    ushort* bsd1 = &Bs[(w * 16 + 8) * 64];

    int fr = lane & 15, kg8 = (lane >> 4) << 3;
    int wrr = (w >> 1) * 32, wcc = (w & 1) * 32;
    int sw = (fr & 7) << 3;

    f32x4 acc[2][2] = {};
    for (int s = 0; s < steps; ++s) {
        int kk = s << 6;
        __syncthreads();
        g2lds16(ap0 + kk, asd0);
        g2lds16(ap1 + kk, asd1);
        g2lds16(wp0 + kk, bsd0);
        g2lds16(wp1 + kk, bsd1);
        __syncthreads();
#pragma unroll
        for (int j = 0; j < 2; ++j) {
            int ko = j * 32 + kg8;
            int kx = ko ^ sw;
            short8 a0 = *(const short8*)&As[(wrr + fr) * 64 + kx];
            short8 a1 = *(const short8*)&As[(wrr + 16 + fr) * 64 + kx];
            short8 b0 = *(const short8*)&Bs[(wcc + fr) * 64 + kx];
            short8 b1 = *(const short8*)&Bs[(wcc + 16 + fr) * 64 + kx];
            acc[0][0] = __builtin_amdgcn_mfma_f32_16x16x32_bf16(a0, b0, acc[0][0], 0, 0, 0);
            acc[0][1] = __builtin_amdgcn_mfma_f32_16x16x32_bf16(a0, b1, acc[0][1], 0, 0, 0);
            acc[1][0] = __builtin_amdgcn_mfma_f32_16x16x32_bf16(a1, b0, acc[1][0], 0, 0, 0);
            acc[1][1] = __builtin_amdgcn_mfma_f32_16x16x32_bf16(a1, b1, acc[1][1], 0, 0, 0);
        }
    }

#pragma unroll
    for (int fi = 0; fi < 2; fi++)
#pragma unroll
        for (int fj = 0; fj < 2; fj++)
#pragma unroll
            for (int r = 0; r < 4; r++) {
                int row = row0 + wrr + fi * 16 + (lane >> 4) * 4 + r;
                int col = col0 + wcc + fj * 16 + fr;
                if (row < M) {
                    if (SPLIT) {
                        part[((size_t)z * M + row) * N + col] = acc[fi][fj][r];
                    } else {
                        float v = acc[fi][fj][r] + bias[col];
                        if (res) v += res[(size_t)row * N + col];
                        if (ACT == 1) v = gelu_f(v);
                        if (OBF16) ((ushort*)Cp)[(size_t)row * N + col] = f2bf(v);
                        else       ((float*)Cp)[(size_t)row * N + col] = v;
                    }
                }
            }
}

// ---------------- PV attention GEMM: k_bgs structure, head-batched ------------
__global__ __launch_bounds__(256) void k_att(const ushort* __restrict__ P,
                                             const ushort* __restrict__ Vt,
                                             ushort* __restrict__ ob) {
    __shared__ __align__(16) ushort As[64 * 64];
    __shared__ __align__(16) ushort Bs[64 * 64];
    int tid = threadIdx.x;

    int nwg  = gridDim.x * gridDim.y * gridDim.z;
    int orig = blockIdx.x + gridDim.x * (blockIdx.y + gridDim.y * blockIdx.z);
    int work = xcd_remap(orig, nwg);
    int bx = work % gridDim.x;
    int rest = work / gridDim.x;
    int by = rest % gridDim.y;
    int h  = rest / gridDim.y;

    int row0 = bx * 64, col0 = by * 64;
    const ushort* Ah = P  + (size_t)h * NT * PW;
    const ushort* Wh = Vt + (size_t)h * VR * PW;

    int w = tid >> 6, lane = tid & 63;
    int lrow = lane >> 3;
    int cg   = ((lane & 7) ^ lrow) << 3;

    int ar0 = row0 + w * 16 + lrow; if (ar0 > NT - 1) ar0 = NT - 1;
    int ar1 = row0 + w * 16 + 8 + lrow; if (ar1 > NT - 1) ar1 = NT - 1;
    int wr0 = col0 + w * 16 + lrow;
    int wr1 = wr0 + 8;
    const ushort* ap0 = Ah + (size_t)ar0 * PW + cg;
    const ushort* ap1 = Ah + (size_t)ar1 * PW + cg;
    const ushort* wp0 = Wh + (size_t)wr0 * PW + cg;
    const ushort* wp1 = Wh + (size_t)wr1 * PW + cg;
    ushort* asd0 = &As[(w * 16) * 64];
    ushort* asd1 = &As[(w * 16 + 8) * 64];
    ushort* bsd0 = &Bs[(w * 16) * 64];
    ushort* bsd1 = &Bs[(w * 16 + 8) * 64];

    int fr = lane & 15, kg8 = (lane >> 4) << 3;
    int wrr = (w >> 1) * 32, wcc = (w & 1) * 32;
    int sw = (fr & 7) << 3;

    f32x4 acc[2][2] = {};
    for (int s = 0; s < 15; ++s) {
        int kk = s << 6;
        __syncthreads();
        g2lds16(ap0 + kk, asd0);
        g2lds16(ap1 + kk, asd1);
        g2lds16(wp0 + kk, bsd0);
        g2lds16(wp1 + kk, bsd1);
        __syncthreads();
#pragma unroll
        for (int j = 0; j < 2; ++j) {
            int ko = j * 32 + kg8;
            int kx = ko ^ sw;
            short8 a0 = *(const short8*)&As[(wrr + fr) * 64 + kx];
            short8 a1 = *(const short8*)&As[(wrr + 16 + fr) * 64 + kx];
            short8 b0 = *(const short8*)&Bs[(wcc + fr) * 64 + kx];
            short8 b1 = *(const short8*)&Bs[(wcc + 16 + fr) * 64 + kx];
            acc[0][0] = __builtin_amdgcn_mfma_f32_16x16x32_bf16(a0, b0, acc[0][0], 0, 0, 0);
            acc[0][1] = __builtin_amdgcn_mfma_f32_16x16x32_bf16(a0, b1, acc[0][1], 0, 0, 0);
            acc[1][0] = __builtin_amdgcn_mfma_f32_16x16x32_bf16(a1, b0, acc[1][0], 0, 0, 0);
            acc[1][1] = __builtin_amdgcn_mfma_f32_16x16x32_bf16(a1, b1, acc[1][1], 0, 0, 0);
        }
    }

#pragma unroll
    for (int fi = 0; fi < 2; fi++)
#pragma unroll
        for (int fj = 0; fj < 2; fj++)
#pragma unroll
            for (int r = 0; r < 4; r++) {
                int row = row0 + wrr + fi * 16 + (lane >> 4) * 4 + r;
                int col = col0 + wcc + fj * 16 + fr;
                if (row < NT && col < DHD)
                    ob[(size_t)row * EMB + h * DHD + col] = f2bf(acc[fi][fj][r]);
            }
}

// ---------------- split-K fixup (no LN) ----------------
template <int ACT, int OBF16>
__global__ __launch_bounds__(256) void k_fix(const float* __restrict__ part,
                                             const float* __restrict__ bias,
                                             const float* __restrict__ res,
                                             void* __restrict__ Cp,
                                             int M, int N, int S) {
    size_t idx = (size_t)blockIdx.x * 256 + threadIdx.x;
    size_t total = (size_t)M * N / 4;
    if (idx >= total) return;
    size_t e = idx * 4;
    int row = (int)(e / N), col = (int)(e - (size_t)row * N);
    float4 v = *(const float4*)(part + e);
    for (int s = 1; s < S; ++s) {
        const float4 p = *(const float4*)(part + (size_t)s * M * N + e);
        v.x += p.x; v.y += p.y; v.z += p.z; v.w += p.w;
    }
    const float4 bi = *(const float4*)(bias + col);
    v.x += bi.x; v.y += bi.y; v.z += bi.z; v.w += bi.w;
    if (res) {
        const float4 rr = *(const float4*)(res + e);
        v.x += rr.x; v.y += rr.y; v.z += rr.z; v.w += rr.w;
    }
    if (ACT == 1) { v.x = gelu_f(v.x); v.y = gelu_f(v.y); v.z = gelu_f(v.z); v.w = gelu_f(v.w); }
    if (OBF16) {
        ushort o[4] = { f2bf(v.x), f2bf(v.y), f2bf(v.z), f2bf(v.w) };
        *(uint2*)((ushort*)Cp + e) = *(const uint2*)o;
    } else {
        *(float4*)((float*)Cp + e) = v;
    }
}

// ---------------- QK^T GEMM (bf16, batched over heads), BK=32, XCD remap ----
__global__ __launch_bounds__(256) void k_mm(const ushort* __restrict__ A,
                                            const ushort* __restrict__ Wb,
                                            float* __restrict__ Cf,
                                            int M, int N, int K, int ldc, int Nw,
                                            long as_, long ws_, long cs_) {
    __shared__ __align__(16) ushort As[64 * 40];
    __shared__ __align__(16) ushort Bs[64 * 40];
    int nwg  = gridDim.x * gridDim.y * gridDim.z;
    int orig = blockIdx.x + gridDim.x * (blockIdx.y + gridDim.y * blockIdx.z);
    int work = xcd_remap(orig, nwg);
    int bx = work % gridDim.x;
    int rest = work / gridDim.x;
    int by = rest % gridDim.y;
    int z  = rest / gridDim.y;

    A  += (size_t)z * as_;
    Wb += (size_t)z * ws_;
    Cf += (size_t)z * cs_;

    int tid = threadIdx.x;
    int row0 = by * 64, col0 = bx * 64;

    int sm = tid >> 2, sp = tid & 3;
    int ar = row0 + sm; if (ar > M - 1) ar = M - 1;
    int wr = col0 + sm; if (wr > N - 1) wr = N - 1;
    const ushort* aptr = A + (size_t)ar * K;

    int lane = tid & 63, wid = tid >> 6;
    int wrr = (wid >> 1) * 32, wcc = (wid & 1) * 32;
    int fr = lane & 15, kg = lane >> 4;

    f32x4 acc[2][2] = {};

    for (int k0 = 0; k0 < K; k0 += 32) {
        *(uint4*)&As[sm * 40 + sp * 8] = *(const uint4*)(aptr + k0 + sp * 8);
        *(uint4*)&Bs[sm * 40 + sp * 8] = *(const uint4*)(Wb + (size_t)wr * K + k0 + sp * 8);
        __syncthreads();
        short8 a0 = *(const short8*)&As[(wrr + fr) * 40 + kg * 8];
        short8 a1 = *(const short8*)&As[(wrr + 16 + fr) * 40 + kg * 8];
        short8 b0 = *(const short8*)&Bs[(wcc + fr) * 40 + kg * 8];
        short8 b1 = *(const short8*)&Bs[(wcc + 16 + fr) * 40 + kg * 8];
        acc[0][0] = __builtin_amdgcn_mfma_f32_16x16x32_bf16(a0, b0, acc[0][0], 0, 0, 0);
        acc[0][1] = __builtin_amdgcn_mfma_f32_16x16x32_bf16(a0, b1, acc[0][1], 0, 0, 0);
        acc[1][0] = __builtin_amdgcn_mfma_f32_16x16x32_bf16(a1, b0, acc[1][0], 0, 0, 0);
        acc[1][1] = __builtin_amdgcn_mfma_f32_16x16x32_bf16(a1, b1, acc[1][1], 0, 0, 0);
        __syncthreads();
    }

#pragma unroll
    for (int fi = 0; fi < 2; fi++)
#pragma unroll
        for (int fj = 0; fj < 2; fj++)
#pragma unroll
            for (int r = 0; r < 4; r++) {
                int row = row0 + wrr + fi * 16 + (lane >> 4) * 4 + r;
                int col = col0 + wcc + fj * 16 + (lane & 15);
                if (row < M && col < Nw)
                    Cf[(size_t)row * ldc + col] = acc[fi][fj][r];
            }
}

// ---------------- qkv f32 -> rope(q),rope(k) bf16 [16,900,96], v^T bf16 [16,128,960]
__global__ __launch_bounds__(256) void k_rope(const float* __restrict__ qkv,
                                              const float* __restrict__ cs,
                                              const float* __restrict__ sn,
                                              ushort* __restrict__ q,
                                              ushort* __restrict__ k,
                                              ushort* __restrict__ vt) {
    int idx = blockIdx.x * 256 + threadIdx.x;
    if (idx >= NT * NH * DHP) return;
    int t = idx / (NH * DHP);
    int rem = idx - t * (NH * DHP);
    int h = rem / DHP, d = rem - h * DHP;
    size_t oi = ((size_t)h * NT + t) * DHP + d;
    if (d < DHD) {
        const float* base = qkv + (size_t)t * 3 * EMB;
        float c = cs[t * DHD + d], s = sn[t * DHD + d];
        int   d2 = (d < DHH) ? d + DHH : d - DHH;
        float sg = (d < DHH) ? -1.f : 1.f;
        int e = h * DHD + d;
        float qv = base[e] * c + sg * base[h * DHD + d2] * s;
        float kv = base[EMB + e] * c + sg * base[EMB + h * DHD + d2] * s;
        q[oi] = f2bf(qv);
        k[oi] = f2bf(kv);
        vt[((size_t)h * VR + d) * PW + t] = f2bf(base[2 * EMB + e]);
    } else {
        q[oi] = 0;
        k[oi] = 0;
    }
}

// ---------------- softmax: S f32 [16*900][928] -> P bf16 [16*900][960] -------
__global__ __launch_bounds__(256) void k_sm(const float* __restrict__ S,
                                            ushort* __restrict__ P) {
    int row = blockIdx.x * 4 + (threadIdx.x >> 6);
    int lane = threadIdx.x & 63;
    const float* sp = S + (size_t)row * KVP;
    ushort* pp = P + (size_t)row * PW;
    float v[15];
#pragma unroll
    for (int i = 0; i < 15; i++) {
        int kt = lane + i * 64;
        v[i] = (kt < NT) ? sp[kt] : -1e30f;
    }
    float mx = -1e30f;
#pragma unroll
    for (int i = 0; i < 15; i++) mx = fmaxf(mx, v[i]);
    for (int off = 32; off; off >>= 1) mx = fmaxf(mx, __shfl_xor(mx, off, 64));
    float sum = 0.f;
#pragma unroll
    for (int i = 0; i < 15; i++) {
        int kt = lane + i * 64;
        v[i] = (kt < NT) ? __expf(v[i] - mx) : 0.f;
        sum += v[i];
    }
    for (int off = 32; off; off >>= 1) sum += __shfl_xor(sum, off, 64);
    float inv = 1.f / sum;
#pragma unroll
    for (int i = 0; i < 15; i++) {
        int kt = lane + i * 64;
        pp[kt] = f2bf(v[i] * inv);      // kt < 960 always (max 959)
    }
}

extern "C" void kernel_launch(void* const* d_in, const int* in_sizes, int n_in,
                              void* d_out, int out_size, void* d_ws, size_t ws_size,
                              hipStream_t stream) {
    const float* pix     = (const float*)d_in[0];
    const float* patch_w = (const float*)d_in[1];
    const float* patch_b = (const float*)d_in[2];
    const float* pos_emb = (const float*)d_in[3];
    const float* cosb    = (const float*)d_in[4];
    const float* sinb    = (const float*)d_in[5];
    const float* ln1_w   = (const float*)d_in[6];
    const float* ln1_b   = (const float*)d_in[7];
    const float* qkv_w   = (const float*)d_in[8];
    const float* qkv_b   = (const float*)d_in[9];
    const float* proj_w  = (const float*)d_in[10];
    const float* proj_b  = (const float*)d_in[11];
    const float* ln2_w   = (const float*)d_in[12];
    const float* ln2_b   = (const float*)d_in[13];
    const float* fc1_w   = (const float*)d_in[14];
    const float* fc1_b   = (const float*)d_in[15];
    const float* fc2_w   = (const float*)d_in[16];
    const float* fc2_b   = (const float*)d_in[17];
    const float* dsn_w   = (const float*)d_in[18];
    const float* dsn_b   = (const float*)d_in[19];
    const float* ds1_w   = (const float*)d_in[20];
    const float* ds1_b   = (const float*)d_in[21];
    const float* ds2_w   = (const float*)d_in[22];
    const float* ds2_b   = (const float*)d_in[23];
    const float* mn_w    = (const float*)d_in[24];
    const float* mn_b    = (const float*)d_in[25];
    const float* mf1_w   = (const float*)d_in[26];
    const float* mf1_b   = (const float*)d_in[27];
    const float* mf2_w   = (const float*)d_in[28];
    const float* mf2_b   = (const float*)d_in[29];
    float* out = (float*)d_out;

    // ---- workspace carve ----
    float* wsf = (float*)d_ws;
    size_t off = 0;
    auto af = [&](size_t n) { float* p = wsf + off; off += (n + 3) & ~(size_t)3; return p; };
    float* h    = af((size_t)NT * EMB);
    float* qkv  = af((size_t)NT * 3 * EMB);
    float* part = af((size_t)4 * NT * EMB);
    float* S    = af((size_t)NH * NT * KVP);
    ushort* wsh = (ushort*)(wsf + off);
    size_t hoff = 0;
    auto ah = [&](size_t n) { ushort* p = wsh + hoff; hoff += (n + 7) & ~(size_t)7; return p; };
    ushort* hn  = ah((size_t)NT * EMB);
    ushort* hn2 = ah((size_t)NM * MHD);
    ushort* qb  = ah((size_t)NH * NT * DHP);
    ushort* kb  = ah((size_t)NH * NT * DHP);
    ushort* vt  = ah((size_t)NH * VR * PW);
    ushort* P   = ah((size_t)NH * NT * PW);
    ushort* ob  = ah((size_t)NT * EMB);
    ushort* t1  = ah((size_t)NT * FFD);
    ushort* xp  = t1;
    // bf16 weight mirrors
    ushort* w_patch = ah((size_t)EMB * 1536);
    ushort* w_qkv   = ah((size_t)NL * 3 * EMB * EMB);
    ushort* w_proj  = ah((size_t)NL * EMB * EMB);
    ushort* w_fc1   = ah((size_t)NL * FFD * EMB);
    ushort* w_fc2   = ah((size_t)NL * EMB * FFD);
    ushort* w_ds1   = ah((size_t)2 * MHD * MHD);
    ushort* w_ds2   = ah((size_t)2 * OUTD * MHD);
    ushort* w_mf1   = ah((size_t)MHD * MHD);
    ushort* w_mf2   = ah((size_t)OUTD * MHD);

    const long QS = (long)NT * DHP;
    const long SS = (long)NT * KVP;
    const long MN = (long)NT * EMB;

    const int MB  = (NT + 63) / 64;   // 15
    const int MBm = (NM + 63) / 64;   // 4
    auto fixg = [](int M, int N) { return dim3(((size_t)M * N / 4 + 255) / 256); };

    // ---- merged weight pre-conversion (one block-chunked launch, wide stores) ----
    CvtArgs ca;
    const float* srcs[9] = { patch_w, qkv_w, proj_w, fc1_w, fc2_w, ds1_w, ds2_w, mf1_w, mf2_w };
    ushort* dsts[9] = { w_patch, w_qkv, w_proj, w_fc1, w_fc2, w_ds1, w_ds2, w_mf1, w_mf2 };
    long lens[9] = { (long)EMB * 1536, (long)NL * 3 * EMB * EMB, (long)NL * EMB * EMB,
                     (long)NL * FFD * EMB, (long)NL * EMB * FFD, (long)2 * MHD * MHD,
                     (long)2 * OUTD * MHD, (long)MHD * MHD, (long)OUTD * MHD };
    ca.blk[0] = 0;
    for (int i = 0; i < 9; ++i) {
        ca.src[i] = srcs[i];
        ca.dst[i] = dsts[i];
        ca.len4[i] = lens[i] / 4;
        ca.blk[i + 1] = ca.blk[i] + (int)((ca.len4[i] + CVT_CHUNK - 1) / CVT_CHUNK);
    }
    k_cvt9<<<dim3((unsigned)ca.blk[9]), 256, 0, stream>>>(ca);

    // patch extraction + vt zero in one launch
    const int PB = (NT * 1536 + 255) / 256;
    const int VB = (NH * VR * PW / 8 + 255) / 256;
    k_patch<<<dim3(PB + VB), 256, 0, stream>>>(pix, xp, vt, PB);
    // patch: M=900 N=1152 K=1536, S=2; fused: +pos_emb -> h, then ln1[0] -> hn
    k_bgs<0, 0, 1><<<dim3(MB, EMB / 64, 2), 256, 0, stream>>>(
        xp, w_patch, nullptr, nullptr, nullptr, part, NT, EMB, 1536, 2);
    k_fixln<<<NT, 256, 0, stream>>>(part, patch_b, pos_emb, h,
                                    ln1_w, ln1_b, hn, EMB, 2, MN);

    for (int l = 0; l < NL; ++l) {
        // qkv: M=900 N=3456 K=1152, S=1 -> 810 blocks, direct f32 + bias
        k_bgs<0, 0, 0><<<dim3(MB, 3 * EMB / 64, 1), 256, 0, stream>>>(
            hn, w_qkv + (size_t)l * 3 * EMB * EMB, qkv_b + l * 3 * EMB, nullptr, qkv,
            nullptr, NT, 3 * EMB, EMB, 1);
        k_rope<<<dim3((NT * NH * DHP + 255) / 256), 256, 0, stream>>>(
            qkv, cosb, sinb, qb, kb, vt);
        // S = Q @ K^T (per head), f32
        k_mm<<<dim3(MB, MB, NH), 256, 0, stream>>>(
            qb, kb, S, NT, NT, DHP, KVP, NT, QS, QS, SS);
        k_sm<<<dim3(NH * NT / 4), 256, 0, stream>>>(S, P);
        // O = P @ V (per head) via k_bgs-structure PV kernel
        k_att<<<dim3(MB, 2, NH), 256, 0, stream>>>(P, vt, ob);
        // proj: M=900 N=1152 K=1152, S=3; fused: +h residual -> h, then ln2 -> hn
        k_bgs<0, 0, 1><<<dim3(MB, EMB / 64, 3), 256, 0, stream>>>(
            ob, w_proj + (size_t)l * EMB * EMB, nullptr, nullptr, nullptr, part,
            NT, EMB, EMB, 3);
        k_fixln<<<NT, 256, 0, stream>>>(part, proj_b + l * EMB, h, h,
                                        ln2_w + l * EMB, ln2_b + l * EMB, hn,
                                        EMB, 3, MN);
        // fc1: M=900 N=4608 K=1152, S=1 -> 1080 blocks, direct gelu bf16
        k_bgs<1, 1, 0><<<dim3(MB, FFD / 64, 1), 256, 0, stream>>>(
            hn, w_fc1 + (size_t)l * FFD * EMB, fc1_b + l * FFD, nullptr, t1,
            nullptr, NT, FFD, EMB, 1);
        // fc2: M=900 N=1152 K=4608, S=4; fused: +h residual -> h, then next-LN -> hn
        const float* nlw = (l == NL - 1) ? mn_w : ln1_w + (l + 1) * EMB;
        const float* nlb = (l == NL - 1) ? mn_b : ln1_b + (l + 1) * EMB;
        k_bgs<0, 0, 1><<<dim3(MB, EMB / 64, 4), 256, 0, stream>>>(
            t1, w_fc2 + (size_t)l * EMB * FFD, nullptr, nullptr, nullptr, part,
            NT, EMB, FFD, 4);
        k_fixln<<<NT, 256, 0, stream>>>(part, fc2_b + l * EMB, h, h,
                                        nlw, nlb, hn, EMB, 4, MN);
        if (l == 2 || l == 5) {
            int d = (l == 2) ? 0 : 1;
            k_ln<<<NM, 256, 0, stream>>>(h, dsn_w + d * MHD, dsn_b + d * MHD, hn2, MHD);
            // ds1: M=225 N=4608 K=4608, S=4
            k_bgs<0, 0, 1><<<dim3(MBm, MHD / 64, 4), 256, 0, stream>>>(
                hn2, w_ds1 + (size_t)d * MHD * MHD, nullptr, nullptr, nullptr, part,
                NM, MHD, MHD, 4);
            k_fix<1, 1><<<fixg(NM, MHD), 256, 0, stream>>>(part, ds1_b + d * MHD,
                                                           nullptr, t1, NM, MHD, 4);
            // ds2: M=225 N=2048 K=4608, S=4
            k_bgs<0, 0, 1><<<dim3(MBm, OUTD / 64, 4), 256, 0, stream>>>(
                t1, w_ds2 + (size_t)d * OUTD * MHD, nullptr, nullptr, nullptr, part,
                NM, OUTD, MHD, 4);
            k_fix<0, 0><<<fixg(NM, OUTD), 256, 0, stream>>>(
                part, ds2_b + d * OUTD, nullptr, out + (size_t)d * NM * OUTD,
                NM, OUTD, 4);
        }
    }
    // merger: hn already holds merger-LN output ([900][1152] == [225][4608])
    k_bgs<0, 0, 1><<<dim3(MBm, MHD / 64, 4), 256, 0, stream>>>(
        hn, w_mf1, nullptr, nullptr, nullptr, part, NM, MHD, MHD, 4);
    k_fix<1, 1><<<fixg(NM, MHD), 256, 0, stream>>>(part, mf1_b, nullptr, t1, NM, MHD, 4);
    k_bgs<0, 0, 1><<<dim3(MBm, OUTD / 64, 4), 256, 0, stream>>>(
        t1, w_mf2, nullptr, nullptr, nullptr, part, NM, OUTD, MHD, 4);
    k_fix<0, 0><<<fixg(NM, OUTD), 256, 0, stream>>>(
        part, mf2_b, nullptr, out + (size_t)2 * NM * OUTD, NM, OUTD, 4);
}

// Round 20
// 1283.104 us; speedup vs baseline: 1.2672x; 1.0090x over previous
//
#include <hip/hip_runtime.h>
#include <hip/hip_bf16.h>
#include <cstdint>

#define NT   900
#define EMB  1152
#define NH   16
#define DHD  72
#define DHH  36
#define DHP  96      // padded head dim for QK (3*32)
#define KVP  928     // S width (29*32)
#define PW   960     // P / V^T K-width for PV (15*64)
#define VR   128     // V^T padded rows per head
#define NL   6
#define FFD  4608
#define MHD  4608
#define OUTD 2048
#define NM   225

typedef __attribute__((ext_vector_type(8))) short short8;
typedef __attribute__((ext_vector_type(4))) float f32x4;
typedef __attribute__((ext_vector_type(4))) float f32x4v;     // for NT builtins
typedef __attribute__((ext_vector_type(4))) unsigned int u32x4;

__device__ __forceinline__ ushort f2bf(float f) {
    uint32_t u = __float_as_uint(f);
    uint32_t r = u + 0x7FFF + ((u >> 16) & 1);
    return (ushort)(r >> 16);
}
__device__ __forceinline__ float gelu_f(float x) {
    return 0.5f * x * (1.0f + tanhf(0.7978845608f * (x + 0.044715f * x * x * x)));
}

// async global -> LDS, 16B per lane (lds dest wave-uniform base; HW adds lane*16)
__device__ __forceinline__ void g2lds16(const ushort* g, ushort* l) {
    __builtin_amdgcn_global_load_lds(
        (const __attribute__((address_space(1))) unsigned int*)g,
        (__attribute__((address_space(3))) unsigned int*)l, 16, 0, 0);
}

// XCD-chunked bijective block remap (T1, m204): contiguous work chunk per XCD.
__device__ __forceinline__ int xcd_remap(int orig, int nwg) {
    int xcd = orig & 7, loc = orig >> 3;
    int q8 = nwg >> 3, r8 = nwg & 7;
    return (xcd < r8 ? xcd * (q8 + 1) : r8 * (q8 + 1) + (xcd - r8) * q8) + loc;
}

// ---------------- merged weight f32 -> bf16 pre-conversion (9 segments) ------
// Block-chunked; NON-TEMPORAL loads/stores via native ext_vector types (the
// builtin rejects HIP_vector_type wrappers). Both streams touched exactly once
// -> bypass cache allocation.
#define CVT_CHUNK 2048L
struct CvtArgs {
    const float* src[9];
    ushort* dst[9];
    long len4[9];          // segment lengths in float4 units
    int blk[10];           // block prefix sums
};
__global__ __launch_bounds__(256) void k_cvt9(CvtArgs a) {
    int b = blockIdx.x;
    int g = 0;
#pragma unroll
    for (int i = 1; i < 9; ++i) if (b >= a.blk[i]) g = i;
    long n4 = a.len4[g];
    long base = (long)(b - a.blk[g]) * CVT_CHUNK;
    const float* s = a.src[g];
    ushort* d = a.dst[g];
#pragma unroll
    for (int j = 0; j < 4; ++j) {
        long i4 = base + ((long)threadIdx.x + j * 256) * 2;   // pair of float4s
        if (i4 + 1 < n4) {
            f32x4v v0 = __builtin_nontemporal_load((const f32x4v*)(s + i4 * 4));
            f32x4v v1 = __builtin_nontemporal_load((const f32x4v*)(s + i4 * 4 + 4));
            ushort o[8] = { f2bf(v0.x), f2bf(v0.y), f2bf(v0.z), f2bf(v0.w),
                            f2bf(v1.x), f2bf(v1.y), f2bf(v1.z), f2bf(v1.w) };
            __builtin_nontemporal_store(*(const u32x4*)o, (u32x4*)(d + i4 * 4));
        }
    }
}

// ---------------- patch extraction + v^T zero (merged grids) ----------------
__global__ __launch_bounds__(256) void k_patch(const float* __restrict__ pix,
                                               ushort* __restrict__ xp,
                                               ushort* __restrict__ vt, int PB) {
    if ((int)blockIdx.x >= PB) {
        int idx = ((int)blockIdx.x - PB) * 256 + threadIdx.x;
        if (idx < NH * VR * PW / 8) {
            uint4 z = { 0, 0, 0, 0 };
            *(uint4*)(vt + (size_t)idx * 8) = z;
        }
        return;
    }
    int idx = blockIdx.x * 256 + threadIdx.x;
    if (idx >= NT * 1536) return;
    int t = idx / 1536, f = idx - t * 1536;
    int mw = t & 1, mh = (t >> 1) & 1;
    int tq = t >> 2;
    int jj = tq % 15, ii = tq / 15;
    int pw = f & 15, ph = (f >> 4) & 15, c = f >> 9;
    int Hi = (ii * 2 + mh) * 16 + ph;
    int Wi = (jj * 2 + mw) * 16 + pw;
    float p = pix[((size_t)c * 480 + Hi) * 480 + Wi];
    xp[idx] = f2bf((p - 127.5f) * (1.0f / 127.5f));
}

// ---------------- layernorm f32 in -> bf16 out, one block per row ----------------
__global__ __launch_bounds__(256) void k_ln(const float* __restrict__ x,
                                            const float* __restrict__ w,
                                            const float* __restrict__ b,
                                            ushort* __restrict__ y, int C) {
    int row = blockIdx.x;
    int tid = threadIdx.x;
    const float* xr = x + (size_t)row * C;
    float s = 0.f, ss = 0.f;
    for (int c = tid; c < C; c += 256) { float v = xr[c]; s += v; ss += v * v; }
    for (int off = 32; off; off >>= 1) {
        s  += __shfl_down(s,  off, 64);
        ss += __shfl_down(ss, off, 64);
    }
    __shared__ float rs[4], rss[4];
    int wid = tid >> 6, lane = tid & 63;
    if (lane == 0) { rs[wid] = s; rss[wid] = ss; }
    __syncthreads();
    float S  = rs[0] + rs[1] + rs[2] + rs[3];
    float SS = rss[0] + rss[1] + rss[2] + rss[3];
    float mu  = S / C;
    float var = SS / C - mu * mu;
    float inv = rsqrtf(var + 1e-6f);
    ushort* yr = y + (size_t)row * C;
    for (int c = tid; c < C; c += 256) yr[c] = f2bf((xr[c] - mu) * inv * w[c] + b[c]);
}

// ---------------- fused split-K reduce + bias + residual + LayerNorm ----------------
__global__ __launch_bounds__(256) void k_fixln(const float* __restrict__ part,
                                               const float* __restrict__ bias,
                                               const float* __restrict__ res,
                                               float* __restrict__ hout,
                                               const float* __restrict__ lw,
                                               const float* __restrict__ lb,
                                               ushort* __restrict__ y,
                                               int C, int S, long MN) {
    int row = blockIdx.x, tid = threadIdx.x;
    int C4 = C >> 2;
    const float* prow = part + (size_t)row * C;
    const float* rrow = res + (size_t)row * C;
    float* hrow = hout + (size_t)row * C;
    ushort* yrow = y + (size_t)row * C;

    float4 vals[2];
    float s = 0.f, ss = 0.f;
    int idx[2] = { tid, tid + 256 };
#pragma unroll
    for (int it = 0; it < 2; ++it) {
        int c4 = idx[it];
        if (c4 < C4) {
            float4 v = *(const float4*)(prow + c4 * 4);
            for (int sI = 1; sI < S; ++sI) {
                const float4 p = *(const float4*)(prow + (size_t)sI * MN + c4 * 4);
                v.x += p.x; v.y += p.y; v.z += p.z; v.w += p.w;
            }
            const float4 bi = *(const float4*)(bias + c4 * 4);
            v.x += bi.x; v.y += bi.y; v.z += bi.z; v.w += bi.w;
            const float4 rr = *(const float4*)(rrow + c4 * 4);
            v.x += rr.x; v.y += rr.y; v.z += rr.z; v.w += rr.w;
            *(float4*)(hrow + c4 * 4) = v;
            vals[it] = v;
            s  += v.x + v.y + v.z + v.w;
            ss += v.x * v.x + v.y * v.y + v.z * v.z + v.w * v.w;
        }
    }
    for (int off = 32; off; off >>= 1) {
        s  += __shfl_down(s,  off, 64);
        ss += __shfl_down(ss, off, 64);
    }
    __shared__ float rs[4], rss[4];
    int wid = tid >> 6, lane = tid & 63;
    if (lane == 0) { rs[wid] = s; rss[wid] = ss; }
    __syncthreads();
    float St  = rs[0] + rs[1] + rs[2] + rs[3];
    float SSt = rss[0] + rss[1] + rss[2] + rss[3];
    float mu  = St / C;
    float var = SSt / C - mu * mu;
    float inv = rsqrtf(var + 1e-6f);
#pragma unroll
    for (int it = 0; it < 2; ++it) {
        int c4 = idx[it];
        if (c4 < C4) {
            float4 v = vals[it];
            const float4 w4 = *(const float4*)(lw + c4 * 4);
            const float4 b4 = *(const float4*)(lb + c4 * 4);
            ushort o[4] = { f2bf((v.x - mu) * inv * w4.x + b4.x),
                            f2bf((v.y - mu) * inv * w4.y + b4.y),
                            f2bf((v.z - mu) * inv * w4.z + b4.z),
                            f2bf((v.w - mu) * inv * w4.w + b4.w) };
            *(uint2*)(yrow + c4 * 4) = *(const uint2*)o;
        }
    }
}

// ---------------- dense MFMA GEMM, 64x64 tile, BK=64, gload_lds + XOR swizzle
// + XCD remap.  C[M,N] = act(A @ W^T + bias) + res   (N % 64 == 0)
template <int ACT, int OBF16, int SPLIT>
__global__ __launch_bounds__(256) void k_bgs(const ushort* __restrict__ A,
                                             const ushort* __restrict__ W,
                                             const float* __restrict__ bias,
                                             const float* __restrict__ res,
                                             void* __restrict__ Cp,
                                             float* __restrict__ part,
                                             int M, int N, int K, int S) {
    __shared__ __align__(16) ushort As[64 * 64];
    __shared__ __align__(16) ushort Bs[64 * 64];
    int tid = threadIdx.x;

    int nwg  = gridDim.x * gridDim.y * gridDim.z;
    int orig = blockIdx.x + gridDim.x * (blockIdx.y + gridDim.y * blockIdx.z);
    int work = xcd_remap(orig, nwg);
    int bx = work % gridDim.x;
    int rest = work / gridDim.x;
    int by = rest % gridDim.y;
    int bz = rest / gridDim.y;

    int row0 = bx * 64, col0 = by * 64;
    int z = bz;
    int Kc = K / S;              // multiple of 64
    int kbeg = z * Kc;
    int steps = Kc >> 6;

    int w = tid >> 6, lane = tid & 63;
    int lrow = lane >> 3;
    int cg   = ((lane & 7) ^ lrow) << 3;

    int ar0 = row0 + w * 16 + lrow; if (ar0 > M - 1) ar0 = M - 1;
    int ar1 = row0 + w * 16 + 8 + lrow; if (ar1 > M - 1) ar1 = M - 1;
    int wr0 = col0 + w * 16 + lrow;
    int wr1 = wr0 + 8;
    const ushort* ap0 = A + (size_t)ar0 * K + kbeg + cg;
    const ushort* ap1 = A + (size_t)ar1 * K + kbeg + cg;
    const ushort* wp0 = W + (size_t)wr0 * K + kbeg + cg;
    const ushort* wp1 = W + (size_t)wr1 * K + kbeg + cg;
    ushort* asd0 = &As[(w * 16) * 64];
    ushort* asd1 = &As[(w * 16 + 8) * 64];
    ushort* bsd0 = &Bs[(w * 16) * 64];
    ushort* bsd1 = &Bs[(w * 16 + 8) * 64];

    int fr = lane & 15, kg8 = (lane >> 4) << 3;
    int wrr = (w >> 1) * 32, wcc = (w & 1) * 32;
    int sw = (fr & 7) << 3;

    f32x4 acc[2][2] = {};
    for (int s = 0; s < steps; ++s) {
        int kk = s << 6;
        __syncthreads();
        g2lds16(ap0 + kk, asd0);
        g2lds16(ap1 + kk, asd1);
        g2lds16(wp0 + kk, bsd0);
        g2lds16(wp1 + kk, bsd1);
        __syncthreads();
#pragma unroll
        for (int j = 0; j < 2; ++j) {
            int ko = j * 32 + kg8;
            int kx = ko ^ sw;
            short8 a0 = *(const short8*)&As[(wrr + fr) * 64 + kx];
            short8 a1 = *(const short8*)&As[(wrr + 16 + fr) * 64 + kx];
            short8 b0 = *(const short8*)&Bs[(wcc + fr) * 64 + kx];
            short8 b1 = *(const short8*)&Bs[(wcc + 16 + fr) * 64 + kx];
            acc[0][0] = __builtin_amdgcn_mfma_f32_16x16x32_bf16(a0, b0, acc[0][0], 0, 0, 0);
            acc[0][1] = __builtin_amdgcn_mfma_f32_16x16x32_bf16(a0, b1, acc[0][1], 0, 0, 0);
            acc[1][0] = __builtin_amdgcn_mfma_f32_16x16x32_bf16(a1, b0, acc[1][0], 0, 0, 0);
            acc[1][1] = __builtin_amdgcn_mfma_f32_16x16x32_bf16(a1, b1, acc[1][1], 0, 0, 0);
        }
    }

#pragma unroll
    for (int fi = 0; fi < 2; fi++)
#pragma unroll
        for (int fj = 0; fj < 2; fj++)
#pragma unroll
            for (int r = 0; r < 4; r++) {
                int row = row0 + wrr + fi * 16 + (lane >> 4) * 4 + r;
                int col = col0 + wcc + fj * 16 + fr;
                if (row < M) {
                    if (SPLIT) {
                        part[((size_t)z * M + row) * N + col] = acc[fi][fj][r];
                    } else {
                        float v = acc[fi][fj][r] + bias[col];
                        if (res) v += res[(size_t)row * N + col];
                        if (ACT == 1) v = gelu_f(v);
                        if (OBF16) ((ushort*)Cp)[(size_t)row * N + col] = f2bf(v);
                        else       ((float*)Cp)[(size_t)row * N + col] = v;
                    }
                }
            }
}

// ---------------- PV attention GEMM: k_bgs structure, head-batched ------------
__global__ __launch_bounds__(256) void k_att(const ushort* __restrict__ P,
                                             const ushort* __restrict__ Vt,
                                             ushort* __restrict__ ob) {
    __shared__ __align__(16) ushort As[64 * 64];
    __shared__ __align__(16) ushort Bs[64 * 64];
    int tid = threadIdx.x;

    int nwg  = gridDim.x * gridDim.y * gridDim.z;
    int orig = blockIdx.x + gridDim.x * (blockIdx.y + gridDim.y * blockIdx.z);
    int work = xcd_remap(orig, nwg);
    int bx = work % gridDim.x;
    int rest = work / gridDim.x;
    int by = rest % gridDim.y;
    int h  = rest / gridDim.y;

    int row0 = bx * 64, col0 = by * 64;
    const ushort* Ah = P  + (size_t)h * NT * PW;
    const ushort* Wh = Vt + (size_t)h * VR * PW;

    int w = tid >> 6, lane = tid & 63;
    int lrow = lane >> 3;
    int cg   = ((lane & 7) ^ lrow) << 3;

    int ar0 = row0 + w * 16 + lrow; if (ar0 > NT - 1) ar0 = NT - 1;
    int ar1 = row0 + w * 16 + 8 + lrow; if (ar1 > NT - 1) ar1 = NT - 1;
    int wr0 = col0 + w * 16 + lrow;
    int wr1 = wr0 + 8;
    const ushort* ap0 = Ah + (size_t)ar0 * PW + cg;
    const ushort* ap1 = Ah + (size_t)ar1 * PW + cg;
    const ushort* wp0 = Wh + (size_t)wr0 * PW + cg;
    const ushort* wp1 = Wh + (size_t)wr1 * PW + cg;
    ushort* asd0 = &As[(w * 16) * 64];
    ushort* asd1 = &As[(w * 16 + 8) * 64];
    ushort* bsd0 = &Bs[(w * 16) * 64];
    ushort* bsd1 = &Bs[(w * 16 + 8) * 64];

    int fr = lane & 15, kg8 = (lane >> 4) << 3;
    int wrr = (w >> 1) * 32, wcc = (w & 1) * 32;
    int sw = (fr & 7) << 3;

    f32x4 acc[2][2] = {};
    for (int s = 0; s < 15; ++s) {
        int kk = s << 6;
        __syncthreads();
        g2lds16(ap0 + kk, asd0);
        g2lds16(ap1 + kk, asd1);
        g2lds16(wp0 + kk, bsd0);
        g2lds16(wp1 + kk, bsd1);
        __syncthreads();
#pragma unroll
        for (int j = 0; j < 2; ++j) {
            int ko = j * 32 + kg8;
            int kx = ko ^ sw;
            short8 a0 = *(const short8*)&As[(wrr + fr) * 64 + kx];
            short8 a1 = *(const short8*)&As[(wrr + 16 + fr) * 64 + kx];
            short8 b0 = *(const short8*)&Bs[(wcc + fr) * 64 + kx];
            short8 b1 = *(const short8*)&Bs[(wcc + 16 + fr) * 64 + kx];
            acc[0][0] = __builtin_amdgcn_mfma_f32_16x16x32_bf16(a0, b0, acc[0][0], 0, 0, 0);
            acc[0][1] = __builtin_amdgcn_mfma_f32_16x16x32_bf16(a0, b1, acc[0][1], 0, 0, 0);
            acc[1][0] = __builtin_amdgcn_mfma_f32_16x16x32_bf16(a1, b0, acc[1][0], 0, 0, 0);
            acc[1][1] = __builtin_amdgcn_mfma_f32_16x16x32_bf16(a1, b1, acc[1][1], 0, 0, 0);
        }
    }

#pragma unroll
    for (int fi = 0; fi < 2; fi++)
#pragma unroll
        for (int fj = 0; fj < 2; fj++)
#pragma unroll
            for (int r = 0; r < 4; r++) {
                int row = row0 + wrr + fi * 16 + (lane >> 4) * 4 + r;
                int col = col0 + wcc + fj * 16 + fr;
                if (row < NT && col < DHD)
                    ob[(size_t)row * EMB + h * DHD + col] = f2bf(acc[fi][fj][r]);
            }
}

// ---------------- split-K fixup (no LN) ----------------
template <int ACT, int OBF16>
__global__ __launch_bounds__(256) void k_fix(const float* __restrict__ part,
                                             const float* __restrict__ bias,
                                             const float* __restrict__ res,
                                             void* __restrict__ Cp,
                                             int M, int N, int S) {
    size_t idx = (size_t)blockIdx.x * 256 + threadIdx.x;
    size_t total = (size_t)M * N / 4;
    if (idx >= total) return;
    size_t e = idx * 4;
    int row = (int)(e / N), col = (int)(e - (size_t)row * N);
    float4 v = *(const float4*)(part + e);
    for (int s = 1; s < S; ++s) {
        const float4 p = *(const float4*)(part + (size_t)s * M * N + e);
        v.x += p.x; v.y += p.y; v.z += p.z; v.w += p.w;
    }
    const float4 bi = *(const float4*)(bias + col);
    v.x += bi.x; v.y += bi.y; v.z += bi.z; v.w += bi.w;
    if (res) {
        const float4 rr = *(const float4*)(res + e);
        v.x += rr.x; v.y += rr.y; v.z += rr.z; v.w += rr.w;
    }
    if (ACT == 1) { v.x = gelu_f(v.x); v.y = gelu_f(v.y); v.z = gelu_f(v.z); v.w = gelu_f(v.w); }
    if (OBF16) {
        ushort o[4] = { f2bf(v.x), f2bf(v.y), f2bf(v.z), f2bf(v.w) };
        *(uint2*)((ushort*)Cp + e) = *(const uint2*)o;
    } else {
        *(float4*)((float*)Cp + e) = v;
    }
}

// ---------------- QK^T GEMM (bf16, batched over heads), BK=32, XCD remap ----
__global__ __launch_bounds__(256) void k_mm(const ushort* __restrict__ A,
                                            const ushort* __restrict__ Wb,
                                            float* __restrict__ Cf,
                                            int M, int N, int K, int ldc, int Nw,
                                            long as_, long ws_, long cs_) {
    __shared__ __align__(16) ushort As[64 * 40];
    __shared__ __align__(16) ushort Bs[64 * 40];
    int nwg  = gridDim.x * gridDim.y * gridDim.z;
    int orig = blockIdx.x + gridDim.x * (blockIdx.y + gridDim.y * blockIdx.z);
    int work = xcd_remap(orig, nwg);
    int bx = work % gridDim.x;
    int rest = work / gridDim.x;
    int by = rest % gridDim.y;
    int z  = rest / gridDim.y;

    A  += (size_t)z * as_;
    Wb += (size_t)z * ws_;
    Cf += (size_t)z * cs_;

    int tid = threadIdx.x;
    int row0 = by * 64, col0 = bx * 64;

    int sm = tid >> 2, sp = tid & 3;
    int ar = row0 + sm; if (ar > M - 1) ar = M - 1;
    int wr = col0 + sm; if (wr > N - 1) wr = N - 1;
    const ushort* aptr = A + (size_t)ar * K;

    int lane = tid & 63, wid = tid >> 6;
    int wrr = (wid >> 1) * 32, wcc = (wid & 1) * 32;
    int fr = lane & 15, kg = lane >> 4;

    f32x4 acc[2][2] = {};

    for (int k0 = 0; k0 < K; k0 += 32) {
        *(uint4*)&As[sm * 40 + sp * 8] = *(const uint4*)(aptr + k0 + sp * 8);
        *(uint4*)&Bs[sm * 40 + sp * 8] = *(const uint4*)(Wb + (size_t)wr * K + k0 + sp * 8);
        __syncthreads();
        short8 a0 = *(const short8*)&As[(wrr + fr) * 40 + kg * 8];
        short8 a1 = *(const short8*)&As[(wrr + 16 + fr) * 40 + kg * 8];
        short8 b0 = *(const short8*)&Bs[(wcc + fr) * 40 + kg * 8];
        short8 b1 = *(const short8*)&Bs[(wcc + 16 + fr) * 40 + kg * 8];
        acc[0][0] = __builtin_amdgcn_mfma_f32_16x16x32_bf16(a0, b0, acc[0][0], 0, 0, 0);
        acc[0][1] = __builtin_amdgcn_mfma_f32_16x16x32_bf16(a0, b1, acc[0][1], 0, 0, 0);
        acc[1][0] = __builtin_amdgcn_mfma_f32_16x16x32_bf16(a1, b0, acc[1][0], 0, 0, 0);
        acc[1][1] = __builtin_amdgcn_mfma_f32_16x16x32_bf16(a1, b1, acc[1][1], 0, 0, 0);
        __syncthreads();
    }

#pragma unroll
    for (int fi = 0; fi < 2; fi++)
#pragma unroll
        for (int fj = 0; fj < 2; fj++)
#pragma unroll
            for (int r = 0; r < 4; r++) {
                int row = row0 + wrr + fi * 16 + (lane >> 4) * 4 + r;
                int col = col0 + wcc + fj * 16 + (lane & 15);
                if (row < M && col < Nw)
                    Cf[(size_t)row * ldc + col] = acc[fi][fj][r];
            }
}

// ---------------- qkv f32 -> rope(q),rope(k) bf16 [16,900,96], v^T bf16 [16,128,960]
__global__ __launch_bounds__(256) void k_rope(const float* __restrict__ qkv,
                                              const float* __restrict__ cs,
                                              const float* __restrict__ sn,
                                              ushort* __restrict__ q,
                                              ushort* __restrict__ k,
                                              ushort* __restrict__ vt) {
    int idx = blockIdx.x * 256 + threadIdx.x;
    if (idx >= NT * NH * DHP) return;
    int t = idx / (NH * DHP);
    int rem = idx - t * (NH * DHP);
    int h = rem / DHP, d = rem - h * DHP;
    size_t oi = ((size_t)h * NT + t) * DHP + d;
    if (d < DHD) {
        const float* base = qkv + (size_t)t * 3 * EMB;
        float c = cs[t * DHD + d], s = sn[t * DHD + d];
        int   d2 = (d < DHH) ? d + DHH : d - DHH;
        float sg = (d < DHH) ? -1.f : 1.f;
        int e = h * DHD + d;
        float qv = base[e] * c + sg * base[h * DHD + d2] * s;
        float kv = base[EMB + e] * c + sg * base[EMB + h * DHD + d2] * s;
        q[oi] = f2bf(qv);
        k[oi] = f2bf(kv);
        vt[((size_t)h * VR + d) * PW + t] = f2bf(base[2 * EMB + e]);
    } else {
        q[oi] = 0;
        k[oi] = 0;
    }
}

// ---------------- softmax: S f32 [16*900][928] -> P bf16 [16*900][960] -------
__global__ __launch_bounds__(256) void k_sm(const float* __restrict__ S,
                                            ushort* __restrict__ P) {
    int row = blockIdx.x * 4 + (threadIdx.x >> 6);
    int lane = threadIdx.x & 63;
    const float* sp = S + (size_t)row * KVP;
    ushort* pp = P + (size_t)row * PW;
    float v[15];
#pragma unroll
    for (int i = 0; i < 15; i++) {
        int kt = lane + i * 64;
        v[i] = (kt < NT) ? sp[kt] : -1e30f;
    }
    float mx = -1e30f;
#pragma unroll
    for (int i = 0; i < 15; i++) mx = fmaxf(mx, v[i]);
    for (int off = 32; off; off >>= 1) mx = fmaxf(mx, __shfl_xor(mx, off, 64));
    float sum = 0.f;
#pragma unroll
    for (int i = 0; i < 15; i++) {
        int kt = lane + i * 64;
        v[i] = (kt < NT) ? __expf(v[i] - mx) : 0.f;
        sum += v[i];
    }
    for (int off = 32; off; off >>= 1) sum += __shfl_xor(sum, off, 64);
    float inv = 1.f / sum;
#pragma unroll
    for (int i = 0; i < 15; i++) {
        int kt = lane + i * 64;
        pp[kt] = f2bf(v[i] * inv);      // kt < 960 always (max 959)
    }
}

extern "C" void kernel_launch(void* const* d_in, const int* in_sizes, int n_in,
                              void* d_out, int out_size, void* d_ws, size_t ws_size,
                              hipStream_t stream) {
    const float* pix     = (const float*)d_in[0];
    const float* patch_w = (const float*)d_in[1];
    const float* patch_b = (const float*)d_in[2];
    const float* pos_emb = (const float*)d_in[3];
    const float* cosb    = (const float*)d_in[4];
    const float* sinb    = (const float*)d_in[5];
    const float* ln1_w   = (const float*)d_in[6];
    const float* ln1_b   = (const float*)d_in[7];
    const float* qkv_w   = (const float*)d_in[8];
    const float* qkv_b   = (const float*)d_in[9];
    const float* proj_w  = (const float*)d_in[10];
    const float* proj_b  = (const float*)d_in[11];
    const float* ln2_w   = (const float*)d_in[12];
    const float* ln2_b   = (const float*)d_in[13];
    const float* fc1_w   = (const float*)d_in[14];
    const float* fc1_b   = (const float*)d_in[15];
    const float* fc2_w   = (const float*)d_in[16];
    const float* fc2_b   = (const float*)d_in[17];
    const float* dsn_w   = (const float*)d_in[18];
    const float* dsn_b   = (const float*)d_in[19];
    const float* ds1_w   = (const float*)d_in[20];
    const float* ds1_b   = (const float*)d_in[21];
    const float* ds2_w   = (const float*)d_in[22];
    const float* ds2_b   = (const float*)d_in[23];
    const float* mn_w    = (const float*)d_in[24];
    const float* mn_b    = (const float*)d_in[25];
    const float* mf1_w   = (const float*)d_in[26];
    const float* mf1_b   = (const float*)d_in[27];
    const float* mf2_w   = (const float*)d_in[28];
    const float* mf2_b   = (const float*)d_in[29];
    float* out = (float*)d_out;

    // ---- workspace carve ----
    float* wsf = (float*)d_ws;
    size_t off = 0;
    auto af = [&](size_t n) { float* p = wsf + off; off += (n + 3) & ~(size_t)3; return p; };
    float* h    = af((size_t)NT * EMB);
    float* qkv  = af((size_t)NT * 3 * EMB);
    float* part = af((size_t)4 * NT * EMB);
    float* S    = af((size_t)NH * NT * KVP);
    ushort* wsh = (ushort*)(wsf + off);
    size_t hoff = 0;
    auto ah = [&](size_t n) { ushort* p = wsh + hoff; hoff += (n + 7) & ~(size_t)7; return p; };
    ushort* hn  = ah((size_t)NT * EMB);
    ushort* hn2 = ah((size_t)NM * MHD);
    ushort* qb  = ah((size_t)NH * NT * DHP);
    ushort* kb  = ah((size_t)NH * NT * DHP);
    ushort* vt  = ah((size_t)NH * VR * PW);
    ushort* P   = ah((size_t)NH * NT * PW);
    ushort* ob  = ah((size_t)NT * EMB);
    ushort* t1  = ah((size_t)NT * FFD);
    ushort* xp  = t1;
    // bf16 weight mirrors
    ushort* w_patch = ah((size_t)EMB * 1536);
    ushort* w_qkv   = ah((size_t)NL * 3 * EMB * EMB);
    ushort* w_proj  = ah((size_t)NL * EMB * EMB);
    ushort* w_fc1   = ah((size_t)NL * FFD * EMB);
    ushort* w_fc2   = ah((size_t)NL * EMB * FFD);
    ushort* w_ds1   = ah((size_t)2 * MHD * MHD);
    ushort* w_ds2   = ah((size_t)2 * OUTD * MHD);
    ushort* w_mf1   = ah((size_t)MHD * MHD);
    ushort* w_mf2   = ah((size_t)OUTD * MHD);

    const long QS = (long)NT * DHP;
    const long SS = (long)NT * KVP;
    const long MN = (long)NT * EMB;

    const int MB  = (NT + 63) / 64;   // 15
    const int MBm = (NM + 63) / 64;   // 4
    auto fixg = [](int M, int N) { return dim3(((size_t)M * N / 4 + 255) / 256); };

    // ---- merged weight pre-conversion (one block-chunked launch, NT streams) ----
    CvtArgs ca;
    const float* srcs[9] = { patch_w, qkv_w, proj_w, fc1_w, fc2_w, ds1_w, ds2_w, mf1_w, mf2_w };
    ushort* dsts[9] = { w_patch, w_qkv, w_proj, w_fc1, w_fc2, w_ds1, w_ds2, w_mf1, w_mf2 };
    long lens[9] = { (long)EMB * 1536, (long)NL * 3 * EMB * EMB, (long)NL * EMB * EMB,
                     (long)NL * FFD * EMB, (long)NL * EMB * FFD, (long)2 * MHD * MHD,
                     (long)2 * OUTD * MHD, (long)MHD * MHD, (long)OUTD * MHD };
    ca.blk[0] = 0;
    for (int i = 0; i < 9; ++i) {
        ca.src[i] = srcs[i];
        ca.dst[i] = dsts[i];
        ca.len4[i] = lens[i] / 4;
        ca.blk[i + 1] = ca.blk[i] + (int)((ca.len4[i] + CVT_CHUNK - 1) / CVT_CHUNK);
    }
    k_cvt9<<<dim3((unsigned)ca.blk[9]), 256, 0, stream>>>(ca);

    // patch extraction + vt zero in one launch
    const int PB = (NT * 1536 + 255) / 256;
    const int VB = (NH * VR * PW / 8 + 255) / 256;
    k_patch<<<dim3(PB + VB), 256, 0, stream>>>(pix, xp, vt, PB);
    // patch: M=900 N=1152 K=1536, S=2; fused: +pos_emb -> h, then ln1[0] -> hn
    k_bgs<0, 0, 1><<<dim3(MB, EMB / 64, 2), 256, 0, stream>>>(
        xp, w_patch, nullptr, nullptr, nullptr, part, NT, EMB, 1536, 2);
    k_fixln<<<NT, 256, 0, stream>>>(part, patch_b, pos_emb, h,
                                    ln1_w, ln1_b, hn, EMB, 2, MN);

    for (int l = 0; l < NL; ++l) {
        // qkv: M=900 N=3456 K=1152, S=1 -> 810 blocks, direct f32 + bias
        k_bgs<0, 0, 0><<<dim3(MB, 3 * EMB / 64, 1), 256, 0, stream>>>(
            hn, w_qkv + (size_t)l * 3 * EMB * EMB, qkv_b + l * 3 * EMB, nullptr, qkv,
            nullptr, NT, 3 * EMB, EMB, 1);
        k_rope<<<dim3((NT * NH * DHP + 255) / 256), 256, 0, stream>>>(
            qkv, cosb, sinb, qb, kb, vt);
        // S = Q @ K^T (per head), f32
        k_mm<<<dim3(MB, MB, NH), 256, 0, stream>>>(
            qb, kb, S, NT, NT, DHP, KVP, NT, QS, QS, SS);
        k_sm<<<dim3(NH * NT / 4), 256, 0, stream>>>(S, P);
        // O = P @ V (per head) via k_bgs-structure PV kernel
        k_att<<<dim3(MB, 2, NH), 256, 0, stream>>>(P, vt, ob);
        // proj: M=900 N=1152 K=1152, S=3; fused: +h residual -> h, then ln2 -> hn
        k_bgs<0, 0, 1><<<dim3(MB, EMB / 64, 3), 256, 0, stream>>>(
            ob, w_proj + (size_t)l * EMB * EMB, nullptr, nullptr, nullptr, part,
            NT, EMB, EMB, 3);
        k_fixln<<<NT, 256, 0, stream>>>(part, proj_b + l * EMB, h, h,
                                        ln2_w + l * EMB, ln2_b + l * EMB, hn,
                                        EMB, 3, MN);
        // fc1: M=900 N=4608 K=1152, S=1 -> 1080 blocks, direct gelu bf16
        k_bgs<1, 1, 0><<<dim3(MB, FFD / 64, 1), 256, 0, stream>>>(
            hn, w_fc1 + (size_t)l * FFD * EMB, fc1_b + l * FFD, nullptr, t1,
            nullptr, NT, FFD, EMB, 1);
        // fc2: M=900 N=1152 K=4608, S=4; fused: +h residual -> h, then next-LN -> hn
        const float* nlw = (l == NL - 1) ? mn_w : ln1_w + (l + 1) * EMB;
        const float* nlb = (l == NL - 1) ? mn_b : ln1_b + (l + 1) * EMB;
        k_bgs<0, 0, 1><<<dim3(MB, EMB / 64, 4), 256, 0, stream>>>(
            t1, w_fc2 + (size_t)l * EMB * FFD, nullptr, nullptr, nullptr, part,
            NT, EMB, FFD, 4);
        k_fixln<<<NT, 256, 0, stream>>>(part, fc2_b + l * EMB, h, h,
                                        nlw, nlb, hn, EMB, 4, MN);
        if (l == 2 || l == 5) {
            int d = (l == 2) ? 0 : 1;
            k_ln<<<NM, 256, 0, stream>>>(h, dsn_w + d * MHD, dsn_b + d * MHD, hn2, MHD);
            // ds1: M=225 N=4608 K=4608, S=4
            k_bgs<0, 0, 1><<<dim3(MBm, MHD / 64, 4), 256, 0, stream>>>(
                hn2, w_ds1 + (size_t)d * MHD * MHD, nullptr, nullptr, nullptr, part,
                NM, MHD, MHD, 4);
            k_fix<1, 1><<<fixg(NM, MHD), 256, 0, stream>>>(part, ds1_b + d * MHD,
                                                           nullptr, t1, NM, MHD, 4);
            // ds2: M=225 N=2048 K=4608, S=4
            k_bgs<0, 0, 1><<<dim3(MBm, OUTD / 64, 4), 256, 0, stream>>>(
                t1, w_ds2 + (size_t)d * OUTD * MHD, nullptr, nullptr, nullptr, part,
                NM, OUTD, MHD, 4);
            k_fix<0, 0><<<fixg(NM, OUTD), 256, 0, stream>>>(
                part, ds2_b + d * OUTD, nullptr, out + (size_t)d * NM * OUTD,
                NM, OUTD, 4);
        }
    }
    // merger: hn already holds merger-LN output ([900][1152] == [225][4608])
    k_bgs<0, 0, 1><<<dim3(MBm, MHD / 64, 4), 256, 0, stream>>>(
        hn, w_mf1, nullptr, nullptr, nullptr, part, NM, MHD, MHD, 4);
    k_fix<1, 1><<<fixg(NM, MHD), 256, 0, stream>>>(part, mf1_b, nullptr, t1, NM, MHD, 4);
    k_bgs<0, 0, 1><<<dim3(MBm, OUTD / 64, 4), 256, 0, stream>>>(
        t1, w_mf2, nullptr, nullptr, nullptr, part, NM, OUTD, MHD, 4);
    k_fix<0, 0><<<fixg(NM, OUTD), 256, 0, stream>>>(
        part, mf2_b, nullptr, out + (size_t)2 * NM * OUTD, NM, OUTD, 4);
}